// Round 1
// baseline (514.949 us; speedup 1.0000x reference)
//
#include <hip/hip_runtime.h>
#include <hip/hip_bf16.h>
#include <cstddef>

typedef __hip_bfloat16 bf16;
typedef __attribute__((ext_vector_type(8))) short short8;
typedef __attribute__((ext_vector_type(4))) float float4v;
typedef __attribute__((ext_vector_type(4))) unsigned short ushort4v;

static __device__ __forceinline__ float b2f(bf16 v) { return __bfloat162float(v); }
static __device__ __forceinline__ float bits2f(unsigned int u) { return __uint_as_float(u); }
static __device__ __forceinline__ unsigned short f2bfbits(float f) {
  bf16 h = __float2bfloat16(f);
  return *reinterpret_cast<unsigned short*>(&h);
}
static __device__ __forceinline__ float ld_any(const void* p, long i, int flag) {
  return flag ? b2f(((const bf16*)p)[i]) : ((const float*)p)[i];
}
static __device__ __forceinline__ void unpack_u4(uint4 u, float* f) {
  f[0] = bits2f(u.x << 16); f[1] = bits2f(u.x & 0xffff0000u);
  f[2] = bits2f(u.y << 16); f[3] = bits2f(u.y & 0xffff0000u);
  f[4] = bits2f(u.z << 16); f[5] = bits2f(u.z & 0xffff0000u);
  f[6] = bits2f(u.w << 16); f[7] = bits2f(u.w & 0xffff0000u);
}

// --------------------------------------------------------- dtype detection
__global__ void detect_dtype_kernel(const void* __restrict__ x, int* __restrict__ flag) {
  __shared__ int ok;
  if (threadIdx.x == 0) ok = 1;
  __syncthreads();
  float v = b2f(((const bf16*)x)[threadIdx.x]);
  if (!(v >= 0.f && v <= 1.0009765625f)) ok = 0;
  __syncthreads();
  if (threadIdx.x == 0) *flag = ok;
}

// ---------------------------------------------------------------- utilities
__global__ void zero2_kernel(float* p) {
  if (threadIdx.x < 2) p[threadIdx.x] = 0.f;
}

// zero only the 1-wide halo ring of up to 3 same-shape padded NHWC buffers.
__global__ void zero_halo(bf16* p0, bf16* p1, bf16* p2, int np,
                          int H, int W, int C8, long imgS, int nimg, int gpi) {
  int tid = blockIdx.x * 256 + threadIdx.x;
  int total = nimg * gpi;
  int which = tid / total;
  if (which >= np) return;
  int r = tid - which * total;
  int img = r / gpi, g = r % gpi;
  int pos = g / C8, c8 = g % C8;
  int row, col;
  if (pos < W) { row = 0; col = pos; }
  else if (pos < 2 * W) { row = H - 1; col = pos - W; }
  else { int s = pos - 2 * W; row = 1 + (s >> 1); col = (s & 1) ? (W - 1) : 0; }
  bf16* base = (which == 0) ? p0 : ((which == 1) ? p1 : p2);
  uint4* dst = (uint4*)(base + (long)img * imgS + ((long)row * W + col) * (C8 * 8) + (long)c8 * 8);
  *dst = uint4{0u, 0u, 0u, 0u};
}

// all 6 conv biases -> one fp32 buffer
__global__ void conv_bias_all(const void* s2, const void* s4, const void* s6,
                              const void* s10, const void* s12, const void* s14,
                              float* __restrict__ dst, const int* __restrict__ flag) {
  int i = blockIdx.x * 256 + threadIdx.x;
  if (i >= 515) return;
  int fl = *flag;
  const void* s; int off;
  if (i < 64)       { s = s2;  off = i; }
  else if (i < 192) { s = s4;  off = i - 64; }
  else if (i < 320) { s = s6;  off = i - 192; }
  else if (i < 448) { s = s10; off = i - 320; }
  else if (i < 512) { s = s12; off = i - 448; }
  else              { s = s14; off = i - 512; }
  dst[i] = ld_any(s, off, fl);
}

// both codebooks -> contiguous bf16 [1024][128]
__global__ void conv_emb(const void* __restrict__ sT, const void* __restrict__ sB,
                         bf16* __restrict__ dst, const int* __restrict__ flag) {
  int i = blockIdx.x * 256 + threadIdx.x;   // 131072
  int fl = *flag;
  const void* s = (i < 65536) ? sT : sB;
  int off = i & 65535;
  dst[i] = fl ? ((const bf16*)s)[off] : __float2bfloat16(((const float*)s)[off]);
}

__global__ void embsq2(const bf16* __restrict__ embTB, float* __restrict__ sqAll) {
  int k = blockIdx.x * blockDim.x + threadIdx.x;
  if (k >= 1024) return;
  float s = 0.f;
  const bf16* e = embTB + (long)k * 128;
  for (int c = 0; c < 128; ++c) { float v = b2f(e[c]); s = fmaf(v, v, s); }
  sqAll[k] = s;
}

// conv1 weights [64][3][4][4] -> [co][k] bf16, K padded 48->64 with zeros
__global__ void rp_c1w(const void* __restrict__ src, bf16* __restrict__ dst,
                       const int* __restrict__ flag) {
  int i = blockIdx.x * blockDim.x + threadIdx.x;   // 64*64
  if (i >= 4096) return;
  int co = i >> 6, k = i & 63;
  float v = (k < 48) ? ld_any(src, co * 48 + k, *flag) : 0.f;
  dst[i] = __float2bfloat16(v);
}

// weights OIHW [CO][CI][4][4] -> [tap=kh*4+kw][co][ci] bf16
template <int CO, int CI>
__global__ void rp_conv_w(const void* __restrict__ src, bf16* __restrict__ dst,
                          const int* __restrict__ flag) {
  const int N = CO * CI * 16;
  int i = blockIdx.x * blockDim.x + threadIdx.x;
  if (i >= N) return;
  int co = i / (CI * 16);
  int rem = i % (CI * 16);
  int ci = rem >> 4;
  int k = rem & 15;
  dst[((long)k * CO + co) * CI + ci] = __float2bfloat16(ld_any(src, i, *flag));
}

// convT weights [CI][CO][4][4] -> [class pq][tap st][co][ci] bf16
template <int CI, int CO>
__global__ void rp_convt_w(const void* __restrict__ src, bf16* __restrict__ dst,
                           const int* __restrict__ flag) {
  const int N = CI * CO * 16;
  int i = blockIdx.x * blockDim.x + threadIdx.x;
  if (i >= N) return;
  int ci = i / (CO * 16);
  int rem = i % (CO * 16);
  int co = rem >> 4;
  int k = rem & 15;
  int kh = k >> 2, kw = k & 3;
  int p = (kh + 1) & 1, s = (kh - 1 + p) >> 1;
  int q = (kw + 1) & 1, t = (kw - 1 + q) >> 1;
  long d = (((long)(p * 2 + q) * 4 + (s * 2 + t)) * CO + co) * CI + ci;
  dst[d] = __float2bfloat16(ld_any(src, i, *flag));
}

// [tg][co][ci] -> fragment order [((tg*MC+mc)*KC+kc)*2+j][ln][quad*8]
template <int MC, int KC>
__global__ void frag_pack(const bf16* __restrict__ src, bf16* __restrict__ dst, int total) {
  int i = blockIdx.x * 256 + threadIdx.x;
  if (i >= total) return;
  int low = i & 511;
  int ln = low >> 5, cl = low & 31;
  int c2 = i >> 9;
  int j = c2 & 1;
  int c3 = c2 >> 1;
  int kc = c3 & (KC - 1);
  int c4 = c3 / KC;
  int mc = c4 & (MC - 1);
  int tg = c4 / MC;
  int co = mc * 32 + j * 16 + ln;
  int ci = kc * 32 + cl;
  dst[i] = src[((long)tg * (MC * 32) + co) * (KC * 32) + ci];
}

// d1 weights [256ci][64co][4][4] -> frag [(((cls*4+t)*8+kc)*4+j)][ln][quad*8]
__global__ void rp_d1f(const void* __restrict__ src, bf16* __restrict__ dst,
                       const int* __restrict__ flag) {
  int i = blockIdx.x * 256 + threadIdx.x;   // 262144
  if (i >= 262144) return;
  int low = i & 511;
  int ln = low >> 5, cl = low & 31;
  int c2 = i >> 9;
  int j = c2 & 3;
  int kc = (c2 >> 2) & 7;
  int t = (c2 >> 5) & 3;
  int cls = c2 >> 7;
  int p = cls >> 1, q = cls & 1;
  int s = t >> 1, t2 = t & 1;
  int kh = 2 * s + 1 - p, kw = 2 * t2 + 1 - q;
  int co = j * 16 + ln, ci = kc * 32 + cl;
  dst[i] = __float2bfloat16(ld_any(src, (long)ci * 1024 + co * 16 + kh * 4 + kw, *flag));
}

// final convT weights [64ci][3co][4][4] -> A[m=cls*4+co][d=dy*3+dx][64ci]
__global__ void rp_finw(const void* __restrict__ src, bf16* __restrict__ dst,
                        const int* __restrict__ flag) {
  int i = blockIdx.x * blockDim.x + threadIdx.x;   // 16*576 = 9216
  if (i >= 9216) return;
  int m = i / 576, rem = i % 576;
  int d = rem >> 6, ci = rem & 63;
  int cls = m >> 2, co = m & 3;
  int p = cls >> 1, q = cls & 1;
  int dy = d / 3, dx = d % 3;
  int s = p - dy + 1, t = q - dx + 1;
  float v = 0.f;
  if (co < 3 && s >= 0 && s <= 1 && t >= 0 && t <= 1) {
    int kh = 2 * s + 1 - p, kw = 2 * t + 1 - q;
    v = ld_any(src, ci * 48 + co * 16 + kh * 4 + kw, *flag);
  }
  dst[i] = __float2bfloat16(v);
}

// -------------------- conv1 as GEMM: im2col (K padded to 64) + MFMA GEMM
__global__ __launch_bounds__(256) void im2col1(const void* __restrict__ x,
                                               const int* __restrict__ flag,
                                               bf16* __restrict__ col) {
  int tid = blockIdx.x * 256 + threadIdx.x;   // 16*128*128
  int ow = tid & 127; int t = tid >> 7;
  int oh = t & 127; int b = t >> 7;
  int fl = *flag;
  int ih0 = oh * 2 - 1, iw0 = ow * 2 - 1;
  unsigned short vals[64];
  #pragma unroll
  for (int j = 48; j < 64; ++j) vals[j] = 0;
  #pragma unroll
  for (int ci = 0; ci < 3; ++ci) {
    long pbase = ((long)(b * 3 + ci)) << 16;
    #pragma unroll
    for (int kh = 0; kh < 4; ++kh) {
      int ih = ih0 + kh;
      bool okh = (unsigned)ih < 256u;
      long rbase = pbase + ((long)ih << 8);
      #pragma unroll
      for (int kw = 0; kw < 4; ++kw) {
        int iw = iw0 + kw;
        float v = (okh && (unsigned)iw < 256u) ? ld_any(x, rbase + iw, fl) : 0.f;
        vals[ci * 16 + kh * 4 + kw] = f2bfbits(v);
      }
    }
  }
  uint4* dst = (uint4*)(col + (long)tid * 64);
  const uint4* s = (const uint4*)vals;
  #pragma unroll
  for (int j = 0; j < 8; ++j) dst[j] = s[j];
}

// M=64 (co), K=64, N=262144; bias+relu; store parity-split padded NHWC
__global__ __launch_bounds__(256) void gemm1(const bf16* __restrict__ col,
                                             const bf16* __restrict__ w,
                                             const float* __restrict__ bias,
                                             bf16* __restrict__ act1p) {
  const int lane = threadIdx.x & 63, wv = threadIdx.x >> 6;
  const int wm = wv & 1, wn = wv >> 1;
  const int ln = lane & 15, quad = lane >> 4;
  const int n0 = blockIdx.x * 128 + wn * 64;
  float4v acc[2][4];
  #pragma unroll
  for (int i = 0; i < 2; ++i)
    #pragma unroll
    for (int j = 0; j < 4; ++j) acc[i][j] = {0.f, 0.f, 0.f, 0.f};
  #pragma unroll
  for (int kc = 0; kc < 2; ++kc) {
    const bf16* wk = w + (wm * 32 + ln) * 64 + kc * 32 + quad * 8;
    short8 a0 = *(const short8*)(wk);
    short8 a1 = *(const short8*)(wk + 16 * 64);
    #pragma unroll
    for (int bf = 0; bf < 4; ++bf) {
      short8 bv = *(const short8*)(col + (long)(n0 + bf * 16 + ln) * 64 + kc * 32 + quad * 8);
      acc[0][bf] = __builtin_amdgcn_mfma_f32_16x16x32_bf16(a0, bv, acc[0][bf], 0, 0, 0);
      acc[1][bf] = __builtin_amdgcn_mfma_f32_16x16x32_bf16(a1, bv, acc[1][bf], 0, 0, 0);
    }
  }
  #pragma unroll
  for (int mf = 0; mf < 2; ++mf) {
    int coB = wm * 32 + mf * 16 + quad * 4;
    float4v bv4 = *(const float4v*)(bias + coB);
    #pragma unroll
    for (int bf = 0; bf < 4; ++bf) {
      int n = n0 + bf * 16 + ln;
      int ow = n & 127; int t2 = n >> 7;
      int oh = t2 & 127; int b = t2 >> 7;
      int xx = ow + 1;   // parity-split column
      long oaddr = ((long)(b * 130 + oh + 1)) * 8320 +
                   (long)(((xx & 1) * 65) + (xx >> 1)) * 64 + coB;
      float4v v = acc[mf][bf];
      ushort4v o;
      #pragma unroll
      for (int e = 0; e < 4; ++e) o[e] = f2bfbits(fmaxf(v[e] + bv4[e], 0.f));
      *(ushort4v*)(act1p + oaddr) = o;
    }
  }
}

// ------------------------------------------- MFMA implicit-GEMM tap conv
template <int COUT, int CINT, int TC, int S, int NT, int INC, int NBF, int PXW>
__global__ __launch_bounds__(256) void mfma_conv(
    const bf16* __restrict__ in1, const bf16* __restrict__ in2,
    long inImgS, int inRowS,
    const bf16* __restrict__ wf, const float* __restrict__ bias,
    bf16* __restrict__ outp, long outImgS, int oRS, int oCS,
    int nxb, long po, long qo, int oPXW) {
  constexpr int TR = (2 * NBF * 16) / TC;
  constexpr int KC = CINT / 32;
  constexpr int MC = COUT / 32;
  constexpr int KSPLIT = (CINT > INC) ? (INC / 32) : KC;
  const int lane = threadIdx.x & 63;
  const int wv = threadIdx.x >> 6;
  const int wm = wv & 1, wn = wv >> 1;
  const int ln = lane & 15, quad = lane >> 4;
  const int cls = blockIdx.x >> nxb;
  const int xb = blockIdx.x & ((1u << nxb) - 1u);
  const int mTile = blockIdx.y * 64;
  const int mc = blockIdx.y * 2 + wm;
  const int oh0 = xb * TR;
  const int b = blockIdx.z;
  const int p = cls >> 1, q = cls & 1;
  const long ooff = (long)(p + 1) * po + (long)(q + 1) * qo;

  long posOff[NBF];
  int rr[NBF], cc[NBF];
  #pragma unroll
  for (int bf = 0; bf < NBF; ++bf) {
    int n = wn * (NBF * 16) + bf * 16 + ln;
    int r = n / TC, c = n % TC;
    rr[bf] = r; cc[bf] = c;
    posOff[bf] = (long)(S * (oh0 + r)) * inRowS +
                 (PXW ? (long)c * INC : (long)(S * c) * INC);
  }
  const bf16* inb1 = in1 + (long)b * inImgS;
  const bf16* inb2 = in2 + (long)b * inImgS;

  float4v acc[2][NBF];
  #pragma unroll
  for (int i = 0; i < 2; ++i)
    #pragma unroll
    for (int j = 0; j < NBF; ++j) acc[i][j] = {0.f, 0.f, 0.f, 0.f};

  for (int t = 0; t < NT; ++t) {
    int dy, dx;
    if (S == 2) { dy = t >> 2; dx = t & 3; }
    else        { dy = p - (t >> 1) + 1; dx = q - (t & 1) + 1; }
    const int dxo = PXW ? ((dx & 1) * PXW + (dx >> 1)) : dx;
    const long tapOff = (long)dy * inRowS + (long)dxo * INC;
    const bf16* wt = wf + ((long)(cls * NT + t) * MC + mc) * (KC * 1024) + ln * 32 + quad * 8;
    #pragma unroll
    for (int kc = 0; kc < KC; ++kc) {
      short8 a0 = *(const short8*)(wt + kc * 1024);
      short8 a1 = *(const short8*)(wt + kc * 1024 + 512);
      const bf16* bp = (kc < KSPLIT) ? inb1 : inb2;
      int kOff = (kc < KSPLIT ? kc : kc - KSPLIT) * 32 + quad * 8;
      #pragma unroll
      for (int bf = 0; bf < NBF; ++bf) {
        short8 bv = *(const short8*)(bp + posOff[bf] + tapOff + kOff);
        acc[0][bf] = __builtin_amdgcn_mfma_f32_16x16x32_bf16(a0, bv, acc[0][bf], 0, 0, 0);
        acc[1][bf] = __builtin_amdgcn_mfma_f32_16x16x32_bf16(a1, bv, acc[1][bf], 0, 0, 0);
      }
    }
  }

  bf16* outb = outp + (long)b * outImgS + ooff;
  #pragma unroll
  for (int mf = 0; mf < 2; ++mf) {
    int coB = mTile + wm * 32 + mf * 16 + quad * 4;
    float4v bv4 = *(const float4v*)(bias + coB);
    #pragma unroll
    for (int bf = 0; bf < NBF; ++bf) {
      float4v v = acc[mf][bf];
      ushort4v o;
      #pragma unroll
      for (int e = 0; e < 4; ++e)
        o[e] = f2bfbits(fmaxf(v[e] + bv4[e], 0.f));
      long coff = oPXW ? (long)((((cc[bf] + 1) & 1) * oPXW) + ((cc[bf] + 1) >> 1)) * oCS
                       : (long)cc[bf] * oCS;
      long oaddr = (long)(oh0 + rr[bf]) * oRS + coff + oCS * 0 + coB;
      *(ushort4v*)(outb + oaddr) = o;
    }
  }
}

// ---------- conv2 (64 -> 128, s2) with LDS-staged input, wave M64xN64
// Block: 128 threads = 2 waves (wave = co-half), one (img, output row oh).
// Phase f in {0,1}: stage act1p rows 2oh+2f, 2oh+2f+1 (2 contiguous parity
// rows, 2080 chunks) into LDS padded 8->9 chunks/pos; taps dy in {2f,2f+1}.
// Per (t,kc): 4 global A-frags + 4 ds_read B-frags -> 16 MFMA (4:1).
__global__ __launch_bounds__(128) void conv2_lds(
    const bf16* __restrict__ in, const bf16* __restrict__ wf,
    const float* __restrict__ bias, bf16* __restrict__ outp) {
  __shared__ short8 lds8[2 * 130 * 9];   // 37440 B
  const int lane = threadIdx.x & 63;
  const int h = threadIdx.x >> 6;        // co-half (wave id)
  const int ln = lane & 15, quad = lane >> 4;
  const int oh = blockIdx.x;             // output row 0..63
  const int b = blockIdx.z;

  const bf16* img = in + (long)b * 1081600;

  float4v acc[4][4];   // [j4 (co chunk)][bf (pos chunk)]
  #pragma unroll
  for (int j = 0; j < 4; ++j)
    #pragma unroll
    for (int bf = 0; bf < 4; ++bf) acc[j][bf] = {0.f, 0.f, 0.f, 0.f};

  #pragma unroll
  for (int f = 0; f < 2; ++f) {
    const short8* src8 = (const short8*)(img + (long)(2 * oh + 2 * f) * 8320);
    __syncthreads();
    for (int i = threadIdx.x; i < 2080; i += 128) {   // 2 rows x 130 pos x 8
      int pos2 = i >> 3, j = i & 7;                   // pos2 = r*130 + pos
      lds8[pos2 * 9 + j] = src8[i];
    }
    __syncthreads();
    #pragma unroll
    for (int tl = 0; tl < 8; ++tl) {
      const int t = 8 * f + tl;
      const int r = (t >> 2) & 1;        // row within phase
      const int dx = t & 3;
      const int pp = dx & 1, cb = dx >> 1;
      const int lbase = (r * 130 + pp * 65 + cb) * 9 + quad;
      const bf16* wt = wf + (long)(t * 4) * 2048 + (long)(2 * h) * 2048 +
                       ln * 32 + quad * 8;
      #pragma unroll
      for (int kc = 0; kc < 2; ++kc) {
        const bf16* wk = wt + kc * 1024;
        short8 a0 = *(const short8*)(wk);          // mc=2h,   j=0
        short8 a1 = *(const short8*)(wk + 512);    // mc=2h,   j=1
        short8 a2 = *(const short8*)(wk + 2048);   // mc=2h+1, j=0
        short8 a3 = *(const short8*)(wk + 2560);   // mc=2h+1, j=1
        #pragma unroll
        for (int bf = 0; bf < 4; ++bf) {
          short8 bv = lds8[lbase + (bf * 16 + ln) * 9 + kc * 4];
          acc[0][bf] = __builtin_amdgcn_mfma_f32_16x16x32_bf16(a0, bv, acc[0][bf], 0, 0, 0);
          acc[1][bf] = __builtin_amdgcn_mfma_f32_16x16x32_bf16(a1, bv, acc[1][bf], 0, 0, 0);
          acc[2][bf] = __builtin_amdgcn_mfma_f32_16x16x32_bf16(a2, bv, acc[2][bf], 0, 0, 0);
          acc[3][bf] = __builtin_amdgcn_mfma_f32_16x16x32_bf16(a3, bv, acc[3][bf], 0, 0, 0);
        }
      }
    }
  }

  // store: zbp parity layout, row oh+1, col map x -> ((x+1)&1)*33 + ((x+1)>>1)
  bf16* outb = outp + (long)b * 557568 + (long)(oh + 1) * 8448;
  #pragma unroll
  for (int j4 = 0; j4 < 4; ++j4) {
    int co = h * 64 + (j4 >> 1) * 32 + (j4 & 1) * 16 + quad * 4;
    float4v bv4 = *(const float4v*)(bias + co);
    #pragma unroll
    for (int bf = 0; bf < 4; ++bf) {
      int x = bf * 16 + ln;
      int col = (((x + 1) & 1) * 33) + ((x + 1) >> 1);
      float4v v = acc[j4][bf];
      ushort4v o;
      #pragma unroll
      for (int e = 0; e < 4; ++e)
        o[e] = f2bfbits(fmaxf(v[e] + bv4[e], 0.f));
      *(ushort4v*)(outb + (long)col * 128 + co) = o;
    }
  }
}

// ------ d1 (concat 256 -> 64): async-staged LDS, 4 classes/block,
// 2 output class-rows per block (r0 = 2*bx, r0+1).
// Staging: global_load_lds width=16, linear LDS dest, XOR-swizzled
// (j ^= pos&7) GLOBAL source (m173 pattern); reads apply the same XOR ->
// conflict-free ds_read_b128, no padding needed.
// Per (t,kc): 4 A-frags reused across 2 rows x 4 bf -> 32 MFMA (8:1),
// halving per-output weight L2 traffic vs 1-row blocks.
__global__ __launch_bounds__(256, 2) void mfma_d1_lds(
    const bf16* __restrict__ in1, const bf16* __restrict__ in2,
    const bf16* __restrict__ wf, const float* __restrict__ bias,
    bf16* __restrict__ outp) {
  __shared__ short8 lds8[4224];   // 4 rows x 66 pos x 16 chunks = 67584 B
  const int lane = threadIdx.x & 63, wv = threadIdx.x >> 6;
  const int ln = lane & 15, quad = lane >> 4;
  const int r0 = blockIdx.x * 2;     // output class-rows r0, r0+1
  const int b = blockIdx.z;
  const int cls = wv, p = cls >> 1, q = cls & 1;

  const bf16* src1 = in1 + (long)b * 557568 + (long)r0 * 8448;  // rows r0..r0+3
  const bf16* src2 = in2 + (long)b * 557568 + (long)r0 * 8448;

  float4v acc[2][4][4];
  #pragma unroll
  for (int rr = 0; rr < 2; ++rr)
    #pragma unroll
    for (int j = 0; j < 4; ++j)
      #pragma unroll
      for (int bf = 0; bf < 4; ++bf) acc[rr][j][bf] = {0.f, 0.f, 0.f, 0.f};

  #pragma unroll
  for (int phase = 0; phase < 2; ++phase) {
    const bf16* src = phase ? src2 : src1;
    __syncthreads();   // lds8 reuse guard (all waves done with prev phase)
    // 4224 = 16.5 * 256 -> last partial pass is exactly 2 full waves.
    for (int i = threadIdx.x; i < 4224; i += 256) {
      int pos = i >> 4;
      int sj = (i & 15) ^ (pos & 7);
      __builtin_amdgcn_global_load_lds(
          (const __attribute__((address_space(1))) void*)(src + (long)pos * 128 + sj * 8),
          (__attribute__((address_space(3))) void*)(lds8 + i), 16, 0, 0);
    }
    asm volatile("s_waitcnt vmcnt(0)" ::: "memory");
    __syncthreads();
    #pragma unroll
    for (int t = 0; t < 4; ++t) {
      int dy = p - (t >> 1) + 1, dx = q - (t & 1) + 1;
      const bf16* wt = wf + (long)(cls * 4 + t) * 16384 + (long)(phase * 4) * 2048 +
                       ln * 32 + quad * 8;
      #pragma unroll
      for (int kc = 0; kc < 4; ++kc) {
        const bf16* wk = wt + kc * 2048;
        short8 a0 = *(const short8*)(wk);
        short8 a1 = *(const short8*)(wk + 512);
        short8 a2 = *(const short8*)(wk + 1024);
        short8 a3 = *(const short8*)(wk + 1536);
        #pragma unroll
        for (int rr = 0; rr < 2; ++rr) {
          int prow = (rr + dy) * 66 + dx;
          // pos&7 == (prow+ln)&7 since bf*16 == 0 (mod 8)
          int jj = (kc * 4 + quad) ^ ((prow + ln) & 7);
          #pragma unroll
          for (int bf = 0; bf < 4; ++bf) {
            short8 bv = lds8[(prow + bf * 16 + ln) * 16 + jj];
            acc[rr][0][bf] = __builtin_amdgcn_mfma_f32_16x16x32_bf16(a0, bv, acc[rr][0][bf], 0, 0, 0);
            acc[rr][1][bf] = __builtin_amdgcn_mfma_f32_16x16x32_bf16(a1, bv, acc[rr][1][bf], 0, 0, 0);
            acc[rr][2][bf] = __builtin_amdgcn_mfma_f32_16x16x32_bf16(a2, bv, acc[rr][2][bf], 0, 0, 0);
            acc[rr][3][bf] = __builtin_amdgcn_mfma_f32_16x16x32_bf16(a3, bv, acc[rr][3][bf], 0, 0, 0);
          }
        }
      }
    }
  }

  #pragma unroll
  for (int rr = 0; rr < 2; ++rr) {
    bf16* outb = outp + (long)b * 1081600 + (long)(p + 1) * 8320 + (long)(q + 1) * 64 +
                 (long)(r0 + rr) * 16640;
    #pragma unroll
    for (int j = 0; j < 4; ++j) {
      int co = j * 16 + quad * 4;
      float4v bv4 = *(const float4v*)(bias + co);
      #pragma unroll
      for (int bf = 0; bf < 4; ++bf) {
        float4v v = acc[rr][j][bf];
        ushort4v o;
        #pragma unroll
        for (int e = 0; e < 4; ++e)
          o[e] = f2bfbits(fmaxf(v[e] + bv4[e], 0.f));
        *(ushort4v*)(outb + (long)(bf * 16 + ln) * 128 + co) = o;
      }
    }
  }
}

// ---------------------------------------------------- VQ via MFMA GEMM
__global__ __launch_bounds__(256) void vq_mfma(
    const bf16* __restrict__ z, long zImgS, int zRowS,
    const bf16* __restrict__ emb, const float* __restrict__ embsq,
    bf16* __restrict__ zq, long qImgS, int qRowS,
    float* __restrict__ loss_acc, int wb, int hwb, int ipxw) {
  const int lane = threadIdx.x & 63, wv = threadIdx.x >> 6;
  const int ln = lane & 15, quad = lane >> 4;
  const int base = blockIdx.x * 256 + wv * 64;

  short8 bfrag[4][4];
  #pragma unroll
  for (int bf = 0; bf < 4; ++bf) {
    int n = base + bf * 16 + ln;
    int b = n >> hwb;
    int rem = n & ((1 << hwb) - 1);
    int y = rem >> wb, x = rem & ((1 << wb) - 1);
    int xcol = ipxw ? ((((x + 1) & 1) * ipxw) + ((x + 1) >> 1)) : x;
    const bf16* zrow = z + (long)b * zImgS + (long)y * zRowS + (long)xcol * 128;
    #pragma unroll
    for (int kc = 0; kc < 4; ++kc)
      bfrag[bf][kc] = *(const short8*)(zrow + kc * 32 + quad * 8);
  }

  float best0 = 3.4e38f, best1 = 3.4e38f, best2 = 3.4e38f, best3 = 3.4e38f;
  int bk0 = 0, bk1 = 0, bk2 = 0, bk3 = 0;
  for (int ct = 0; ct < 32; ++ct) {
    const bf16* erow = emb + (long)(ct * 16 + ln) * 128 + quad * 8;
    short8 a0 = *(const short8*)(erow);
    short8 a1 = *(const short8*)(erow + 32);
    short8 a2 = *(const short8*)(erow + 64);
    short8 a3 = *(const short8*)(erow + 96);
    float4v sq4 = *(const float4v*)(embsq + ct * 16 + quad * 4);
    #pragma unroll
    for (int bf = 0; bf < 4; ++bf) {
      float4v acc = {0.f, 0.f, 0.f, 0.f};
      acc = __builtin_amdgcn_mfma_f32_16x16x32_bf16(a0, bfrag[bf][0], acc, 0, 0, 0);
      acc = __builtin_amdgcn_mfma_f32_16x16x32_bf16(a1, bfrag[bf][1], acc, 0, 0, 0);
      acc = __builtin_amdgcn_mfma_f32_16x16x32_bf16(a2, bfrag[bf][2], acc, 0, 0, 0);
      acc = __builtin_amdgcn_mfma_f32_16x16x32_bf16(a3, bfrag[bf][3], acc, 0, 0, 0);
      int kb = ct * 16 + quad * 4;
      #pragma unroll
      for (int r = 0; r < 4; ++r) {
        float s = fmaf(-2.f, acc[r], sq4[r]);
        if (bf == 0) { if (s < best0) { best0 = s; bk0 = kb + r; } }
        if (bf == 1) { if (s < best1) { best1 = s; bk1 = kb + r; } }
        if (bf == 2) { if (s < best2) { best2 = s; bk2 = kb + r; } }
        if (bf == 3) { if (s < best3) { best3 = s; bk3 = kb + r; } }
      }
    }
  }
  float bs[4] = {best0, best1, best2, best3};
  int bk[4] = {bk0, bk1, bk2, bk3};
  #pragma unroll
  for (int bf = 0; bf < 4; ++bf) {
    #pragma unroll
    for (int m = 16; m <= 32; m <<= 1) {
      float os = __shfl_xor(bs[bf], m, 64);
      int ok = __shfl_xor(bk[bf], m, 64);
      if (os < bs[bf] || (os == bs[bf] && ok < bk[bf])) { bs[bf] = os; bk[bf] = ok; }
    }
  }
  int myk = (quad == 0) ? bk[0] : (quad == 1) ? bk[1] : (quad == 2) ? bk[2] : bk[3];
  int n = base + quad * 16 + ln;
  int b = n >> hwb;
  int rem = n & ((1 << hwb) - 1);
  int y = rem >> wb, x = rem & ((1 << wb) - 1);
  int xcol = ipxw ? ((((x + 1) & 1) * ipxw) + ((x + 1) >> 1)) : x;
  const uint4* zr = (const uint4*)(z + (long)b * zImgS + (long)y * zRowS + (long)xcol * 128);
  uint4* qr = (uint4*)(zq + (long)b * qImgS + (long)y * qRowS + (long)x * 128);
  const uint4* er = (const uint4*)(emb + (long)myk * 128);
  float lsum = 0.f;
  #pragma unroll
  for (int j = 0; j < 16; ++j) {
    uint4 ue = er[j];
    uint4 uz = zr[j];
    qr[j] = ue;
    float ev[8], zv[8];
    unpack_u4(ue, ev);
    unpack_u4(uz, zv);
    #pragma unroll
    for (int e = 0; e < 8; ++e) {
      float dv = ev[e] - zv[e];
      lsum = fmaf(dv, dv, lsum);
    }
  }
  for (int o = 32; o > 0; o >>= 1) lsum += __shfl_down(lsum, o, 64);
  if (lane == 0) atomicAdd(loss_acc, lsum);
}

// --------------------- final convT(64->3)+sigmoid via class-packed MFMA
__global__ __launch_bounds__(256) void final_convt_mfma(
    const bf16* __restrict__ hp, const bf16* __restrict__ wfin,
    const float* __restrict__ bf_, float* __restrict__ out) {
  const int lane = threadIdx.x & 63, wv = threadIdx.x >> 6;
  const int ln = lane & 15, quad = lane >> 4;
  const int base = blockIdx.x * 256 + wv * 64;   // 262144 positions total

  short8 afr[18];
  #pragma unroll
  for (int kc = 0; kc < 18; ++kc)
    afr[kc] = *(const short8*)(wfin + ln * 576 + kc * 32 + quad * 8);

  float4v acc[4];
  #pragma unroll
  for (int bf = 0; bf < 4; ++bf) acc[bf] = {0.f, 0.f, 0.f, 0.f};

  #pragma unroll
  for (int bf = 0; bf < 4; ++bf) {
    int n = base + bf * 16 + ln;
    int xx = n & 127, y = (n >> 7) & 127, b = n >> 14;
    const bf16* hb = hp + (long)b * 1081600 + (long)y * 8320 + (long)xx * 64;
    #pragma unroll
    for (int kc = 0; kc < 18; ++kc) {
      int d = kc >> 1;
      const bf16* bp = hb + (long)(d / 3) * 8320 + (d % 3) * 64 + (kc & 1) * 32 + quad * 8;
      short8 bv = *(const short8*)bp;
      acc[bf] = __builtin_amdgcn_mfma_f32_16x16x32_bf16(afr[kc], bv, acc[bf], 0, 0, 0);
    }
  }

  const int p = quad >> 1, q = quad & 1;
  float b0 = bf_[0], b1 = bf_[1], b2 = bf_[2];
  #pragma unroll
  for (int bf = 0; bf < 4; ++bf) {
    int n = base + bf * 16 + ln;
    int xx = n & 127, y = (n >> 7) & 127, b = n >> 14;
    long ob = (long)b * 196608 + (long)(2 * y + p) * 256 + (2 * xx + q);
    float v0 = acc[bf][0] + b0, v1 = acc[bf][1] + b1, v2 = acc[bf][2] + b2;
    out[ob]          = 1.f / (1.f + expf(-v0));
    out[ob + 65536]  = 1.f / (1.f + expf(-v1));
    out[ob + 131072] = 1.f / (1.f + expf(-v2));
  }
}

__global__ void finalize_loss_kernel(const float* __restrict__ lacc, float* __restrict__ out) {
  if (threadIdx.x == 0) {
    float lt = lacc[0] * (1.5f / 2097152.f);
    float lb = lacc[1] * (1.5f / 8388608.f);
    *out = lt + lb;
  }
}

// ------------------------------------------------------------------ launch
extern "C" void kernel_launch(void* const* d_in, const int* in_sizes, int n_in,
                              void* d_out, int out_size, void* d_ws, size_t ws_size,
                              hipStream_t stream) {
  float* out = (float*)d_out;
  char* base = (char*)d_ws;
  size_t off = 0;
  auto alloc = [&](size_t bytes) {
    void* pp = base + off;
    off = (off + bytes + 255) & ~(size_t)255;
    return pp;
  };

  int* flag = (int*)alloc(256);
  float* biasAll = (float*)alloc(515 * 4);
  float* beB1f = biasAll + 0;
  float* beB2f = biasAll + 64;
  float* beTf  = biasAll + 192;
  float* bdTf  = biasAll + 320;
  float* bd1f  = biasAll + 448;
  float* bd2f  = biasAll + 512;
  float* sqAll = (float*)alloc(1024 * 4);
  float* sqT = sqAll, *sqB = sqAll + 512;
  float* lacc = (float*)alloc(2 * 4);
  bf16* Wc1  = (bf16*)alloc((size_t)4096 * 2);
  bf16* Wt2  = (bf16*)alloc((size_t)131072 * 2);
  bf16* Wtt  = (bf16*)alloc((size_t)262144 * 2);
  bf16* Wdt  = (bf16*)alloc((size_t)262144 * 2);
  bf16* Wt2f = (bf16*)alloc((size_t)131072 * 2);
  bf16* Wttf = (bf16*)alloc((size_t)262144 * 2);
  bf16* Wdtf = (bf16*)alloc((size_t)262144 * 2);
  bf16* Wd1f = (bf16*)alloc((size_t)262144 * 2);
  bf16* Wfin = (bf16*)alloc((size_t)9216 * 2);
  bf16* embTB = (bf16*)alloc((size_t)131072 * 2);
  bf16* embT = embTB, *embB = embTB + 65536;
  bf16* colb = (bf16*)alloc((size_t)16777216 * 2);   // im2col [262144][64]
  bf16* act1p = (bf16*)alloc((size_t)17305600 * 2);  // [16][130][2][65][64] parity
  bf16* zbp   = (bf16*)alloc((size_t)8921088 * 2);   // [16][66][2][33][128] parity
  bf16* zqtp  = (bf16*)alloc((size_t)2367488 * 2);   // [16][34][34][128]
  bf16* eup   = (bf16*)alloc((size_t)8921088 * 2);   // [16][66][66][128]
  bf16* fqp   = (bf16*)alloc((size_t)8921088 * 2);   // [16][66][66][128]
  bf16* hp    = (bf16*)alloc((size_t)17305600 * 2);  // [16][130][130][64]
  bf16* ztp   = (bf16*)alloc((size_t)2097152 * 2);   // [16][32][32][128]

  detect_dtype_kernel<<<1, 256, 0, stream>>>(d_in[0], flag);
  zero2_kernel<<<1, 64, 0, stream>>>(lacc);

  // halo-only zeroing (edge offsets identical in parity-split layout)
  zero_halo<<<517, 256, 0, stream>>>(act1p, hp, nullptr, 2, 130, 130, 8, 1081600, 16, 4128);
  zero_halo<<<781, 256, 0, stream>>>(zbp, eup, fqp, 3, 66, 66, 16, 557568, 16, 4160);
  zero_halo<<<132, 256, 0, stream>>>(zqtp, nullptr, nullptr, 1, 34, 34, 16, 147968, 16, 2112);

  // converts / repacks
  conv_bias_all<<<3, 256, 0, stream>>>(d_in[2], d_in[4], d_in[6], d_in[10],
                                       d_in[12], d_in[14], biasAll, flag);
  conv_emb<<<512, 256, 0, stream>>>(d_in[7], d_in[8], embTB, flag);
  embsq2<<<4, 256, 0, stream>>>(embTB, sqAll);
  rp_c1w<<<16, 256, 0, stream>>>(d_in[1], Wc1, flag);
  rp_conv_w<128, 64><<<512, 256, 0, stream>>>(d_in[3], Wt2, flag);
  rp_conv_w<128, 128><<<1024, 256, 0, stream>>>(d_in[5], Wtt, flag);
  rp_convt_w<128, 128><<<1024, 256, 0, stream>>>(d_in[9], Wdt, flag);
  rp_d1f<<<1024, 256, 0, stream>>>(d_in[11], Wd1f, flag);
  rp_finw<<<36, 256, 0, stream>>>(d_in[13], Wfin, flag);
  frag_pack<4, 2><<<512, 256, 0, stream>>>(Wt2, Wt2f, 131072);
  frag_pack<4, 4><<<1024, 256, 0, stream>>>(Wtt, Wttf, 262144);
  frag_pack<4, 4><<<1024, 256, 0, stream>>>(Wdt, Wdtf, 262144);

  // encoder: conv1 = im2col + MFMA GEMM (parity-split store)
  im2col1<<<1024, 256, 0, stream>>>(d_in[0], flag, colb);
  gemm1<<<2048, 256, 0, stream>>>(colb, Wc1, beB1f, act1p);
  // conv2: LDS-staged, wave M64xN64, 1024 blocks x 128 threads
  conv2_lds<<<dim3(64, 1, 16), 128, 0, stream>>>(act1p, Wt2f, beB2f, zbp);
  // conv_t: PXW=33 (zbp parity), output ztp row-major
  mfma_conv<128, 128, 32, 2, 16, 128, 2, 33><<<dim3(16, 2, 16), 256, 0, stream>>>(
      zbp, zbp, 557568, 8448, Wttf, beTf, ztp, 131072, 4096, 128, 30, 0, 0, 0);

  // VQ top (16384 positions, row-major)
  vq_mfma<<<64, 256, 0, stream>>>(ztp, 131072, 4096, embT, sqT,
                                  zqtp + 4480, 147968, 4352, lacc + 0, 5, 10, 0);

  // decoder_top upsample: 4 classes in one launch (row-major in/out)
  mfma_conv<128, 128, 32, 1, 4, 128, 2, 0><<<dim3(64, 2, 16), 256, 0, stream>>>(
      zqtp, zqtp, 147968, 4352, Wdtf, bdTf, eup, 557568, 16896, 256, 4, 8448, 128, 0);

  // VQ bottom (65536 positions; zbp parity-split input, fqp row-major out)
  vq_mfma<<<256, 256, 0, stream>>>(zbp + 8448, 557568, 8448, embB, sqB,
                                   fqp + 8576, 557568, 8448, lacc + 1, 6, 12, 33);

  // decoder conv d1: async-staged LDS, 4 classes + 2 rows per block, 512 blocks
  mfma_d1_lds<<<dim3(32, 1, 16), 256, 0, stream>>>(fqp, eup, Wd1f, bd1f, hp);

  // final convT + sigmoid via MFMA -> fp32 NCHW output
  final_convt_mfma<<<1024, 256, 0, stream>>>(hp, Wfin, bd2f, out);
  finalize_loss_kernel<<<1, 64, 0, stream>>>(lacc, out + 3145728);
}

// Round 2
// 492.621 us; speedup vs baseline: 1.0453x; 1.0453x over previous
//
#include <hip/hip_runtime.h>
#include <hip/hip_bf16.h>
#include <cstddef>

typedef __hip_bfloat16 bf16;
typedef __attribute__((ext_vector_type(8))) short short8;
typedef __attribute__((ext_vector_type(4))) float float4v;
typedef __attribute__((ext_vector_type(4))) unsigned short ushort4v;

static __device__ __forceinline__ float b2f(bf16 v) { return __bfloat162float(v); }
static __device__ __forceinline__ float bits2f(unsigned int u) { return __uint_as_float(u); }
static __device__ __forceinline__ unsigned short f2bfbits(float f) {
  bf16 h = __float2bfloat16(f);
  return *reinterpret_cast<unsigned short*>(&h);
}
static __device__ __forceinline__ float ld_any(const void* p, long i, int flag) {
  return flag ? b2f(((const bf16*)p)[i]) : ((const float*)p)[i];
}
static __device__ __forceinline__ void unpack_u4(uint4 u, float* f) {
  f[0] = bits2f(u.x << 16); f[1] = bits2f(u.x & 0xffff0000u);
  f[2] = bits2f(u.y << 16); f[3] = bits2f(u.y & 0xffff0000u);
  f[4] = bits2f(u.z << 16); f[5] = bits2f(u.z & 0xffff0000u);
  f[6] = bits2f(u.w << 16); f[7] = bits2f(u.w & 0xffff0000u);
}

// --------------------------------------------------------- dtype detection
__global__ void detect_dtype_kernel(const void* __restrict__ x, int* __restrict__ flag) {
  __shared__ int ok;
  if (threadIdx.x == 0) ok = 1;
  __syncthreads();
  float v = b2f(((const bf16*)x)[threadIdx.x]);
  if (!(v >= 0.f && v <= 1.0009765625f)) ok = 0;
  __syncthreads();
  if (threadIdx.x == 0) *flag = ok;
}

// ---------------------------------------------------------------- utilities
__global__ void zero2_kernel(float* p) {
  if (threadIdx.x < 2) p[threadIdx.x] = 0.f;
}

// zero only the 1-wide halo ring of up to 3 same-shape padded NHWC buffers.
__global__ void zero_halo(bf16* p0, bf16* p1, bf16* p2, int np,
                          int H, int W, int C8, long imgS, int nimg, int gpi) {
  int tid = blockIdx.x * 256 + threadIdx.x;
  int total = nimg * gpi;
  int which = tid / total;
  if (which >= np) return;
  int r = tid - which * total;
  int img = r / gpi, g = r % gpi;
  int pos = g / C8, c8 = g % C8;
  int row, col;
  if (pos < W) { row = 0; col = pos; }
  else if (pos < 2 * W) { row = H - 1; col = pos - W; }
  else { int s = pos - 2 * W; row = 1 + (s >> 1); col = (s & 1) ? (W - 1) : 0; }
  bf16* base = (which == 0) ? p0 : ((which == 1) ? p1 : p2);
  uint4* dst = (uint4*)(base + (long)img * imgS + ((long)row * W + col) * (C8 * 8) + (long)c8 * 8);
  *dst = uint4{0u, 0u, 0u, 0u};
}

// all 6 conv biases -> one fp32 buffer
__global__ void conv_bias_all(const void* s2, const void* s4, const void* s6,
                              const void* s10, const void* s12, const void* s14,
                              float* __restrict__ dst, const int* __restrict__ flag) {
  int i = blockIdx.x * 256 + threadIdx.x;
  if (i >= 515) return;
  int fl = *flag;
  const void* s; int off;
  if (i < 64)       { s = s2;  off = i; }
  else if (i < 192) { s = s4;  off = i - 64; }
  else if (i < 320) { s = s6;  off = i - 192; }
  else if (i < 448) { s = s10; off = i - 320; }
  else if (i < 512) { s = s12; off = i - 448; }
  else              { s = s14; off = i - 512; }
  dst[i] = ld_any(s, off, fl);
}

// both codebooks -> contiguous bf16 [1024][128]
__global__ void conv_emb(const void* __restrict__ sT, const void* __restrict__ sB,
                         bf16* __restrict__ dst, const int* __restrict__ flag) {
  int i = blockIdx.x * 256 + threadIdx.x;   // 131072
  int fl = *flag;
  const void* s = (i < 65536) ? sT : sB;
  int off = i & 65535;
  dst[i] = fl ? ((const bf16*)s)[off] : __float2bfloat16(((const float*)s)[off]);
}

__global__ void embsq2(const bf16* __restrict__ embTB, float* __restrict__ sqAll) {
  int k = blockIdx.x * blockDim.x + threadIdx.x;
  if (k >= 1024) return;
  float s = 0.f;
  const bf16* e = embTB + (long)k * 128;
  for (int c = 0; c < 128; ++c) { float v = b2f(e[c]); s = fmaf(v, v, s); }
  sqAll[k] = s;
}

// conv1 weights [64][3][4][4] -> [co][k] bf16, K padded 48->64 with zeros
__global__ void rp_c1w(const void* __restrict__ src, bf16* __restrict__ dst,
                       const int* __restrict__ flag) {
  int i = blockIdx.x * blockDim.x + threadIdx.x;   // 64*64
  if (i >= 4096) return;
  int co = i >> 6, k = i & 63;
  float v = (k < 48) ? ld_any(src, co * 48 + k, *flag) : 0.f;
  dst[i] = __float2bfloat16(v);
}

// weights OIHW [CO][CI][4][4] -> [tap=kh*4+kw][co][ci] bf16
template <int CO, int CI>
__global__ void rp_conv_w(const void* __restrict__ src, bf16* __restrict__ dst,
                          const int* __restrict__ flag) {
  const int N = CO * CI * 16;
  int i = blockIdx.x * blockDim.x + threadIdx.x;
  if (i >= N) return;
  int co = i / (CI * 16);
  int rem = i % (CI * 16);
  int ci = rem >> 4;
  int k = rem & 15;
  dst[((long)k * CO + co) * CI + ci] = __float2bfloat16(ld_any(src, i, *flag));
}

// convT weights [CI][CO][4][4] -> [class pq][tap st][co][ci] bf16
template <int CI, int CO>
__global__ void rp_convt_w(const void* __restrict__ src, bf16* __restrict__ dst,
                           const int* __restrict__ flag) {
  const int N = CI * CO * 16;
  int i = blockIdx.x * blockDim.x + threadIdx.x;
  if (i >= N) return;
  int ci = i / (CO * 16);
  int rem = i % (CO * 16);
  int co = rem >> 4;
  int k = rem & 15;
  int kh = k >> 2, kw = k & 3;
  int p = (kh + 1) & 1, s = (kh - 1 + p) >> 1;
  int q = (kw + 1) & 1, t = (kw - 1 + q) >> 1;
  long d = (((long)(p * 2 + q) * 4 + (s * 2 + t)) * CO + co) * CI + ci;
  dst[d] = __float2bfloat16(ld_any(src, i, *flag));
}

// [tg][co][ci] -> fragment order [((tg*MC+mc)*KC+kc)*2+j][ln][quad*8]
template <int MC, int KC>
__global__ void frag_pack(const bf16* __restrict__ src, bf16* __restrict__ dst, int total) {
  int i = blockIdx.x * 256 + threadIdx.x;
  if (i >= total) return;
  int low = i & 511;
  int ln = low >> 5, cl = low & 31;
  int c2 = i >> 9;
  int j = c2 & 1;
  int c3 = c2 >> 1;
  int kc = c3 & (KC - 1);
  int c4 = c3 / KC;
  int mc = c4 & (MC - 1);
  int tg = c4 / MC;
  int co = mc * 32 + j * 16 + ln;
  int ci = kc * 32 + cl;
  dst[i] = src[((long)tg * (MC * 32) + co) * (KC * 32) + ci];
}

// d1 weights [256ci][64co][4][4] -> frag [(((cls*4+t)*8+kc)*4+j)][ln][quad*8]
__global__ void rp_d1f(const void* __restrict__ src, bf16* __restrict__ dst,
                       const int* __restrict__ flag) {
  int i = blockIdx.x * 256 + threadIdx.x;   // 262144
  if (i >= 262144) return;
  int low = i & 511;
  int ln = low >> 5, cl = low & 31;
  int c2 = i >> 9;
  int j = c2 & 3;
  int kc = (c2 >> 2) & 7;
  int t = (c2 >> 5) & 3;
  int cls = c2 >> 7;
  int p = cls >> 1, q = cls & 1;
  int s = t >> 1, t2 = t & 1;
  int kh = 2 * s + 1 - p, kw = 2 * t2 + 1 - q;
  int co = j * 16 + ln, ci = kc * 32 + cl;
  dst[i] = __float2bfloat16(ld_any(src, (long)ci * 1024 + co * 16 + kh * 4 + kw, *flag));
}

// final convT weights [64ci][3co][4][4] -> A[m=cls*4+co][d=dy*3+dx][64ci]
__global__ void rp_finw(const void* __restrict__ src, bf16* __restrict__ dst,
                        const int* __restrict__ flag) {
  int i = blockIdx.x * blockDim.x + threadIdx.x;   // 16*576 = 9216
  if (i >= 9216) return;
  int m = i / 576, rem = i % 576;
  int d = rem >> 6, ci = rem & 63;
  int cls = m >> 2, co = m & 3;
  int p = cls >> 1, q = cls & 1;
  int dy = d / 3, dx = d % 3;
  int s = p - dy + 1, t = q - dx + 1;
  float v = 0.f;
  if (co < 3 && s >= 0 && s <= 1 && t >= 0 && t <= 1) {
    int kh = 2 * s + 1 - p, kw = 2 * t + 1 - q;
    v = ld_any(src, ci * 48 + co * 16 + kh * 4 + kw, *flag);
  }
  dst[i] = __float2bfloat16(v);
}

// -------------------- conv1 fused: inline im2col gather + MFMA GEMM
// M=64 (co), K=64 (48 real + 16 pad), N=262144; bias+relu; parity-split store.
// Each lane gathers its own 8 k-values (2 input rows x 4 contiguous pixels)
// directly from x -- no colb materialization (saves 64 MB HBM round-trip).
__global__ __launch_bounds__(256) void gemm1_fused(
    const void* __restrict__ x, const int* __restrict__ flag,
    const bf16* __restrict__ w, const float* __restrict__ bias,
    bf16* __restrict__ act1p) {
  const int lane = threadIdx.x & 63, wv = threadIdx.x >> 6;
  const int wm = wv & 1, wn = wv >> 1;
  const int ln = lane & 15, quad = lane >> 4;
  const int n0 = blockIdx.x * 128 + wn * 64;
  const int fl = *flag;
  float4v acc[2][4];
  #pragma unroll
  for (int i = 0; i < 2; ++i)
    #pragma unroll
    for (int j = 0; j < 4; ++j) acc[i][j] = {0.f, 0.f, 0.f, 0.f};
  #pragma unroll
  for (int kc = 0; kc < 2; ++kc) {
    const bf16* wk = w + (wm * 32 + ln) * 64 + kc * 32 + quad * 8;
    short8 a0 = *(const short8*)(wk);
    short8 a1 = *(const short8*)(wk + 16 * 64);
    const int k0 = kc * 32 + quad * 8;      // 0,8,...,56; >=48 is zero-pad
    #pragma unroll
    for (int bf = 0; bf < 4; ++bf) {
      short8 bv;
      if (k0 >= 48) {
        bv = (short8){0, 0, 0, 0, 0, 0, 0, 0};
      } else {
        int n = n0 + bf * 16 + ln;
        int ow = n & 127, oh = (n >> 7) & 127, b = n >> 14;
        int ci = k0 >> 4;
        int kh0 = (k0 & 15) >> 2;           // 0 or 2
        long pbase = ((long)(b * 3 + ci)) << 16;
        int iw0 = ow * 2 - 1;
        unsigned short tmp[8];
        #pragma unroll
        for (int r = 0; r < 2; ++r) {
          int ih = oh * 2 - 1 + kh0 + r;
          bool okh = (unsigned)ih < 256u;
          long rbase = pbase + ((long)ih << 8);
          #pragma unroll
          for (int c = 0; c < 4; ++c) {
            int iw = iw0 + c;
            float v = (okh && (unsigned)iw < 256u) ? ld_any(x, rbase + iw, fl) : 0.f;
            tmp[r * 4 + c] = f2bfbits(v);
          }
        }
        bv = *(const short8*)tmp;
      }
      acc[0][bf] = __builtin_amdgcn_mfma_f32_16x16x32_bf16(a0, bv, acc[0][bf], 0, 0, 0);
      acc[1][bf] = __builtin_amdgcn_mfma_f32_16x16x32_bf16(a1, bv, acc[1][bf], 0, 0, 0);
    }
  }
  #pragma unroll
  for (int mf = 0; mf < 2; ++mf) {
    int coB = wm * 32 + mf * 16 + quad * 4;
    float4v bv4 = *(const float4v*)(bias + coB);
    #pragma unroll
    for (int bf = 0; bf < 4; ++bf) {
      int n = n0 + bf * 16 + ln;
      int ow = n & 127; int t2 = n >> 7;
      int oh = t2 & 127; int b = t2 >> 7;
      int xx = ow + 1;   // parity-split column
      long oaddr = ((long)(b * 130 + oh + 1)) * 8320 +
                   (long)(((xx & 1) * 65) + (xx >> 1)) * 64 + coB;
      float4v v = acc[mf][bf];
      ushort4v o;
      #pragma unroll
      for (int e = 0; e < 4; ++e) o[e] = f2bfbits(fmaxf(v[e] + bv4[e], 0.f));
      *(ushort4v*)(act1p + oaddr) = o;
    }
  }
}

// ------------------------------------------- MFMA implicit-GEMM tap conv
template <int COUT, int CINT, int TC, int S, int NT, int INC, int NBF, int PXW>
__global__ __launch_bounds__(256) void mfma_conv(
    const bf16* __restrict__ in1, const bf16* __restrict__ in2,
    long inImgS, int inRowS,
    const bf16* __restrict__ wf, const float* __restrict__ bias,
    bf16* __restrict__ outp, long outImgS, int oRS, int oCS,
    int nxb, long po, long qo, int oPXW) {
  constexpr int TR = (2 * NBF * 16) / TC;
  constexpr int KC = CINT / 32;
  constexpr int MC = COUT / 32;
  constexpr int KSPLIT = (CINT > INC) ? (INC / 32) : KC;
  const int lane = threadIdx.x & 63;
  const int wv = threadIdx.x >> 6;
  const int wm = wv & 1, wn = wv >> 1;
  const int ln = lane & 15, quad = lane >> 4;
  const int cls = blockIdx.x >> nxb;
  const int xb = blockIdx.x & ((1u << nxb) - 1u);
  const int mTile = blockIdx.y * 64;
  const int mc = blockIdx.y * 2 + wm;
  const int oh0 = xb * TR;
  const int b = blockIdx.z;
  const int p = cls >> 1, q = cls & 1;
  const long ooff = (long)(p + 1) * po + (long)(q + 1) * qo;

  long posOff[NBF];
  int rr[NBF], cc[NBF];
  #pragma unroll
  for (int bf = 0; bf < NBF; ++bf) {
    int n = wn * (NBF * 16) + bf * 16 + ln;
    int r = n / TC, c = n % TC;
    rr[bf] = r; cc[bf] = c;
    posOff[bf] = (long)(S * (oh0 + r)) * inRowS +
                 (PXW ? (long)c * INC : (long)(S * c) * INC);
  }
  const bf16* inb1 = in1 + (long)b * inImgS;
  const bf16* inb2 = in2 + (long)b * inImgS;

  float4v acc[2][NBF];
  #pragma unroll
  for (int i = 0; i < 2; ++i)
    #pragma unroll
    for (int j = 0; j < NBF; ++j) acc[i][j] = {0.f, 0.f, 0.f, 0.f};

  for (int t = 0; t < NT; ++t) {
    int dy, dx;
    if (S == 2) { dy = t >> 2; dx = t & 3; }
    else        { dy = p - (t >> 1) + 1; dx = q - (t & 1) + 1; }
    const int dxo = PXW ? ((dx & 1) * PXW + (dx >> 1)) : dx;
    const long tapOff = (long)dy * inRowS + (long)dxo * INC;
    const bf16* wt = wf + ((long)(cls * NT + t) * MC + mc) * (KC * 1024) + ln * 32 + quad * 8;
    #pragma unroll
    for (int kc = 0; kc < KC; ++kc) {
      short8 a0 = *(const short8*)(wt + kc * 1024);
      short8 a1 = *(const short8*)(wt + kc * 1024 + 512);
      const bf16* bp = (kc < KSPLIT) ? inb1 : inb2;
      int kOff = (kc < KSPLIT ? kc : kc - KSPLIT) * 32 + quad * 8;
      #pragma unroll
      for (int bf = 0; bf < NBF; ++bf) {
        short8 bv = *(const short8*)(bp + posOff[bf] + tapOff + kOff);
        acc[0][bf] = __builtin_amdgcn_mfma_f32_16x16x32_bf16(a0, bv, acc[0][bf], 0, 0, 0);
        acc[1][bf] = __builtin_amdgcn_mfma_f32_16x16x32_bf16(a1, bv, acc[1][bf], 0, 0, 0);
      }
    }
  }

  bf16* outb = outp + (long)b * outImgS + ooff;
  #pragma unroll
  for (int mf = 0; mf < 2; ++mf) {
    int coB = mTile + wm * 32 + mf * 16 + quad * 4;
    float4v bv4 = *(const float4v*)(bias + coB);
    #pragma unroll
    for (int bf = 0; bf < NBF; ++bf) {
      float4v v = acc[mf][bf];
      ushort4v o;
      #pragma unroll
      for (int e = 0; e < 4; ++e)
        o[e] = f2bfbits(fmaxf(v[e] + bv4[e], 0.f));
      long coff = oPXW ? (long)((((cc[bf] + 1) & 1) * oPXW) + ((cc[bf] + 1) >> 1)) * oCS
                       : (long)cc[bf] * oCS;
      long oaddr = (long)(oh0 + rr[bf]) * oRS + coff + oCS * 0 + coB;
      *(ushort4v*)(outb + oaddr) = o;
    }
  }
}

// ---------- conv2 (64 -> 128, s2) with LDS-staged input, wave M64xN64
// Block: 128 threads = 2 waves (wave = co-half), one (img, output row oh).
// Phase f in {0,1}: stage act1p rows 2oh+2f, 2oh+2f+1 (2 contiguous parity
// rows, 2080 chunks) into LDS padded 8->9 chunks/pos; taps dy in {2f,2f+1}.
// Per (t,kc): 4 global A-frags + 4 ds_read B-frags -> 16 MFMA (4:1).
__global__ __launch_bounds__(128) void conv2_lds(
    const bf16* __restrict__ in, const bf16* __restrict__ wf,
    const float* __restrict__ bias, bf16* __restrict__ outp) {
  __shared__ short8 lds8[2 * 130 * 9];   // 37440 B
  const int lane = threadIdx.x & 63;
  const int h = threadIdx.x >> 6;        // co-half (wave id)
  const int ln = lane & 15, quad = lane >> 4;
  const int oh = blockIdx.x;             // output row 0..63
  const int b = blockIdx.z;

  const bf16* img = in + (long)b * 1081600;

  float4v acc[4][4];   // [j4 (co chunk)][bf (pos chunk)]
  #pragma unroll
  for (int j = 0; j < 4; ++j)
    #pragma unroll
    for (int bf = 0; bf < 4; ++bf) acc[j][bf] = {0.f, 0.f, 0.f, 0.f};

  #pragma unroll
  for (int f = 0; f < 2; ++f) {
    const short8* src8 = (const short8*)(img + (long)(2 * oh + 2 * f) * 8320);
    __syncthreads();
    for (int i = threadIdx.x; i < 2080; i += 128) {   // 2 rows x 130 pos x 8
      int pos2 = i >> 3, j = i & 7;                   // pos2 = r*130 + pos
      lds8[pos2 * 9 + j] = src8[i];
    }
    __syncthreads();
    #pragma unroll
    for (int tl = 0; tl < 8; ++tl) {
      const int t = 8 * f + tl;
      const int r = (t >> 2) & 1;        // row within phase
      const int dx = t & 3;
      const int pp = dx & 1, cb = dx >> 1;
      const int lbase = (r * 130 + pp * 65 + cb) * 9 + quad;
      const bf16* wt = wf + (long)(t * 4) * 2048 + (long)(2 * h) * 2048 +
                       ln * 32 + quad * 8;
      #pragma unroll
      for (int kc = 0; kc < 2; ++kc) {
        const bf16* wk = wt + kc * 1024;
        short8 a0 = *(const short8*)(wk);          // mc=2h,   j=0
        short8 a1 = *(const short8*)(wk + 512);    // mc=2h,   j=1
        short8 a2 = *(const short8*)(wk + 2048);   // mc=2h+1, j=0
        short8 a3 = *(const short8*)(wk + 2560);   // mc=2h+1, j=1
        #pragma unroll
        for (int bf = 0; bf < 4; ++bf) {
          short8 bv = lds8[lbase + (bf * 16 + ln) * 9 + kc * 4];
          acc[0][bf] = __builtin_amdgcn_mfma_f32_16x16x32_bf16(a0, bv, acc[0][bf], 0, 0, 0);
          acc[1][bf] = __builtin_amdgcn_mfma_f32_16x16x32_bf16(a1, bv, acc[1][bf], 0, 0, 0);
          acc[2][bf] = __builtin_amdgcn_mfma_f32_16x16x32_bf16(a2, bv, acc[2][bf], 0, 0, 0);
          acc[3][bf] = __builtin_amdgcn_mfma_f32_16x16x32_bf16(a3, bv, acc[3][bf], 0, 0, 0);
        }
      }
    }
  }

  // store: zbp parity layout, row oh+1, col map x -> ((x+1)&1)*33 + ((x+1)>>1)
  bf16* outb = outp + (long)b * 557568 + (long)(oh + 1) * 8448;
  #pragma unroll
  for (int j4 = 0; j4 < 4; ++j4) {
    int co = h * 64 + (j4 >> 1) * 32 + (j4 & 1) * 16 + quad * 4;
    float4v bv4 = *(const float4v*)(bias + co);
    #pragma unroll
    for (int bf = 0; bf < 4; ++bf) {
      int x = bf * 16 + ln;
      int col = (((x + 1) & 1) * 33) + ((x + 1) >> 1);
      float4v v = acc[j4][bf];
      ushort4v o;
      #pragma unroll
      for (int e = 0; e < 4; ++e)
        o[e] = f2bfbits(fmaxf(v[e] + bv4[e], 0.f));
      *(ushort4v*)(outb + (long)col * 128 + co) = o;
    }
  }
}

// ------ d1 (concat 256 -> 64) with LDS-staged input, 4 classes per block
__global__ __launch_bounds__(256) void mfma_d1_lds(
    const bf16* __restrict__ in1, const bf16* __restrict__ in2,
    const bf16* __restrict__ wf, const float* __restrict__ bias,
    bf16* __restrict__ outp) {
  __shared__ short8 lds8[198 * 17];   // 53856 B
  const int lane = threadIdx.x & 63, wv = threadIdx.x >> 6;
  const int ln = lane & 15, quad = lane >> 4;
  const int r = blockIdx.x;          // output class-row 0..63
  const int b = blockIdx.z;
  const int cls = wv, p = cls >> 1, q = cls & 1;

  const bf16* src1 = in1 + (long)b * 557568 + (long)r * 8448;  // rows r..r+2
  const bf16* src2 = in2 + (long)b * 557568 + (long)r * 8448;

  float4v acc[4][4];
  #pragma unroll
  for (int j = 0; j < 4; ++j)
    #pragma unroll
    for (int bf = 0; bf < 4; ++bf) acc[j][bf] = {0.f, 0.f, 0.f, 0.f};

  #pragma unroll
  for (int phase = 0; phase < 2; ++phase) {
    const bf16* src = phase ? src2 : src1;
    __syncthreads();
    for (int i = threadIdx.x; i < 3168; i += 256) {   // 198 pos x 16 chunks
      int pos = i >> 4, j = i & 15;
      lds8[pos * 17 + j] = *(const short8*)(src + (long)pos * 128 + j * 8);
    }
    __syncthreads();
    #pragma unroll
    for (int t = 0; t < 4; ++t) {
      int dy = p - (t >> 1) + 1, dx = q - (t & 1) + 1;
      const bf16* wt = wf + (long)(cls * 4 + t) * 16384 + (long)(phase * 4) * 2048 +
                       ln * 32 + quad * 8;
      const int lbase = (dy * 66 + dx) * 17 + quad;
      #pragma unroll
      for (int kc = 0; kc < 4; ++kc) {
        const bf16* wk = wt + kc * 2048;
        short8 a0 = *(const short8*)(wk);
        short8 a1 = *(const short8*)(wk + 512);
        short8 a2 = *(const short8*)(wk + 1024);
        short8 a3 = *(const short8*)(wk + 1536);
        #pragma unroll
        for (int bf = 0; bf < 4; ++bf) {
          short8 bv = lds8[lbase + kc * 4 + (bf * 16 + ln) * 17];
          acc[0][bf] = __builtin_amdgcn_mfma_f32_16x16x32_bf16(a0, bv, acc[0][bf], 0, 0, 0);
          acc[1][bf] = __builtin_amdgcn_mfma_f32_16x16x32_bf16(a1, bv, acc[1][bf], 0, 0, 0);
          acc[2][bf] = __builtin_amdgcn_mfma_f32_16x16x32_bf16(a2, bv, acc[2][bf], 0, 0, 0);
          acc[3][bf] = __builtin_amdgcn_mfma_f32_16x16x32_bf16(a3, bv, acc[3][bf], 0, 0, 0);
        }
      }
    }
  }

  bf16* outb = outp + (long)b * 1081600 + (long)(p + 1) * 8320 + (long)(q + 1) * 64 +
               (long)r * 16640;
  #pragma unroll
  for (int j = 0; j < 4; ++j) {
    int co = j * 16 + quad * 4;
    float4v bv4 = *(const float4v*)(bias + co);
    #pragma unroll
    for (int bf = 0; bf < 4; ++bf) {
      float4v v = acc[j][bf];
      ushort4v o;
      #pragma unroll
      for (int e = 0; e < 4; ++e)
        o[e] = f2bfbits(fmaxf(v[e] + bv4[e], 0.f));
      *(ushort4v*)(outb + (long)(bf * 16 + ln) * 128 + co) = o;
    }
  }
}

// ---------------------------------------------------- VQ via MFMA GEMM
__global__ __launch_bounds__(256) void vq_mfma(
    const bf16* __restrict__ z, long zImgS, int zRowS,
    const bf16* __restrict__ emb, const float* __restrict__ embsq,
    bf16* __restrict__ zq, long qImgS, int qRowS,
    float* __restrict__ loss_acc, int wb, int hwb, int ipxw) {
  const int lane = threadIdx.x & 63, wv = threadIdx.x >> 6;
  const int ln = lane & 15, quad = lane >> 4;
  const int base = blockIdx.x * 256 + wv * 64;

  short8 bfrag[4][4];
  #pragma unroll
  for (int bf = 0; bf < 4; ++bf) {
    int n = base + bf * 16 + ln;
    int b = n >> hwb;
    int rem = n & ((1 << hwb) - 1);
    int y = rem >> wb, x = rem & ((1 << wb) - 1);
    int xcol = ipxw ? ((((x + 1) & 1) * ipxw) + ((x + 1) >> 1)) : x;
    const bf16* zrow = z + (long)b * zImgS + (long)y * zRowS + (long)xcol * 128;
    #pragma unroll
    for (int kc = 0; kc < 4; ++kc)
      bfrag[bf][kc] = *(const short8*)(zrow + kc * 32 + quad * 8);
  }

  float best0 = 3.4e38f, best1 = 3.4e38f, best2 = 3.4e38f, best3 = 3.4e38f;
  int bk0 = 0, bk1 = 0, bk2 = 0, bk3 = 0;
  for (int ct = 0; ct < 32; ++ct) {
    const bf16* erow = emb + (long)(ct * 16 + ln) * 128 + quad * 8;
    short8 a0 = *(const short8*)(erow);
    short8 a1 = *(const short8*)(erow + 32);
    short8 a2 = *(const short8*)(erow + 64);
    short8 a3 = *(const short8*)(erow + 96);
    float4v sq4 = *(const float4v*)(embsq + ct * 16 + quad * 4);
    #pragma unroll
    for (int bf = 0; bf < 4; ++bf) {
      float4v acc = {0.f, 0.f, 0.f, 0.f};
      acc = __builtin_amdgcn_mfma_f32_16x16x32_bf16(a0, bfrag[bf][0], acc, 0, 0, 0);
      acc = __builtin_amdgcn_mfma_f32_16x16x32_bf16(a1, bfrag[bf][1], acc, 0, 0, 0);
      acc = __builtin_amdgcn_mfma_f32_16x16x32_bf16(a2, bfrag[bf][2], acc, 0, 0, 0);
      acc = __builtin_amdgcn_mfma_f32_16x16x32_bf16(a3, bfrag[bf][3], acc, 0, 0, 0);
      int kb = ct * 16 + quad * 4;
      #pragma unroll
      for (int r = 0; r < 4; ++r) {
        float s = fmaf(-2.f, acc[r], sq4[r]);
        if (bf == 0) { if (s < best0) { best0 = s; bk0 = kb + r; } }
        if (bf == 1) { if (s < best1) { best1 = s; bk1 = kb + r; } }
        if (bf == 2) { if (s < best2) { best2 = s; bk2 = kb + r; } }
        if (bf == 3) { if (s < best3) { best3 = s; bk3 = kb + r; } }
      }
    }
  }
  float bs[4] = {best0, best1, best2, best3};
  int bk[4] = {bk0, bk1, bk2, bk3};
  #pragma unroll
  for (int bf = 0; bf < 4; ++bf) {
    #pragma unroll
    for (int m = 16; m <= 32; m <<= 1) {
      float os = __shfl_xor(bs[bf], m, 64);
      int ok = __shfl_xor(bk[bf], m, 64);
      if (os < bs[bf] || (os == bs[bf] && ok < bk[bf])) { bs[bf] = os; bk[bf] = ok; }
    }
  }
  int myk = (quad == 0) ? bk[0] : (quad == 1) ? bk[1] : (quad == 2) ? bk[2] : bk[3];
  int n = base + quad * 16 + ln;
  int b = n >> hwb;
  int rem = n & ((1 << hwb) - 1);
  int y = rem >> wb, x = rem & ((1 << wb) - 1);
  int xcol = ipxw ? ((((x + 1) & 1) * ipxw) + ((x + 1) >> 1)) : x;
  const uint4* zr = (const uint4*)(z + (long)b * zImgS + (long)y * zRowS + (long)xcol * 128);
  uint4* qr = (uint4*)(zq + (long)b * qImgS + (long)y * qRowS + (long)x * 128);
  const uint4* er = (const uint4*)(emb + (long)myk * 128);
  float lsum = 0.f;
  #pragma unroll
  for (int j = 0; j < 16; ++j) {
    uint4 ue = er[j];
    uint4 uz = zr[j];
    qr[j] = ue;
    float ev[8], zv[8];
    unpack_u4(ue, ev);
    unpack_u4(uz, zv);
    #pragma unroll
    for (int e = 0; e < 8; ++e) {
      float dv = ev[e] - zv[e];
      lsum = fmaf(dv, dv, lsum);
    }
  }
  for (int o = 32; o > 0; o >>= 1) lsum += __shfl_down(lsum, o, 64);
  if (lane == 0) atomicAdd(loss_acc, lsum);
}

// --------------------- final convT(64->3)+sigmoid via class-packed MFMA
__global__ __launch_bounds__(256) void final_convt_mfma(
    const bf16* __restrict__ hp, const bf16* __restrict__ wfin,
    const float* __restrict__ bf_, float* __restrict__ out) {
  const int lane = threadIdx.x & 63, wv = threadIdx.x >> 6;
  const int ln = lane & 15, quad = lane >> 4;
  const int base = blockIdx.x * 256 + wv * 64;   // 262144 positions total

  short8 afr[18];
  #pragma unroll
  for (int kc = 0; kc < 18; ++kc)
    afr[kc] = *(const short8*)(wfin + ln * 576 + kc * 32 + quad * 8);

  float4v acc[4];
  #pragma unroll
  for (int bf = 0; bf < 4; ++bf) acc[bf] = {0.f, 0.f, 0.f, 0.f};

  #pragma unroll
  for (int bf = 0; bf < 4; ++bf) {
    int n = base + bf * 16 + ln;
    int xx = n & 127, y = (n >> 7) & 127, b = n >> 14;
    const bf16* hb = hp + (long)b * 1081600 + (long)y * 8320 + (long)xx * 64;
    #pragma unroll
    for (int kc = 0; kc < 18; ++kc) {
      int d = kc >> 1;
      const bf16* bp = hb + (long)(d / 3) * 8320 + (d % 3) * 64 + (kc & 1) * 32 + quad * 8;
      short8 bv = *(const short8*)bp;
      acc[bf] = __builtin_amdgcn_mfma_f32_16x16x32_bf16(afr[kc], bv, acc[bf], 0, 0, 0);
    }
  }

  const int p = quad >> 1, q = quad & 1;
  float b0 = bf_[0], b1 = bf_[1], b2 = bf_[2];
  #pragma unroll
  for (int bf = 0; bf < 4; ++bf) {
    int n = base + bf * 16 + ln;
    int xx = n & 127, y = (n >> 7) & 127, b = n >> 14;
    long ob = (long)b * 196608 + (long)(2 * y + p) * 256 + (2 * xx + q);
    float v0 = acc[bf][0] + b0, v1 = acc[bf][1] + b1, v2 = acc[bf][2] + b2;
    out[ob]          = 1.f / (1.f + expf(-v0));
    out[ob + 65536]  = 1.f / (1.f + expf(-v1));
    out[ob + 131072] = 1.f / (1.f + expf(-v2));
  }
}

__global__ void finalize_loss_kernel(const float* __restrict__ lacc, float* __restrict__ out) {
  if (threadIdx.x == 0) {
    float lt = lacc[0] * (1.5f / 2097152.f);
    float lb = lacc[1] * (1.5f / 8388608.f);
    *out = lt + lb;
  }
}

// ------------------------------------------------------------------ launch
extern "C" void kernel_launch(void* const* d_in, const int* in_sizes, int n_in,
                              void* d_out, int out_size, void* d_ws, size_t ws_size,
                              hipStream_t stream) {
  float* out = (float*)d_out;
  char* base = (char*)d_ws;
  size_t off = 0;
  auto alloc = [&](size_t bytes) {
    void* pp = base + off;
    off = (off + bytes + 255) & ~(size_t)255;
    return pp;
  };

  int* flag = (int*)alloc(256);
  float* biasAll = (float*)alloc(515 * 4);
  float* beB1f = biasAll + 0;
  float* beB2f = biasAll + 64;
  float* beTf  = biasAll + 192;
  float* bdTf  = biasAll + 320;
  float* bd1f  = biasAll + 448;
  float* bd2f  = biasAll + 512;
  float* sqAll = (float*)alloc(1024 * 4);
  float* sqT = sqAll, *sqB = sqAll + 512;
  float* lacc = (float*)alloc(2 * 4);
  bf16* Wc1  = (bf16*)alloc((size_t)4096 * 2);
  bf16* Wt2  = (bf16*)alloc((size_t)131072 * 2);
  bf16* Wtt  = (bf16*)alloc((size_t)262144 * 2);
  bf16* Wdt  = (bf16*)alloc((size_t)262144 * 2);
  bf16* Wt2f = (bf16*)alloc((size_t)131072 * 2);
  bf16* Wttf = (bf16*)alloc((size_t)262144 * 2);
  bf16* Wdtf = (bf16*)alloc((size_t)262144 * 2);
  bf16* Wd1f = (bf16*)alloc((size_t)262144 * 2);
  bf16* Wfin = (bf16*)alloc((size_t)9216 * 2);
  bf16* embTB = (bf16*)alloc((size_t)131072 * 2);
  bf16* embT = embTB, *embB = embTB + 65536;
  bf16* act1p = (bf16*)alloc((size_t)17305600 * 2);  // [16][130][2][65][64] parity
  bf16* zbp   = (bf16*)alloc((size_t)8921088 * 2);   // [16][66][2][33][128] parity
  bf16* zqtp  = (bf16*)alloc((size_t)2367488 * 2);   // [16][34][34][128]
  bf16* eup   = (bf16*)alloc((size_t)8921088 * 2);   // [16][66][66][128]
  bf16* fqp   = (bf16*)alloc((size_t)8921088 * 2);   // [16][66][66][128]
  bf16* hp    = (bf16*)alloc((size_t)17305600 * 2);  // [16][130][130][64]
  bf16* ztp   = (bf16*)alloc((size_t)2097152 * 2);   // [16][32][32][128]

  detect_dtype_kernel<<<1, 256, 0, stream>>>(d_in[0], flag);
  zero2_kernel<<<1, 64, 0, stream>>>(lacc);

  // halo-only zeroing (edge offsets identical in parity-split layout)
  zero_halo<<<517, 256, 0, stream>>>(act1p, hp, nullptr, 2, 130, 130, 8, 1081600, 16, 4128);
  zero_halo<<<781, 256, 0, stream>>>(zbp, eup, fqp, 3, 66, 66, 16, 557568, 16, 4160);
  zero_halo<<<132, 256, 0, stream>>>(zqtp, nullptr, nullptr, 1, 34, 34, 16, 147968, 16, 2112);

  // converts / repacks
  conv_bias_all<<<3, 256, 0, stream>>>(d_in[2], d_in[4], d_in[6], d_in[10],
                                       d_in[12], d_in[14], biasAll, flag);
  conv_emb<<<512, 256, 0, stream>>>(d_in[7], d_in[8], embTB, flag);
  embsq2<<<4, 256, 0, stream>>>(embTB, sqAll);
  rp_c1w<<<16, 256, 0, stream>>>(d_in[1], Wc1, flag);
  rp_conv_w<128, 64><<<512, 256, 0, stream>>>(d_in[3], Wt2, flag);
  rp_conv_w<128, 128><<<1024, 256, 0, stream>>>(d_in[5], Wtt, flag);
  rp_convt_w<128, 128><<<1024, 256, 0, stream>>>(d_in[9], Wdt, flag);
  rp_d1f<<<1024, 256, 0, stream>>>(d_in[11], Wd1f, flag);
  rp_finw<<<36, 256, 0, stream>>>(d_in[13], Wfin, flag);
  frag_pack<4, 2><<<512, 256, 0, stream>>>(Wt2, Wt2f, 131072);
  frag_pack<4, 4><<<1024, 256, 0, stream>>>(Wtt, Wttf, 262144);
  frag_pack<4, 4><<<1024, 256, 0, stream>>>(Wdt, Wdtf, 262144);

  // encoder: conv1 = fused im2col gather + MFMA GEMM (parity-split store)
  gemm1_fused<<<2048, 256, 0, stream>>>(d_in[0], flag, Wc1, beB1f, act1p);
  // conv2: LDS-staged, wave M64xN64, 1024 blocks x 128 threads
  conv2_lds<<<dim3(64, 1, 16), 128, 0, stream>>>(act1p, Wt2f, beB2f, zbp);
  // conv_t: PXW=33 (zbp parity), output ztp row-major
  mfma_conv<128, 128, 32, 2, 16, 128, 2, 33><<<dim3(16, 2, 16), 256, 0, stream>>>(
      zbp, zbp, 557568, 8448, Wttf, beTf, ztp, 131072, 4096, 128, 30, 0, 0, 0);

  // VQ top (16384 positions, row-major)
  vq_mfma<<<64, 256, 0, stream>>>(ztp, 131072, 4096, embT, sqT,
                                  zqtp + 4480, 147968, 4352, lacc + 0, 5, 10, 0);

  // decoder_top upsample: 4 classes in one launch (row-major in/out)
  mfma_conv<128, 128, 32, 1, 4, 128, 2, 0><<<dim3(64, 2, 16), 256, 0, stream>>>(
      zqtp, zqtp, 147968, 4352, Wdtf, bdTf, eup, 557568, 16896, 256, 4, 8448, 128, 0);

  // VQ bottom (65536 positions; zbp parity-split input, fqp row-major out)
  vq_mfma<<<256, 256, 0, stream>>>(zbp + 8448, 557568, 8448, embB, sqB,
                                   fqp + 8576, 557568, 8448, lacc + 1, 6, 12, 33);

  // decoder conv d1: LDS-staged, 4 classes per block, 1024 blocks
  mfma_d1_lds<<<dim3(64, 1, 16), 256, 0, stream>>>(fqp, eup, Wd1f, bd1f, hp);

  // final convT + sigmoid via MFMA -> fp32 NCHW output
  final_convt_mfma<<<1024, 256, 0, stream>>>(hp, Wfin, bd2f, out);
  finalize_loss_kernel<<<1, 64, 0, stream>>>(lacc, out + 3145728);
}

// Round 3
// 490.535 us; speedup vs baseline: 1.0498x; 1.0043x over previous
//
#include <hip/hip_runtime.h>
#include <hip/hip_bf16.h>
#include <cstddef>

typedef __hip_bfloat16 bf16;
typedef __attribute__((ext_vector_type(8))) short short8;
typedef __attribute__((ext_vector_type(4))) float float4v;
typedef __attribute__((ext_vector_type(4))) unsigned short ushort4v;

static __device__ __forceinline__ float b2f(bf16 v) { return __bfloat162float(v); }
static __device__ __forceinline__ float bits2f(unsigned int u) { return __uint_as_float(u); }
static __device__ __forceinline__ unsigned short f2bfbits(float f) {
  bf16 h = __float2bfloat16(f);
  return *reinterpret_cast<unsigned short*>(&h);
}
static __device__ __forceinline__ float ld_any(const void* p, long i, int flag) {
  return flag ? b2f(((const bf16*)p)[i]) : ((const float*)p)[i];
}
static __device__ __forceinline__ void unpack_u4(uint4 u, float* f) {
  f[0] = bits2f(u.x << 16); f[1] = bits2f(u.x & 0xffff0000u);
  f[2] = bits2f(u.y << 16); f[3] = bits2f(u.y & 0xffff0000u);
  f[4] = bits2f(u.z << 16); f[5] = bits2f(u.z & 0xffff0000u);
  f[6] = bits2f(u.w << 16); f[7] = bits2f(u.w & 0xffff0000u);
}

// --------------------------------- dtype detection (+ loss accumulator zero)
__global__ void detect_dtype_kernel(const void* __restrict__ x, int* __restrict__ flag,
                                    float* __restrict__ lacc) {
  if (threadIdx.x < 2) lacc[threadIdx.x] = 0.f;
  __shared__ int ok;
  if (threadIdx.x == 0) ok = 1;
  __syncthreads();
  float v = b2f(((const bf16*)x)[threadIdx.x]);
  if (!(v >= 0.f && v <= 1.0009765625f)) ok = 0;
  __syncthreads();
  if (threadIdx.x == 0) *flag = ok;
}

// ------------------------------------------------- fused halo-ring zeroing
// zero the 1-wide halo ring of padded NHWC buffers; r indexes (buf, img, elem)
static __device__ __forceinline__ void halo_seg(bf16* p0, bf16* p1, bf16* p2,
                                                int np, int H, int W, int C8,
                                                long imgS, int gpi, int r) {
  int total = 16 * gpi;
  int which = r / total;
  if (which >= np) return;
  int rr = r - which * total;
  int img = rr / gpi, g = rr % gpi;
  int pos = g / C8, c8 = g % C8;
  int row, col;
  if (pos < W) { row = 0; col = pos; }
  else if (pos < 2 * W) { row = H - 1; col = pos - W; }
  else { int s = pos - 2 * W; row = 1 + (s >> 1); col = (s & 1) ? (W - 1) : 0; }
  bf16* base = (which == 0) ? p0 : ((which == 1) ? p1 : p2);
  uint4* dst = (uint4*)(base + (long)img * imgS + ((long)row * W + col) * (C8 * 8) + (long)c8 * 8);
  *dst = uint4{0u, 0u, 0u, 0u};
}

__global__ __launch_bounds__(256) void zero_halo_all(bf16* act1p, bf16* hp,
                                                     bf16* zbp, bf16* eup, bf16* fqp,
                                                     bf16* zqtp) {
  int tid = blockIdx.x * 256 + threadIdx.x;
  if (tid < 132096) { halo_seg(act1p, hp, nullptr, 2, 130, 130, 8, 1081600, 4128, tid); return; }
  tid -= 132096;
  if (tid < 199680) { halo_seg(zbp, eup, fqp, 3, 66, 66, 16, 557568, 4160, tid); return; }
  tid -= 199680;
  if (tid < 33792)  { halo_seg(zqtp, nullptr, nullptr, 1, 34, 34, 16, 147968, 2112, tid); }
}

// ---------------- all converts / repacks fused into one kernel (segmented).
// Two-step repack chains (rp_conv_w/rp_convt_w -> frag_pack) are collapsed
// into direct one-pass index maps (kh = 2s+1-p, kw = 2t+1-q inverts the
// class decomposition).
__global__ __launch_bounds__(256) void setup_all(
    const void* s2, const void* s4, const void* s6,
    const void* s10, const void* s12, const void* s14,
    const void* sT, const void* sB, const void* c1s,
    const void* fins, const void* d1s, const void* t2s,
    const void* tts, const void* dts,
    float* __restrict__ biasAll, bf16* __restrict__ embTB,
    float* __restrict__ sqAll, bf16* __restrict__ Wc1,
    bf16* __restrict__ Wfin, bf16* __restrict__ Wd1f,
    bf16* __restrict__ Wt2f, bf16* __restrict__ Wttf,
    bf16* __restrict__ Wdtf, const int* __restrict__ flag) {
  long i = (long)blockIdx.x * 256 + threadIdx.x;
  const int fl = *flag;
  // seg0: 6 conv biases -> one fp32 buffer [515]
  if (i < 515) {
    const void* s; long off;
    if (i < 64)       { s = s2;  off = i; }
    else if (i < 192) { s = s4;  off = i - 64; }
    else if (i < 320) { s = s6;  off = i - 192; }
    else if (i < 448) { s = s10; off = i - 320; }
    else if (i < 512) { s = s12; off = i - 448; }
    else              { s = s14; off = i - 512; }
    biasAll[i] = ld_any(s, off, fl);
    return;
  }
  i -= 515;
  // seg1: both codebooks -> contiguous bf16 [1024][128]
  if (i < 131072) {
    const void* s = (i < 65536) ? sT : sB;
    long off = i & 65535;
    embTB[i] = fl ? ((const bf16*)s)[off] : __float2bfloat16(((const float*)s)[off]);
    return;
  }
  i -= 131072;
  // seg2: emb row sum-of-squares from RAW src through identical bf16 rounding
  if (i < 1024) {
    const void* s = (i < 512) ? sT : sB;
    long base = (i & 511) * 128;
    float acc = 0.f;
    for (int c = 0; c < 128; ++c) {
      float v = b2f(__float2bfloat16(ld_any(s, base + c, fl)));
      acc = fmaf(v, v, acc);
    }
    sqAll[i] = acc;
    return;
  }
  i -= 1024;
  // seg3: conv1 weights [64][3][4][4] -> [co][k], K padded 48->64 [4096]
  if (i < 4096) {
    int co = (int)i >> 6, k = (int)i & 63;
    float v = (k < 48) ? ld_any(c1s, co * 48 + k, fl) : 0.f;
    Wc1[i] = __float2bfloat16(v);
    return;
  }
  i -= 4096;
  // seg4: final convT weights -> A[m=cls*4+co][d=dy*3+dx][64ci] [9216]
  if (i < 9216) {
    int m = (int)i / 576, rem = (int)i % 576;
    int d = rem >> 6, ci = rem & 63;
    int cls = m >> 2, co = m & 3;
    int p = cls >> 1, q = cls & 1;
    int dy = d / 3, dx = d % 3;
    int s_ = p - dy + 1, t_ = q - dx + 1;
    float v = 0.f;
    if (co < 3 && s_ >= 0 && s_ <= 1 && t_ >= 0 && t_ <= 1) {
      int kh = 2 * s_ + 1 - p, kw = 2 * t_ + 1 - q;
      v = ld_any(fins, ci * 48 + co * 16 + kh * 4 + kw, fl);
    }
    Wfin[i] = __float2bfloat16(v);
    return;
  }
  i -= 9216;
  // seg5: d1 weights [256ci][64co][4][4] -> frag [262144]
  if (i < 262144) {
    int low = (int)i & 511;
    int ln = low >> 5, cl = low & 31;
    int c2 = (int)(i >> 9);
    int j = c2 & 3;
    int kc = (c2 >> 2) & 7;
    int t = (c2 >> 5) & 3;
    int cls = c2 >> 7;
    int p = cls >> 1, q = cls & 1;
    int s_ = t >> 1, t2 = t & 1;
    int kh = 2 * s_ + 1 - p, kw = 2 * t2 + 1 - q;
    int co = j * 16 + ln, ci = kc * 32 + cl;
    Wd1f[i] = __float2bfloat16(ld_any(d1s, (long)ci * 1024 + co * 16 + kh * 4 + kw, fl));
    return;
  }
  i -= 262144;
  // seg6: conv2 weights OIHW[128][64][4][4] -> frag direct (MC=4,KC=2) [131072]
  if (i < 131072) {
    int low = (int)i & 511;
    int ln = low >> 5, cl = low & 31;
    int c2 = (int)(i >> 9);
    int j = c2 & 1, c3 = c2 >> 1;
    int kc = c3 & 1, c4 = c3 >> 1;
    int mc = c4 & 3, tg = c4 >> 2;
    int co = mc * 32 + j * 16 + ln, ci = kc * 32 + cl;
    Wt2f[i] = __float2bfloat16(ld_any(t2s, (long)co * 1024 + ci * 16 + tg, fl));
    return;
  }
  i -= 131072;
  // seg7: conv_t weights OIHW[128][128][4][4] -> frag direct (MC=4,KC=4) [262144]
  if (i < 262144) {
    int low = (int)i & 511;
    int ln = low >> 5, cl = low & 31;
    int c2 = (int)(i >> 9);
    int j = c2 & 1, c3 = c2 >> 1;
    int kc = c3 & 3, c4 = c3 >> 2;
    int mc = c4 & 3, tg = c4 >> 2;
    int co = mc * 32 + j * 16 + ln, ci = kc * 32 + cl;
    Wttf[i] = __float2bfloat16(ld_any(tts, (long)co * 2048 + ci * 16 + tg, fl));
    return;
  }
  i -= 262144;
  // seg8: convT dt weights [128ci][128co][4][4] -> class frag direct [262144]
  if (i < 262144) {
    int low = (int)i & 511;
    int ln = low >> 5, cl = low & 31;
    int c2 = (int)(i >> 9);
    int j = c2 & 1, c3 = c2 >> 1;
    int kc = c3 & 3, c4 = c3 >> 2;
    int mc = c4 & 3, tg = c4 >> 2;
    int co = mc * 32 + j * 16 + ln, ci = kc * 32 + cl;
    int cls = tg >> 2, st = tg & 3;
    int p = cls >> 1, q = cls & 1;
    int s_ = st >> 1, tt_ = st & 1;
    int kh = 2 * s_ + 1 - p, kw = 2 * tt_ + 1 - q;
    Wdtf[i] = __float2bfloat16(ld_any(dts, (long)ci * 2048 + co * 16 + kh * 4 + kw, fl));
    return;
  }
}

// -------------------- conv1 fused: inline im2col gather + MFMA GEMM
// M=64 (co), K=64 (48 real + 16 pad), N=262144; bias+relu; parity-split store.
__global__ __launch_bounds__(256) void gemm1_fused(
    const void* __restrict__ x, const int* __restrict__ flag,
    const bf16* __restrict__ w, const float* __restrict__ bias,
    bf16* __restrict__ act1p) {
  const int lane = threadIdx.x & 63, wv = threadIdx.x >> 6;
  const int wm = wv & 1, wn = wv >> 1;
  const int ln = lane & 15, quad = lane >> 4;
  const int n0 = blockIdx.x * 128 + wn * 64;
  const int fl = *flag;
  float4v acc[2][4];
  #pragma unroll
  for (int i = 0; i < 2; ++i)
    #pragma unroll
    for (int j = 0; j < 4; ++j) acc[i][j] = {0.f, 0.f, 0.f, 0.f};
  #pragma unroll
  for (int kc = 0; kc < 2; ++kc) {
    const bf16* wk = w + (wm * 32 + ln) * 64 + kc * 32 + quad * 8;
    short8 a0 = *(const short8*)(wk);
    short8 a1 = *(const short8*)(wk + 16 * 64);
    const int k0 = kc * 32 + quad * 8;      // 0,8,...,56; >=48 is zero-pad
    #pragma unroll
    for (int bf = 0; bf < 4; ++bf) {
      short8 bv;
      if (k0 >= 48) {
        bv = (short8){0, 0, 0, 0, 0, 0, 0, 0};
      } else {
        int n = n0 + bf * 16 + ln;
        int ow = n & 127, oh = (n >> 7) & 127, b = n >> 14;
        int ci = k0 >> 4;
        int kh0 = (k0 & 15) >> 2;           // 0 or 2
        long pbase = ((long)(b * 3 + ci)) << 16;
        int iw0 = ow * 2 - 1;
        unsigned short tmp[8];
        #pragma unroll
        for (int r = 0; r < 2; ++r) {
          int ih = oh * 2 - 1 + kh0 + r;
          bool okh = (unsigned)ih < 256u;
          long rbase = pbase + ((long)ih << 8);
          #pragma unroll
          for (int c = 0; c < 4; ++c) {
            int iw = iw0 + c;
            float v = (okh && (unsigned)iw < 256u) ? ld_any(x, rbase + iw, fl) : 0.f;
            tmp[r * 4 + c] = f2bfbits(v);
          }
        }
        bv = *(const short8*)tmp;
      }
      acc[0][bf] = __builtin_amdgcn_mfma_f32_16x16x32_bf16(a0, bv, acc[0][bf], 0, 0, 0);
      acc[1][bf] = __builtin_amdgcn_mfma_f32_16x16x32_bf16(a1, bv, acc[1][bf], 0, 0, 0);
    }
  }
  #pragma unroll
  for (int mf = 0; mf < 2; ++mf) {
    int coB = wm * 32 + mf * 16 + quad * 4;
    float4v bv4 = *(const float4v*)(bias + coB);
    #pragma unroll
    for (int bf = 0; bf < 4; ++bf) {
      int n = n0 + bf * 16 + ln;
      int ow = n & 127; int t2 = n >> 7;
      int oh = t2 & 127; int b = t2 >> 7;
      int xx = ow + 1;   // parity-split column
      long oaddr = ((long)(b * 130 + oh + 1)) * 8320 +
                   (long)(((xx & 1) * 65) + (xx >> 1)) * 64 + coB;
      float4v v = acc[mf][bf];
      ushort4v o;
      #pragma unroll
      for (int e = 0; e < 4; ++e) o[e] = f2bfbits(fmaxf(v[e] + bv4[e], 0.f));
      *(ushort4v*)(act1p + oaddr) = o;
    }
  }
}

// ------------------------------------------- MFMA implicit-GEMM tap conv
template <int COUT, int CINT, int TC, int S, int NT, int INC, int NBF, int PXW>
__global__ __launch_bounds__(256) void mfma_conv(
    const bf16* __restrict__ in1, const bf16* __restrict__ in2,
    long inImgS, int inRowS,
    const bf16* __restrict__ wf, const float* __restrict__ bias,
    bf16* __restrict__ outp, long outImgS, int oRS, int oCS,
    int nxb, long po, long qo, int oPXW) {
  constexpr int TR = (2 * NBF * 16) / TC;
  constexpr int KC = CINT / 32;
  constexpr int MC = COUT / 32;
  constexpr int KSPLIT = (CINT > INC) ? (INC / 32) : KC;
  const int lane = threadIdx.x & 63;
  const int wv = threadIdx.x >> 6;
  const int wm = wv & 1, wn = wv >> 1;
  const int ln = lane & 15, quad = lane >> 4;
  const int cls = blockIdx.x >> nxb;
  const int xb = blockIdx.x & ((1u << nxb) - 1u);
  const int mTile = blockIdx.y * 64;
  const int mc = blockIdx.y * 2 + wm;
  const int oh0 = xb * TR;
  const int b = blockIdx.z;
  const int p = cls >> 1, q = cls & 1;
  const long ooff = (long)(p + 1) * po + (long)(q + 1) * qo;

  long posOff[NBF];
  int rr[NBF], cc[NBF];
  #pragma unroll
  for (int bf = 0; bf < NBF; ++bf) {
    int n = wn * (NBF * 16) + bf * 16 + ln;
    int r = n / TC, c = n % TC;
    rr[bf] = r; cc[bf] = c;
    posOff[bf] = (long)(S * (oh0 + r)) * inRowS +
                 (PXW ? (long)c * INC : (long)(S * c) * INC);
  }
  const bf16* inb1 = in1 + (long)b * inImgS;
  const bf16* inb2 = in2 + (long)b * inImgS;

  float4v acc[2][NBF];
  #pragma unroll
  for (int i = 0; i < 2; ++i)
    #pragma unroll
    for (int j = 0; j < NBF; ++j) acc[i][j] = {0.f, 0.f, 0.f, 0.f};

  for (int t = 0; t < NT; ++t) {
    int dy, dx;
    if (S == 2) { dy = t >> 2; dx = t & 3; }
    else        { dy = p - (t >> 1) + 1; dx = q - (t & 1) + 1; }
    const int dxo = PXW ? ((dx & 1) * PXW + (dx >> 1)) : dx;
    const long tapOff = (long)dy * inRowS + (long)dxo * INC;
    const bf16* wt = wf + ((long)(cls * NT + t) * MC + mc) * (KC * 1024) + ln * 32 + quad * 8;
    #pragma unroll
    for (int kc = 0; kc < KC; ++kc) {
      short8 a0 = *(const short8*)(wt + kc * 1024);
      short8 a1 = *(const short8*)(wt + kc * 1024 + 512);
      const bf16* bp = (kc < KSPLIT) ? inb1 : inb2;
      int kOff = (kc < KSPLIT ? kc : kc - KSPLIT) * 32 + quad * 8;
      #pragma unroll
      for (int bf = 0; bf < NBF; ++bf) {
        short8 bv = *(const short8*)(bp + posOff[bf] + tapOff + kOff);
        acc[0][bf] = __builtin_amdgcn_mfma_f32_16x16x32_bf16(a0, bv, acc[0][bf], 0, 0, 0);
        acc[1][bf] = __builtin_amdgcn_mfma_f32_16x16x32_bf16(a1, bv, acc[1][bf], 0, 0, 0);
      }
    }
  }

  bf16* outb = outp + (long)b * outImgS + ooff;
  #pragma unroll
  for (int mf = 0; mf < 2; ++mf) {
    int coB = mTile + wm * 32 + mf * 16 + quad * 4;
    float4v bv4 = *(const float4v*)(bias + coB);
    #pragma unroll
    for (int bf = 0; bf < NBF; ++bf) {
      float4v v = acc[mf][bf];
      ushort4v o;
      #pragma unroll
      for (int e = 0; e < 4; ++e)
        o[e] = f2bfbits(fmaxf(v[e] + bv4[e], 0.f));
      long coff = oPXW ? (long)((((cc[bf] + 1) & 1) * oPXW) + ((cc[bf] + 1) >> 1)) * oCS
                       : (long)cc[bf] * oCS;
      long oaddr = (long)(oh0 + rr[bf]) * oRS + coff + oCS * 0 + coB;
      *(ushort4v*)(outb + oaddr) = o;
    }
  }
}

// ---------- conv2 (64 -> 128, s2) with LDS-staged input, wave M64xN64
__global__ __launch_bounds__(128) void conv2_lds(
    const bf16* __restrict__ in, const bf16* __restrict__ wf,
    const float* __restrict__ bias, bf16* __restrict__ outp) {
  __shared__ short8 lds8[2 * 130 * 9];   // 37440 B
  const int lane = threadIdx.x & 63;
  const int h = threadIdx.x >> 6;        // co-half (wave id)
  const int ln = lane & 15, quad = lane >> 4;
  const int oh = blockIdx.x;             // output row 0..63
  const int b = blockIdx.z;

  const bf16* img = in + (long)b * 1081600;

  float4v acc[4][4];   // [j4 (co chunk)][bf (pos chunk)]
  #pragma unroll
  for (int j = 0; j < 4; ++j)
    #pragma unroll
    for (int bf = 0; bf < 4; ++bf) acc[j][bf] = {0.f, 0.f, 0.f, 0.f};

  #pragma unroll
  for (int f = 0; f < 2; ++f) {
    const short8* src8 = (const short8*)(img + (long)(2 * oh + 2 * f) * 8320);
    __syncthreads();
    for (int i = threadIdx.x; i < 2080; i += 128) {   // 2 rows x 130 pos x 8
      int pos2 = i >> 3, j = i & 7;                   // pos2 = r*130 + pos
      lds8[pos2 * 9 + j] = src8[i];
    }
    __syncthreads();
    #pragma unroll
    for (int tl = 0; tl < 8; ++tl) {
      const int t = 8 * f + tl;
      const int r = (t >> 2) & 1;        // row within phase
      const int dx = t & 3;
      const int pp = dx & 1, cb = dx >> 1;
      const int lbase = (r * 130 + pp * 65 + cb) * 9 + quad;
      const bf16* wt = wf + (long)(t * 4) * 2048 + (long)(2 * h) * 2048 +
                       ln * 32 + quad * 8;
      #pragma unroll
      for (int kc = 0; kc < 2; ++kc) {
        const bf16* wk = wt + kc * 1024;
        short8 a0 = *(const short8*)(wk);          // mc=2h,   j=0
        short8 a1 = *(const short8*)(wk + 512);    // mc=2h,   j=1
        short8 a2 = *(const short8*)(wk + 2048);   // mc=2h+1, j=0
        short8 a3 = *(const short8*)(wk + 2560);   // mc=2h+1, j=1
        #pragma unroll
        for (int bf = 0; bf < 4; ++bf) {
          short8 bv = lds8[lbase + (bf * 16 + ln) * 9 + kc * 4];
          acc[0][bf] = __builtin_amdgcn_mfma_f32_16x16x32_bf16(a0, bv, acc[0][bf], 0, 0, 0);
          acc[1][bf] = __builtin_amdgcn_mfma_f32_16x16x32_bf16(a1, bv, acc[1][bf], 0, 0, 0);
          acc[2][bf] = __builtin_amdgcn_mfma_f32_16x16x32_bf16(a2, bv, acc[2][bf], 0, 0, 0);
          acc[3][bf] = __builtin_amdgcn_mfma_f32_16x16x32_bf16(a3, bv, acc[3][bf], 0, 0, 0);
        }
      }
    }
  }

  // store: zbp parity layout, row oh+1, col map x -> ((x+1)&1)*33 + ((x+1)>>1)
  bf16* outb = outp + (long)b * 557568 + (long)(oh + 1) * 8448;
  #pragma unroll
  for (int j4 = 0; j4 < 4; ++j4) {
    int co = h * 64 + (j4 >> 1) * 32 + (j4 & 1) * 16 + quad * 4;
    float4v bv4 = *(const float4v*)(bias + co);
    #pragma unroll
    for (int bf = 0; bf < 4; ++bf) {
      int x = bf * 16 + ln;
      int col = (((x + 1) & 1) * 33) + ((x + 1) >> 1);
      float4v v = acc[j4][bf];
      ushort4v o;
      #pragma unroll
      for (int e = 0; e < 4; ++e)
        o[e] = f2bfbits(fmaxf(v[e] + bv4[e], 0.f));
      *(ushort4v*)(outb + (long)col * 128 + co) = o;
    }
  }
}

// ------ d1 (concat 256 -> 64): LDS-staged (reg-staged stores, 17-stride pad),
// 4 classes per block, TWO output class-rows per block (r0 = 2*bx, r0+1).
// Stages 4 input rows/phase (vs 3 for 1-row blocks): halves per-output weight
// L2 traffic (A-frags reused across both rows), stage re-read 3x -> 2x.
__global__ __launch_bounds__(256) void mfma_d1_lds(
    const bf16* __restrict__ in1, const bf16* __restrict__ in2,
    const bf16* __restrict__ wf, const float* __restrict__ bias,
    bf16* __restrict__ outp) {
  __shared__ short8 lds8[264 * 17];   // 4 rows x 66 pos x 16 chunks, pad 17 -> 71808 B
  const int lane = threadIdx.x & 63, wv = threadIdx.x >> 6;
  const int ln = lane & 15, quad = lane >> 4;
  const int r0 = blockIdx.x * 2;     // output class-rows r0, r0+1
  const int b = blockIdx.z;
  const int cls = wv, p = cls >> 1, q = cls & 1;

  const bf16* src1 = in1 + (long)b * 557568 + (long)r0 * 8448;  // rows r0..r0+3
  const bf16* src2 = in2 + (long)b * 557568 + (long)r0 * 8448;

  float4v acc[2][4][4];
  #pragma unroll
  for (int rr = 0; rr < 2; ++rr)
    #pragma unroll
    for (int j = 0; j < 4; ++j)
      #pragma unroll
      for (int bf = 0; bf < 4; ++bf) acc[rr][j][bf] = {0.f, 0.f, 0.f, 0.f};

  #pragma unroll
  for (int phase = 0; phase < 2; ++phase) {
    const bf16* src = phase ? src2 : src1;
    __syncthreads();
    for (int i = threadIdx.x; i < 4224; i += 256) {   // 4 rows x 66 pos x 16 chunks
      int pos = i >> 4, j = i & 15;
      lds8[pos * 17 + j] = *(const short8*)(src + (long)pos * 128 + j * 8);
    }
    __syncthreads();
    #pragma unroll
    for (int t = 0; t < 4; ++t) {
      int dy = p - (t >> 1) + 1, dx = q - (t & 1) + 1;
      const bf16* wt = wf + (long)(cls * 4 + t) * 16384 + (long)(phase * 4) * 2048 +
                       ln * 32 + quad * 8;
      #pragma unroll
      for (int kc = 0; kc < 4; ++kc) {
        const bf16* wk = wt + kc * 2048;
        short8 a0 = *(const short8*)(wk);
        short8 a1 = *(const short8*)(wk + 512);
        short8 a2 = *(const short8*)(wk + 1024);
        short8 a3 = *(const short8*)(wk + 1536);
        #pragma unroll
        for (int rr = 0; rr < 2; ++rr) {
          const int lbase = ((rr + dy) * 66 + dx) * 17 + quad;
          #pragma unroll
          for (int bf = 0; bf < 4; ++bf) {
            short8 bv = lds8[lbase + kc * 4 + (bf * 16 + ln) * 17];
            acc[rr][0][bf] = __builtin_amdgcn_mfma_f32_16x16x32_bf16(a0, bv, acc[rr][0][bf], 0, 0, 0);
            acc[rr][1][bf] = __builtin_amdgcn_mfma_f32_16x16x32_bf16(a1, bv, acc[rr][1][bf], 0, 0, 0);
            acc[rr][2][bf] = __builtin_amdgcn_mfma_f32_16x16x32_bf16(a2, bv, acc[rr][2][bf], 0, 0, 0);
            acc[rr][3][bf] = __builtin_amdgcn_mfma_f32_16x16x32_bf16(a3, bv, acc[rr][3][bf], 0, 0, 0);
          }
        }
      }
    }
  }

  #pragma unroll
  for (int rr = 0; rr < 2; ++rr) {
    bf16* outb = outp + (long)b * 1081600 + (long)(p + 1) * 8320 + (long)(q + 1) * 64 +
                 (long)(r0 + rr) * 16640;
    #pragma unroll
    for (int j = 0; j < 4; ++j) {
      int co = j * 16 + quad * 4;
      float4v bv4 = *(const float4v*)(bias + co);
      #pragma unroll
      for (int bf = 0; bf < 4; ++bf) {
        float4v v = acc[rr][j][bf];
        ushort4v o;
        #pragma unroll
        for (int e = 0; e < 4; ++e)
          o[e] = f2bfbits(fmaxf(v[e] + bv4[e], 0.f));
        *(ushort4v*)(outb + (long)(bf * 16 + ln) * 128 + co) = o;
      }
    }
  }
}

// ---------------------------------------------------- VQ via MFMA GEMM
__global__ __launch_bounds__(256) void vq_mfma(
    const bf16* __restrict__ z, long zImgS, int zRowS,
    const bf16* __restrict__ emb, const float* __restrict__ embsq,
    bf16* __restrict__ zq, long qImgS, int qRowS,
    float* __restrict__ loss_acc, int wb, int hwb, int ipxw) {
  const int lane = threadIdx.x & 63, wv = threadIdx.x >> 6;
  const int ln = lane & 15, quad = lane >> 4;
  const int base = blockIdx.x * 256 + wv * 64;

  short8 bfrag[4][4];
  #pragma unroll
  for (int bf = 0; bf < 4; ++bf) {
    int n = base + bf * 16 + ln;
    int b = n >> hwb;
    int rem = n & ((1 << hwb) - 1);
    int y = rem >> wb, x = rem & ((1 << wb) - 1);
    int xcol = ipxw ? ((((x + 1) & 1) * ipxw) + ((x + 1) >> 1)) : x;
    const bf16* zrow = z + (long)b * zImgS + (long)y * zRowS + (long)xcol * 128;
    #pragma unroll
    for (int kc = 0; kc < 4; ++kc)
      bfrag[bf][kc] = *(const short8*)(zrow + kc * 32 + quad * 8);
  }

  float best0 = 3.4e38f, best1 = 3.4e38f, best2 = 3.4e38f, best3 = 3.4e38f;
  int bk0 = 0, bk1 = 0, bk2 = 0, bk3 = 0;
  for (int ct = 0; ct < 32; ++ct) {
    const bf16* erow = emb + (long)(ct * 16 + ln) * 128 + quad * 8;
    short8 a0 = *(const short8*)(erow);
    short8 a1 = *(const short8*)(erow + 32);
    short8 a2 = *(const short8*)(erow + 64);
    short8 a3 = *(const short8*)(erow + 96);
    float4v sq4 = *(const float4v*)(embsq + ct * 16 + quad * 4);
    #pragma unroll
    for (int bf = 0; bf < 4; ++bf) {
      float4v acc = {0.f, 0.f, 0.f, 0.f};
      acc = __builtin_amdgcn_mfma_f32_16x16x32_bf16(a0, bfrag[bf][0], acc, 0, 0, 0);
      acc = __builtin_amdgcn_mfma_f32_16x16x32_bf16(a1, bfrag[bf][1], acc, 0, 0, 0);
      acc = __builtin_amdgcn_mfma_f32_16x16x32_bf16(a2, bfrag[bf][2], acc, 0, 0, 0);
      acc = __builtin_amdgcn_mfma_f32_16x16x32_bf16(a3, bfrag[bf][3], acc, 0, 0, 0);
      int kb = ct * 16 + quad * 4;
      #pragma unroll
      for (int r = 0; r < 4; ++r) {
        float s = fmaf(-2.f, acc[r], sq4[r]);
        if (bf == 0) { if (s < best0) { best0 = s; bk0 = kb + r; } }
        if (bf == 1) { if (s < best1) { best1 = s; bk1 = kb + r; } }
        if (bf == 2) { if (s < best2) { best2 = s; bk2 = kb + r; } }
        if (bf == 3) { if (s < best3) { best3 = s; bk3 = kb + r; } }
      }
    }
  }
  float bs[4] = {best0, best1, best2, best3};
  int bk[4] = {bk0, bk1, bk2, bk3};
  #pragma unroll
  for (int bf = 0; bf < 4; ++bf) {
    #pragma unroll
    for (int m = 16; m <= 32; m <<= 1) {
      float os = __shfl_xor(bs[bf], m, 64);
      int ok = __shfl_xor(bk[bf], m, 64);
      if (os < bs[bf] || (os == bs[bf] && ok < bk[bf])) { bs[bf] = os; bk[bf] = ok; }
    }
  }
  int myk = (quad == 0) ? bk[0] : (quad == 1) ? bk[1] : (quad == 2) ? bk[2] : bk[3];
  int n = base + quad * 16 + ln;
  int b = n >> hwb;
  int rem = n & ((1 << hwb) - 1);
  int y = rem >> wb, x = rem & ((1 << wb) - 1);
  int xcol = ipxw ? ((((x + 1) & 1) * ipxw) + ((x + 1) >> 1)) : x;
  const uint4* zr = (const uint4*)(z + (long)b * zImgS + (long)y * zRowS + (long)xcol * 128);
  uint4* qr = (uint4*)(zq + (long)b * qImgS + (long)y * qRowS + (long)x * 128);
  const uint4* er = (const uint4*)(emb + (long)myk * 128);
  float lsum = 0.f;
  #pragma unroll
  for (int j = 0; j < 16; ++j) {
    uint4 ue = er[j];
    uint4 uz = zr[j];
    qr[j] = ue;
    float ev[8], zv[8];
    unpack_u4(ue, ev);
    unpack_u4(uz, zv);
    #pragma unroll
    for (int e = 0; e < 8; ++e) {
      float dv = ev[e] - zv[e];
      lsum = fmaf(dv, dv, lsum);
    }
  }
  for (int o = 32; o > 0; o >>= 1) lsum += __shfl_down(lsum, o, 64);
  if (lane == 0) atomicAdd(loss_acc, lsum);
}

// --------------------- final convT(64->3)+sigmoid via class-packed MFMA
__global__ __launch_bounds__(256) void final_convt_mfma(
    const bf16* __restrict__ hp, const bf16* __restrict__ wfin,
    const float* __restrict__ bf_, float* __restrict__ out) {
  const int lane = threadIdx.x & 63, wv = threadIdx.x >> 6;
  const int ln = lane & 15, quad = lane >> 4;
  const int base = blockIdx.x * 256 + wv * 64;   // 262144 positions total

  short8 afr[18];
  #pragma unroll
  for (int kc = 0; kc < 18; ++kc)
    afr[kc] = *(const short8*)(wfin + ln * 576 + kc * 32 + quad * 8);

  float4v acc[4];
  #pragma unroll
  for (int bf = 0; bf < 4; ++bf) acc[bf] = {0.f, 0.f, 0.f, 0.f};

  #pragma unroll
  for (int bf = 0; bf < 4; ++bf) {
    int n = base + bf * 16 + ln;
    int xx = n & 127, y = (n >> 7) & 127, b = n >> 14;
    const bf16* hb = hp + (long)b * 1081600 + (long)y * 8320 + (long)xx * 64;
    #pragma unroll
    for (int kc = 0; kc < 18; ++kc) {
      int d = kc >> 1;
      const bf16* bp = hb + (long)(d / 3) * 8320 + (d % 3) * 64 + (kc & 1) * 32 + quad * 8;
      short8 bv = *(const short8*)bp;
      acc[bf] = __builtin_amdgcn_mfma_f32_16x16x32_bf16(afr[kc], bv, acc[bf], 0, 0, 0);
    }
  }

  const int p = quad >> 1, q = quad & 1;
  float b0 = bf_[0], b1 = bf_[1], b2 = bf_[2];
  #pragma unroll
  for (int bf = 0; bf < 4; ++bf) {
    int n = base + bf * 16 + ln;
    int xx = n & 127, y = (n >> 7) & 127, b = n >> 14;
    long ob = (long)b * 196608 + (long)(2 * y + p) * 256 + (2 * xx + q);
    float v0 = acc[bf][0] + b0, v1 = acc[bf][1] + b1, v2 = acc[bf][2] + b2;
    out[ob]          = 1.f / (1.f + expf(-v0));
    out[ob + 65536]  = 1.f / (1.f + expf(-v1));
    out[ob + 131072] = 1.f / (1.f + expf(-v2));
  }
}

__global__ void finalize_loss_kernel(const float* __restrict__ lacc, float* __restrict__ out) {
  if (threadIdx.x == 0) {
    float lt = lacc[0] * (1.5f / 2097152.f);
    float lb = lacc[1] * (1.5f / 8388608.f);
    *out = lt + lb;
  }
}

// ------------------------------------------------------------------ launch
extern "C" void kernel_launch(void* const* d_in, const int* in_sizes, int n_in,
                              void* d_out, int out_size, void* d_ws, size_t ws_size,
                              hipStream_t stream) {
  float* out = (float*)d_out;
  char* base = (char*)d_ws;
  size_t off = 0;
  auto alloc = [&](size_t bytes) {
    void* pp = base + off;
    off = (off + bytes + 255) & ~(size_t)255;
    return pp;
  };

  int* flag = (int*)alloc(256);
  float* biasAll = (float*)alloc(515 * 4);
  float* beB1f = biasAll + 0;
  float* beB2f = biasAll + 64;
  float* beTf  = biasAll + 192;
  float* bdTf  = biasAll + 320;
  float* bd1f  = biasAll + 448;
  float* bd2f  = biasAll + 512;
  float* sqAll = (float*)alloc(1024 * 4);
  float* sqT = sqAll, *sqB = sqAll + 512;
  float* lacc = (float*)alloc(2 * 4);
  bf16* Wc1  = (bf16*)alloc((size_t)4096 * 2);
  bf16* Wt2f = (bf16*)alloc((size_t)131072 * 2);
  bf16* Wttf = (bf16*)alloc((size_t)262144 * 2);
  bf16* Wdtf = (bf16*)alloc((size_t)262144 * 2);
  bf16* Wd1f = (bf16*)alloc((size_t)262144 * 2);
  bf16* Wfin = (bf16*)alloc((size_t)9216 * 2);
  bf16* embTB = (bf16*)alloc((size_t)131072 * 2);
  bf16* embT = embTB, *embB = embTB + 65536;
  bf16* act1p = (bf16*)alloc((size_t)17305600 * 2);  // [16][130][2][65][64] parity
  bf16* zbp   = (bf16*)alloc((size_t)8921088 * 2);   // [16][66][2][33][128] parity
  bf16* zqtp  = (bf16*)alloc((size_t)2367488 * 2);   // [16][34][34][128]
  bf16* eup   = (bf16*)alloc((size_t)8921088 * 2);   // [16][66][66][128]
  bf16* fqp   = (bf16*)alloc((size_t)8921088 * 2);   // [16][66][66][128]
  bf16* hp    = (bf16*)alloc((size_t)17305600 * 2);  // [16][130][130][64]
  bf16* ztp   = (bf16*)alloc((size_t)2097152 * 2);   // [16][32][32][128]

  // 3 setup launches (was 17)
  detect_dtype_kernel<<<1, 256, 0, stream>>>(d_in[0], flag, lacc);
  zero_halo_all<<<1428, 256, 0, stream>>>(act1p, hp, zbp, eup, fqp, zqtp);
  setup_all<<<4155, 256, 0, stream>>>(
      d_in[2], d_in[4], d_in[6], d_in[10], d_in[12], d_in[14],
      d_in[7], d_in[8], d_in[1], d_in[13], d_in[11], d_in[3],
      d_in[5], d_in[9],
      biasAll, embTB, sqAll, Wc1, Wfin, Wd1f, Wt2f, Wttf, Wdtf, flag);

  // encoder: conv1 = fused im2col gather + MFMA GEMM (parity-split store)
  gemm1_fused<<<2048, 256, 0, stream>>>(d_in[0], flag, Wc1, beB1f, act1p);
  // conv2: LDS-staged, wave M64xN64, 1024 blocks x 128 threads
  conv2_lds<<<dim3(64, 1, 16), 128, 0, stream>>>(act1p, Wt2f, beB2f, zbp);
  // conv_t: PXW=33 (zbp parity), output ztp row-major
  mfma_conv<128, 128, 32, 2, 16, 128, 2, 33><<<dim3(16, 2, 16), 256, 0, stream>>>(
      zbp, zbp, 557568, 8448, Wttf, beTf, ztp, 131072, 4096, 128, 30, 0, 0, 0);

  // VQ top (16384 positions, row-major)
  vq_mfma<<<64, 256, 0, stream>>>(ztp, 131072, 4096, embT, sqT,
                                  zqtp + 4480, 147968, 4352, lacc + 0, 5, 10, 0);

  // decoder_top upsample: 4 classes in one launch (row-major in/out)
  mfma_conv<128, 128, 32, 1, 4, 128, 2, 0><<<dim3(64, 2, 16), 256, 0, stream>>>(
      zqtp, zqtp, 147968, 4352, Wdtf, bdTf, eup, 557568, 16896, 256, 4, 8448, 128, 0);

  // VQ bottom (65536 positions; zbp parity-split input, fqp row-major out)
  vq_mfma<<<256, 256, 0, stream>>>(zbp + 8448, 557568, 8448, embB, sqB,
                                   fqp + 8576, 557568, 8448, lacc + 1, 6, 12, 33);

  // decoder conv d1: LDS-staged, 4 classes x 2 rows per block, 512 blocks
  mfma_d1_lds<<<dim3(32, 1, 16), 256, 0, stream>>>(fqp, eup, Wd1f, bd1f, hp);

  // final convT + sigmoid via MFMA -> fp32 NCHW output
  final_convt_mfma<<<1024, 256, 0, stream>>>(hp, Wfin, bd2f, out);
  finalize_loss_kernel<<<1, 64, 0, stream>>>(lacc, out + 3145728);
}

// Round 4
// 486.954 us; speedup vs baseline: 1.0575x; 1.0074x over previous
//
#include <hip/hip_runtime.h>
#include <hip/hip_bf16.h>
#include <cstddef>

typedef __hip_bfloat16 bf16;
typedef __attribute__((ext_vector_type(8))) short short8;
typedef __attribute__((ext_vector_type(4))) float float4v;
typedef __attribute__((ext_vector_type(4))) unsigned short ushort4v;

static __device__ __forceinline__ float b2f(bf16 v) { return __bfloat162float(v); }
static __device__ __forceinline__ float bits2f(unsigned int u) { return __uint_as_float(u); }
static __device__ __forceinline__ unsigned short f2bfbits(float f) {
  bf16 h = __float2bfloat16(f);
  return *reinterpret_cast<unsigned short*>(&h);
}
static __device__ __forceinline__ float ld_any(const void* p, long i, int flag) {
  return flag ? b2f(((const bf16*)p)[i]) : ((const float*)p)[i];
}
static __device__ __forceinline__ void unpack_u4(uint4 u, float* f) {
  f[0] = bits2f(u.x << 16); f[1] = bits2f(u.x & 0xffff0000u);
  f[2] = bits2f(u.y << 16); f[3] = bits2f(u.y & 0xffff0000u);
  f[4] = bits2f(u.z << 16); f[5] = bits2f(u.z & 0xffff0000u);
  f[6] = bits2f(u.w << 16); f[7] = bits2f(u.w & 0xffff0000u);
}

// --------------------------------- dtype detection (+ loss accumulator zero)
__global__ void detect_dtype_kernel(const void* __restrict__ x, int* __restrict__ flag,
                                    float* __restrict__ lacc) {
  if (threadIdx.x < 2) lacc[threadIdx.x] = 0.f;
  __shared__ int ok;
  if (threadIdx.x == 0) ok = 1;
  __syncthreads();
  float v = b2f(((const bf16*)x)[threadIdx.x]);
  if (!(v >= 0.f && v <= 1.0009765625f)) ok = 0;
  __syncthreads();
  if (threadIdx.x == 0) *flag = ok;
}

// ------------------------------------------------- fused halo-ring zeroing
// zero the 1-wide halo ring of padded NHWC buffers; r indexes (buf, img, elem)
static __device__ __forceinline__ void halo_seg(bf16* p0, bf16* p1, bf16* p2,
                                                int np, int H, int W, int C8,
                                                long imgS, int gpi, int r) {
  int total = 16 * gpi;
  int which = r / total;
  if (which >= np) return;
  int rr = r - which * total;
  int img = rr / gpi, g = rr % gpi;
  int pos = g / C8, c8 = g % C8;
  int row, col;
  if (pos < W) { row = 0; col = pos; }
  else if (pos < 2 * W) { row = H - 1; col = pos - W; }
  else { int s = pos - 2 * W; row = 1 + (s >> 1); col = (s & 1) ? (W - 1) : 0; }
  bf16* base = (which == 0) ? p0 : ((which == 1) ? p1 : p2);
  uint4* dst = (uint4*)(base + (long)img * imgS + ((long)row * W + col) * (C8 * 8) + (long)c8 * 8);
  *dst = uint4{0u, 0u, 0u, 0u};
}

__global__ __launch_bounds__(256) void zero_halo_all(bf16* act1p, bf16* hp,
                                                     bf16* zbp, bf16* eup, bf16* fqp,
                                                     bf16* zqtp) {
  int tid = blockIdx.x * 256 + threadIdx.x;
  if (tid < 132096) { halo_seg(act1p, hp, nullptr, 2, 130, 130, 8, 1081600, 4128, tid); return; }
  tid -= 132096;
  if (tid < 199680) { halo_seg(zbp, eup, fqp, 3, 66, 66, 16, 557568, 4160, tid); return; }
  tid -= 199680;
  if (tid < 33792)  { halo_seg(zqtp, nullptr, nullptr, 1, 34, 34, 16, 147968, 2112, tid); }
}

// ---------------- all converts / repacks fused into one kernel (segmented).
// Two-step repack chains (rp_conv_w/rp_convt_w -> frag_pack) are collapsed
// into direct one-pass index maps (kh = 2s+1-p, kw = 2t+1-q inverts the
// class decomposition).
__global__ __launch_bounds__(256) void setup_all(
    const void* s2, const void* s4, const void* s6,
    const void* s10, const void* s12, const void* s14,
    const void* sT, const void* sB, const void* c1s,
    const void* fins, const void* d1s, const void* t2s,
    const void* tts, const void* dts,
    float* __restrict__ biasAll, bf16* __restrict__ embTB,
    float* __restrict__ sqAll, bf16* __restrict__ Wc1,
    bf16* __restrict__ Wfin, bf16* __restrict__ Wd1f,
    bf16* __restrict__ Wt2f, bf16* __restrict__ Wttf,
    bf16* __restrict__ Wdtf, const int* __restrict__ flag) {
  long i = (long)blockIdx.x * 256 + threadIdx.x;
  const int fl = *flag;
  // seg0: 6 conv biases -> one fp32 buffer [515]
  if (i < 515) {
    const void* s; long off;
    if (i < 64)       { s = s2;  off = i; }
    else if (i < 192) { s = s4;  off = i - 64; }
    else if (i < 320) { s = s6;  off = i - 192; }
    else if (i < 448) { s = s10; off = i - 320; }
    else if (i < 512) { s = s12; off = i - 448; }
    else              { s = s14; off = i - 512; }
    biasAll[i] = ld_any(s, off, fl);
    return;
  }
  i -= 515;
  // seg1: both codebooks -> contiguous bf16 [1024][128]
  if (i < 131072) {
    const void* s = (i < 65536) ? sT : sB;
    long off = i & 65535;
    embTB[i] = fl ? ((const bf16*)s)[off] : __float2bfloat16(((const float*)s)[off]);
    return;
  }
  i -= 131072;
  // seg2: emb row sum-of-squares from RAW src through identical bf16 rounding
  if (i < 1024) {
    const void* s = (i < 512) ? sT : sB;
    long base = (i & 511) * 128;
    float acc = 0.f;
    for (int c = 0; c < 128; ++c) {
      float v = b2f(__float2bfloat16(ld_any(s, base + c, fl)));
      acc = fmaf(v, v, acc);
    }
    sqAll[i] = acc;
    return;
  }
  i -= 1024;
  // seg3: conv1 weights [64][3][4][4] -> [co][k], K padded 48->64 [4096]
  if (i < 4096) {
    int co = (int)i >> 6, k = (int)i & 63;
    float v = (k < 48) ? ld_any(c1s, co * 48 + k, fl) : 0.f;
    Wc1[i] = __float2bfloat16(v);
    return;
  }
  i -= 4096;
  // seg4: final convT weights -> A[m=cls*4+co][d=dy*3+dx][64ci] [9216]
  if (i < 9216) {
    int m = (int)i / 576, rem = (int)i % 576;
    int d = rem >> 6, ci = rem & 63;
    int cls = m >> 2, co = m & 3;
    int p = cls >> 1, q = cls & 1;
    int dy = d / 3, dx = d % 3;
    int s_ = p - dy + 1, t_ = q - dx + 1;
    float v = 0.f;
    if (co < 3 && s_ >= 0 && s_ <= 1 && t_ >= 0 && t_ <= 1) {
      int kh = 2 * s_ + 1 - p, kw = 2 * t_ + 1 - q;
      v = ld_any(fins, ci * 48 + co * 16 + kh * 4 + kw, fl);
    }
    Wfin[i] = __float2bfloat16(v);
    return;
  }
  i -= 9216;
  // seg5: d1 weights [256ci][64co][4][4] -> frag [262144]
  if (i < 262144) {
    int low = (int)i & 511;
    int ln = low >> 5, cl = low & 31;
    int c2 = (int)(i >> 9);
    int j = c2 & 3;
    int kc = (c2 >> 2) & 7;
    int t = (c2 >> 5) & 3;
    int cls = c2 >> 7;
    int p = cls >> 1, q = cls & 1;
    int s_ = t >> 1, t2 = t & 1;
    int kh = 2 * s_ + 1 - p, kw = 2 * t2 + 1 - q;
    int co = j * 16 + ln, ci = kc * 32 + cl;
    Wd1f[i] = __float2bfloat16(ld_any(d1s, (long)ci * 1024 + co * 16 + kh * 4 + kw, fl));
    return;
  }
  i -= 262144;
  // seg6: conv2 weights OIHW[128][64][4][4] -> frag direct (MC=4,KC=2) [131072]
  if (i < 131072) {
    int low = (int)i & 511;
    int ln = low >> 5, cl = low & 31;
    int c2 = (int)(i >> 9);
    int j = c2 & 1, c3 = c2 >> 1;
    int kc = c3 & 1, c4 = c3 >> 1;
    int mc = c4 & 3, tg = c4 >> 2;
    int co = mc * 32 + j * 16 + ln, ci = kc * 32 + cl;
    Wt2f[i] = __float2bfloat16(ld_any(t2s, (long)co * 1024 + ci * 16 + tg, fl));
    return;
  }
  i -= 131072;
  // seg7: conv_t weights OIHW[128][128][4][4] -> frag direct (MC=4,KC=4) [262144]
  if (i < 262144) {
    int low = (int)i & 511;
    int ln = low >> 5, cl = low & 31;
    int c2 = (int)(i >> 9);
    int j = c2 & 1, c3 = c2 >> 1;
    int kc = c3 & 3, c4 = c3 >> 2;
    int mc = c4 & 3, tg = c4 >> 2;
    int co = mc * 32 + j * 16 + ln, ci = kc * 32 + cl;
    Wttf[i] = __float2bfloat16(ld_any(tts, (long)co * 2048 + ci * 16 + tg, fl));
    return;
  }
  i -= 262144;
  // seg8: convT dt weights [128ci][128co][4][4] -> class frag direct [262144]
  if (i < 262144) {
    int low = (int)i & 511;
    int ln = low >> 5, cl = low & 31;
    int c2 = (int)(i >> 9);
    int j = c2 & 1, c3 = c2 >> 1;
    int kc = c3 & 3, c4 = c3 >> 2;
    int mc = c4 & 3, tg = c4 >> 2;
    int co = mc * 32 + j * 16 + ln, ci = kc * 32 + cl;
    int cls = tg >> 2, st = tg & 3;
    int p = cls >> 1, q = cls & 1;
    int s_ = st >> 1, tt_ = st & 1;
    int kh = 2 * s_ + 1 - p, kw = 2 * tt_ + 1 - q;
    Wdtf[i] = __float2bfloat16(ld_any(dts, (long)ci * 2048 + co * 16 + kh * 4 + kw, fl));
    return;
  }
}

// -------------------- conv1 fused: inline im2col gather + MFMA GEMM
// M=64 (co), K=64 (48 real + 16 pad), N=262144; bias+relu; parity-split store.
__global__ __launch_bounds__(256) void gemm1_fused(
    const void* __restrict__ x, const int* __restrict__ flag,
    const bf16* __restrict__ w, const float* __restrict__ bias,
    bf16* __restrict__ act1p) {
  const int lane = threadIdx.x & 63, wv = threadIdx.x >> 6;
  const int wm = wv & 1, wn = wv >> 1;
  const int ln = lane & 15, quad = lane >> 4;
  const int n0 = blockIdx.x * 128 + wn * 64;
  const int fl = *flag;
  float4v acc[2][4];
  #pragma unroll
  for (int i = 0; i < 2; ++i)
    #pragma unroll
    for (int j = 0; j < 4; ++j) acc[i][j] = {0.f, 0.f, 0.f, 0.f};
  #pragma unroll
  for (int kc = 0; kc < 2; ++kc) {
    const bf16* wk = w + (wm * 32 + ln) * 64 + kc * 32 + quad * 8;
    short8 a0 = *(const short8*)(wk);
    short8 a1 = *(const short8*)(wk + 16 * 64);
    const int k0 = kc * 32 + quad * 8;      // 0,8,...,56; >=48 is zero-pad
    #pragma unroll
    for (int bf = 0; bf < 4; ++bf) {
      short8 bv;
      if (k0 >= 48) {
        bv = (short8){0, 0, 0, 0, 0, 0, 0, 0};
      } else {
        int n = n0 + bf * 16 + ln;
        int ow = n & 127, oh = (n >> 7) & 127, b = n >> 14;
        int ci = k0 >> 4;
        int kh0 = (k0 & 15) >> 2;           // 0 or 2
        long pbase = ((long)(b * 3 + ci)) << 16;
        int iw0 = ow * 2 - 1;
        unsigned short tmp[8];
        #pragma unroll
        for (int r = 0; r < 2; ++r) {
          int ih = oh * 2 - 1 + kh0 + r;
          bool okh = (unsigned)ih < 256u;
          long rbase = pbase + ((long)ih << 8);
          #pragma unroll
          for (int c = 0; c < 4; ++c) {
            int iw = iw0 + c;
            float v = (okh && (unsigned)iw < 256u) ? ld_any(x, rbase + iw, fl) : 0.f;
            tmp[r * 4 + c] = f2bfbits(v);
          }
        }
        bv = *(const short8*)tmp;
      }
      acc[0][bf] = __builtin_amdgcn_mfma_f32_16x16x32_bf16(a0, bv, acc[0][bf], 0, 0, 0);
      acc[1][bf] = __builtin_amdgcn_mfma_f32_16x16x32_bf16(a1, bv, acc[1][bf], 0, 0, 0);
    }
  }
  #pragma unroll
  for (int mf = 0; mf < 2; ++mf) {
    int coB = wm * 32 + mf * 16 + quad * 4;
    float4v bv4 = *(const float4v*)(bias + coB);
    #pragma unroll
    for (int bf = 0; bf < 4; ++bf) {
      int n = n0 + bf * 16 + ln;
      int ow = n & 127; int t2 = n >> 7;
      int oh = t2 & 127; int b = t2 >> 7;
      int xx = ow + 1;   // parity-split column
      long oaddr = ((long)(b * 130 + oh + 1)) * 8320 +
                   (long)(((xx & 1) * 65) + (xx >> 1)) * 64 + coB;
      float4v v = acc[mf][bf];
      ushort4v o;
      #pragma unroll
      for (int e = 0; e < 4; ++e) o[e] = f2bfbits(fmaxf(v[e] + bv4[e], 0.f));
      *(ushort4v*)(act1p + oaddr) = o;
    }
  }
}

// ------------------------------------------- MFMA implicit-GEMM tap conv
template <int COUT, int CINT, int TC, int S, int NT, int INC, int NBF, int PXW>
__global__ __launch_bounds__(256) void mfma_conv(
    const bf16* __restrict__ in1, const bf16* __restrict__ in2,
    long inImgS, int inRowS,
    const bf16* __restrict__ wf, const float* __restrict__ bias,
    bf16* __restrict__ outp, long outImgS, int oRS, int oCS,
    int nxb, long po, long qo, int oPXW) {
  constexpr int TR = (2 * NBF * 16) / TC;
  constexpr int KC = CINT / 32;
  constexpr int MC = COUT / 32;
  constexpr int KSPLIT = (CINT > INC) ? (INC / 32) : KC;
  const int lane = threadIdx.x & 63;
  const int wv = threadIdx.x >> 6;
  const int wm = wv & 1, wn = wv >> 1;
  const int ln = lane & 15, quad = lane >> 4;
  const int cls = blockIdx.x >> nxb;
  const int xb = blockIdx.x & ((1u << nxb) - 1u);
  const int mTile = blockIdx.y * 64;
  const int mc = blockIdx.y * 2 + wm;
  const int oh0 = xb * TR;
  const int b = blockIdx.z;
  const int p = cls >> 1, q = cls & 1;
  const long ooff = (long)(p + 1) * po + (long)(q + 1) * qo;

  long posOff[NBF];
  int rr[NBF], cc[NBF];
  #pragma unroll
  for (int bf = 0; bf < NBF; ++bf) {
    int n = wn * (NBF * 16) + bf * 16 + ln;
    int r = n / TC, c = n % TC;
    rr[bf] = r; cc[bf] = c;
    posOff[bf] = (long)(S * (oh0 + r)) * inRowS +
                 (PXW ? (long)c * INC : (long)(S * c) * INC);
  }
  const bf16* inb1 = in1 + (long)b * inImgS;
  const bf16* inb2 = in2 + (long)b * inImgS;

  float4v acc[2][NBF];
  #pragma unroll
  for (int i = 0; i < 2; ++i)
    #pragma unroll
    for (int j = 0; j < NBF; ++j) acc[i][j] = {0.f, 0.f, 0.f, 0.f};

  for (int t = 0; t < NT; ++t) {
    int dy, dx;
    if (S == 2) { dy = t >> 2; dx = t & 3; }
    else        { dy = p - (t >> 1) + 1; dx = q - (t & 1) + 1; }
    const int dxo = PXW ? ((dx & 1) * PXW + (dx >> 1)) : dx;
    const long tapOff = (long)dy * inRowS + (long)dxo * INC;
    const bf16* wt = wf + ((long)(cls * NT + t) * MC + mc) * (KC * 1024) + ln * 32 + quad * 8;
    #pragma unroll
    for (int kc = 0; kc < KC; ++kc) {
      short8 a0 = *(const short8*)(wt + kc * 1024);
      short8 a1 = *(const short8*)(wt + kc * 1024 + 512);
      const bf16* bp = (kc < KSPLIT) ? inb1 : inb2;
      int kOff = (kc < KSPLIT ? kc : kc - KSPLIT) * 32 + quad * 8;
      #pragma unroll
      for (int bf = 0; bf < NBF; ++bf) {
        short8 bv = *(const short8*)(bp + posOff[bf] + tapOff + kOff);
        acc[0][bf] = __builtin_amdgcn_mfma_f32_16x16x32_bf16(a0, bv, acc[0][bf], 0, 0, 0);
        acc[1][bf] = __builtin_amdgcn_mfma_f32_16x16x32_bf16(a1, bv, acc[1][bf], 0, 0, 0);
      }
    }
  }

  bf16* outb = outp + (long)b * outImgS + ooff;
  #pragma unroll
  for (int mf = 0; mf < 2; ++mf) {
    int coB = mTile + wm * 32 + mf * 16 + quad * 4;
    float4v bv4 = *(const float4v*)(bias + coB);
    #pragma unroll
    for (int bf = 0; bf < NBF; ++bf) {
      float4v v = acc[mf][bf];
      ushort4v o;
      #pragma unroll
      for (int e = 0; e < 4; ++e)
        o[e] = f2bfbits(fmaxf(v[e] + bv4[e], 0.f));
      long coff = oPXW ? (long)((((cc[bf] + 1) & 1) * oPXW) + ((cc[bf] + 1) >> 1)) * oCS
                       : (long)cc[bf] * oCS;
      long oaddr = (long)(oh0 + rr[bf]) * oRS + coff + oCS * 0 + coB;
      *(ushort4v*)(outb + oaddr) = o;
    }
  }
}

// ---------- conv2 (64 -> 128, s2) with LDS-staged input, wave M64xN64
__global__ __launch_bounds__(128) void conv2_lds(
    const bf16* __restrict__ in, const bf16* __restrict__ wf,
    const float* __restrict__ bias, bf16* __restrict__ outp) {
  __shared__ short8 lds8[2 * 130 * 9];   // 37440 B
  const int lane = threadIdx.x & 63;
  const int h = threadIdx.x >> 6;        // co-half (wave id)
  const int ln = lane & 15, quad = lane >> 4;
  const int oh = blockIdx.x;             // output row 0..63
  const int b = blockIdx.z;

  const bf16* img = in + (long)b * 1081600;

  float4v acc[4][4];   // [j4 (co chunk)][bf (pos chunk)]
  #pragma unroll
  for (int j = 0; j < 4; ++j)
    #pragma unroll
    for (int bf = 0; bf < 4; ++bf) acc[j][bf] = {0.f, 0.f, 0.f, 0.f};

  #pragma unroll
  for (int f = 0; f < 2; ++f) {
    const short8* src8 = (const short8*)(img + (long)(2 * oh + 2 * f) * 8320);
    __syncthreads();
    for (int i = threadIdx.x; i < 2080; i += 128) {   // 2 rows x 130 pos x 8
      int pos2 = i >> 3, j = i & 7;                   // pos2 = r*130 + pos
      lds8[pos2 * 9 + j] = src8[i];
    }
    __syncthreads();
    #pragma unroll
    for (int tl = 0; tl < 8; ++tl) {
      const int t = 8 * f + tl;
      const int r = (t >> 2) & 1;        // row within phase
      const int dx = t & 3;
      const int pp = dx & 1, cb = dx >> 1;
      const int lbase = (r * 130 + pp * 65 + cb) * 9 + quad;
      const bf16* wt = wf + (long)(t * 4) * 2048 + (long)(2 * h) * 2048 +
                       ln * 32 + quad * 8;
      #pragma unroll
      for (int kc = 0; kc < 2; ++kc) {
        const bf16* wk = wt + kc * 1024;
        short8 a0 = *(const short8*)(wk);          // mc=2h,   j=0
        short8 a1 = *(const short8*)(wk + 512);    // mc=2h,   j=1
        short8 a2 = *(const short8*)(wk + 2048);   // mc=2h+1, j=0
        short8 a3 = *(const short8*)(wk + 2560);   // mc=2h+1, j=1
        #pragma unroll
        for (int bf = 0; bf < 4; ++bf) {
          short8 bv = lds8[lbase + (bf * 16 + ln) * 9 + kc * 4];
          acc[0][bf] = __builtin_amdgcn_mfma_f32_16x16x32_bf16(a0, bv, acc[0][bf], 0, 0, 0);
          acc[1][bf] = __builtin_amdgcn_mfma_f32_16x16x32_bf16(a1, bv, acc[1][bf], 0, 0, 0);
          acc[2][bf] = __builtin_amdgcn_mfma_f32_16x16x32_bf16(a2, bv, acc[2][bf], 0, 0, 0);
          acc[3][bf] = __builtin_amdgcn_mfma_f32_16x16x32_bf16(a3, bv, acc[3][bf], 0, 0, 0);
        }
      }
    }
  }

  // store: zbp parity layout, row oh+1, col map x -> ((x+1)&1)*33 + ((x+1)>>1)
  bf16* outb = outp + (long)b * 557568 + (long)(oh + 1) * 8448;
  #pragma unroll
  for (int j4 = 0; j4 < 4; ++j4) {
    int co = h * 64 + (j4 >> 1) * 32 + (j4 & 1) * 16 + quad * 4;
    float4v bv4 = *(const float4v*)(bias + co);
    #pragma unroll
    for (int bf = 0; bf < 4; ++bf) {
      int x = bf * 16 + ln;
      int col = (((x + 1) & 1) * 33) + ((x + 1) >> 1);
      float4v v = acc[j4][bf];
      ushort4v o;
      #pragma unroll
      for (int e = 0; e < 4; ++e)
        o[e] = f2bfbits(fmaxf(v[e] + bv4[e], 0.f));
      *(ushort4v*)(outb + (long)col * 128 + co) = o;
    }
  }
}

// ------ d1 (concat 256 -> 64): LDS-staged, 4 classes per block, 1 row.
// Occupancy-first: XOR slot swizzle (write slot' = j ^ (pos&7); read with the
// same XOR) replaces the 17-stride pad -> LDS 53856 -> 50688 B, 3 blocks/CU
// (was 2), 92 VGPR keeps 3 waves/SIMD legal. Bank math: physical slot low bits
// cycle (slot&7)^(pos&7) as ln varies -> 8 bank-groups x 2-way (free).
__global__ __launch_bounds__(256) void mfma_d1_lds(
    const bf16* __restrict__ in1, const bf16* __restrict__ in2,
    const bf16* __restrict__ wf, const float* __restrict__ bias,
    bf16* __restrict__ outp) {
  __shared__ short8 lds8[198 * 16];   // 50688 B, swizzled slots (no pad)
  const int lane = threadIdx.x & 63, wv = threadIdx.x >> 6;
  const int ln = lane & 15, quad = lane >> 4;
  const int r = blockIdx.x;          // output class-row 0..63
  const int b = blockIdx.z;
  const int cls = wv, p = cls >> 1, q = cls & 1;

  const bf16* src1 = in1 + (long)b * 557568 + (long)r * 8448;  // rows r..r+2
  const bf16* src2 = in2 + (long)b * 557568 + (long)r * 8448;

  float4v acc[4][4];
  #pragma unroll
  for (int j = 0; j < 4; ++j)
    #pragma unroll
    for (int bf = 0; bf < 4; ++bf) acc[j][bf] = {0.f, 0.f, 0.f, 0.f};

  #pragma unroll
  for (int phase = 0; phase < 2; ++phase) {
    const bf16* src = phase ? src2 : src1;
    __syncthreads();
    for (int i = threadIdx.x; i < 3168; i += 256) {   // 198 pos x 16 chunks
      int pos = i >> 4, j = i & 15;
      lds8[pos * 16 + (j ^ (pos & 7))] = *(const short8*)(src + (long)pos * 128 + j * 8);
    }
    __syncthreads();
    #pragma unroll
    for (int t = 0; t < 4; ++t) {
      int dy = p - (t >> 1) + 1, dx = q - (t & 1) + 1;
      const bf16* wt = wf + (long)(cls * 4 + t) * 16384 + (long)(phase * 4) * 2048 +
                       ln * 32 + quad * 8;
      const int pbase = dy * 66 + dx;
      #pragma unroll
      for (int kc = 0; kc < 4; ++kc) {
        const bf16* wk = wt + kc * 2048;
        short8 a0 = *(const short8*)(wk);
        short8 a1 = *(const short8*)(wk + 512);
        short8 a2 = *(const short8*)(wk + 1024);
        short8 a3 = *(const short8*)(wk + 1536);
        const int slot = kc * 4 + quad;
        #pragma unroll
        for (int bf = 0; bf < 4; ++bf) {
          int P = pbase + bf * 16 + ln;
          short8 bv = lds8[P * 16 + (slot ^ (P & 7))];
          acc[0][bf] = __builtin_amdgcn_mfma_f32_16x16x32_bf16(a0, bv, acc[0][bf], 0, 0, 0);
          acc[1][bf] = __builtin_amdgcn_mfma_f32_16x16x32_bf16(a1, bv, acc[1][bf], 0, 0, 0);
          acc[2][bf] = __builtin_amdgcn_mfma_f32_16x16x32_bf16(a2, bv, acc[2][bf], 0, 0, 0);
          acc[3][bf] = __builtin_amdgcn_mfma_f32_16x16x32_bf16(a3, bv, acc[3][bf], 0, 0, 0);
        }
      }
    }
  }

  bf16* outb = outp + (long)b * 1081600 + (long)(p + 1) * 8320 + (long)(q + 1) * 64 +
               (long)r * 16640;
  #pragma unroll
  for (int j = 0; j < 4; ++j) {
    int co = j * 16 + quad * 4;
    float4v bv4 = *(const float4v*)(bias + co);
    #pragma unroll
    for (int bf = 0; bf < 4; ++bf) {
      float4v v = acc[j][bf];
      ushort4v o;
      #pragma unroll
      for (int e = 0; e < 4; ++e)
        o[e] = f2bfbits(fmaxf(v[e] + bv4[e], 0.f));
      *(ushort4v*)(outb + (long)(bf * 16 + ln) * 128 + co) = o;
    }
  }
}

// ---------------------------------------------------- VQ via MFMA GEMM
__global__ __launch_bounds__(256) void vq_mfma(
    const bf16* __restrict__ z, long zImgS, int zRowS,
    const bf16* __restrict__ emb, const float* __restrict__ embsq,
    bf16* __restrict__ zq, long qImgS, int qRowS,
    float* __restrict__ loss_acc, int wb, int hwb, int ipxw) {
  const int lane = threadIdx.x & 63, wv = threadIdx.x >> 6;
  const int ln = lane & 15, quad = lane >> 4;
  const int base = blockIdx.x * 256 + wv * 64;

  short8 bfrag[4][4];
  #pragma unroll
  for (int bf = 0; bf < 4; ++bf) {
    int n = base + bf * 16 + ln;
    int b = n >> hwb;
    int rem = n & ((1 << hwb) - 1);
    int y = rem >> wb, x = rem & ((1 << wb) - 1);
    int xcol = ipxw ? ((((x + 1) & 1) * ipxw) + ((x + 1) >> 1)) : x;
    const bf16* zrow = z + (long)b * zImgS + (long)y * zRowS + (long)xcol * 128;
    #pragma unroll
    for (int kc = 0; kc < 4; ++kc)
      bfrag[bf][kc] = *(const short8*)(zrow + kc * 32 + quad * 8);
  }

  float best0 = 3.4e38f, best1 = 3.4e38f, best2 = 3.4e38f, best3 = 3.4e38f;
  int bk0 = 0, bk1 = 0, bk2 = 0, bk3 = 0;
  for (int ct = 0; ct < 32; ++ct) {
    const bf16* erow = emb + (long)(ct * 16 + ln) * 128 + quad * 8;
    short8 a0 = *(const short8*)(erow);
    short8 a1 = *(const short8*)(erow + 32);
    short8 a2 = *(const short8*)(erow + 64);
    short8 a3 = *(const short8*)(erow + 96);
    float4v sq4 = *(const float4v*)(embsq + ct * 16 + quad * 4);
    #pragma unroll
    for (int bf = 0; bf < 4; ++bf) {
      float4v acc = {0.f, 0.f, 0.f, 0.f};
      acc = __builtin_amdgcn_mfma_f32_16x16x32_bf16(a0, bfrag[bf][0], acc, 0, 0, 0);
      acc = __builtin_amdgcn_mfma_f32_16x16x32_bf16(a1, bfrag[bf][1], acc, 0, 0, 0);
      acc = __builtin_amdgcn_mfma_f32_16x16x32_bf16(a2, bfrag[bf][2], acc, 0, 0, 0);
      acc = __builtin_amdgcn_mfma_f32_16x16x32_bf16(a3, bfrag[bf][3], acc, 0, 0, 0);
      int kb = ct * 16 + quad * 4;
      #pragma unroll
      for (int r = 0; r < 4; ++r) {
        float s = fmaf(-2.f, acc[r], sq4[r]);
        if (bf == 0) { if (s < best0) { best0 = s; bk0 = kb + r; } }
        if (bf == 1) { if (s < best1) { best1 = s; bk1 = kb + r; } }
        if (bf == 2) { if (s < best2) { best2 = s; bk2 = kb + r; } }
        if (bf == 3) { if (s < best3) { best3 = s; bk3 = kb + r; } }
      }
    }
  }
  float bs[4] = {best0, best1, best2, best3};
  int bk[4] = {bk0, bk1, bk2, bk3};
  #pragma unroll
  for (int bf = 0; bf < 4; ++bf) {
    #pragma unroll
    for (int m = 16; m <= 32; m <<= 1) {
      float os = __shfl_xor(bs[bf], m, 64);
      int ok = __shfl_xor(bk[bf], m, 64);
      if (os < bs[bf] || (os == bs[bf] && ok < bk[bf])) { bs[bf] = os; bk[bf] = ok; }
    }
  }
  int myk = (quad == 0) ? bk[0] : (quad == 1) ? bk[1] : (quad == 2) ? bk[2] : bk[3];
  int n = base + quad * 16 + ln;
  int b = n >> hwb;
  int rem = n & ((1 << hwb) - 1);
  int y = rem >> wb, x = rem & ((1 << wb) - 1);
  int xcol = ipxw ? ((((x + 1) & 1) * ipxw) + ((x + 1) >> 1)) : x;
  const uint4* zr = (const uint4*)(z + (long)b * zImgS + (long)y * zRowS + (long)xcol * 128);
  uint4* qr = (uint4*)(zq + (long)b * qImgS + (long)y * qRowS + (long)x * 128);
  const uint4* er = (const uint4*)(emb + (long)myk * 128);
  float lsum = 0.f;
  #pragma unroll
  for (int j = 0; j < 16; ++j) {
    uint4 ue = er[j];
    uint4 uz = zr[j];
    qr[j] = ue;
    float ev[8], zv[8];
    unpack_u4(ue, ev);
    unpack_u4(uz, zv);
    #pragma unroll
    for (int e = 0; e < 8; ++e) {
      float dv = ev[e] - zv[e];
      lsum = fmaf(dv, dv, lsum);
    }
  }
  for (int o = 32; o > 0; o >>= 1) lsum += __shfl_down(lsum, o, 64);
  if (lane == 0) atomicAdd(loss_acc, lsum);
}

// --------------------- final convT(64->3)+sigmoid via class-packed MFMA
__global__ __launch_bounds__(256) void final_convt_mfma(
    const bf16* __restrict__ hp, const bf16* __restrict__ wfin,
    const float* __restrict__ bf_, float* __restrict__ out) {
  const int lane = threadIdx.x & 63, wv = threadIdx.x >> 6;
  const int ln = lane & 15, quad = lane >> 4;
  const int base = blockIdx.x * 256 + wv * 64;   // 262144 positions total

  short8 afr[18];
  #pragma unroll
  for (int kc = 0; kc < 18; ++kc)
    afr[kc] = *(const short8*)(wfin + ln * 576 + kc * 32 + quad * 8);

  float4v acc[4];
  #pragma unroll
  for (int bf = 0; bf < 4; ++bf) acc[bf] = {0.f, 0.f, 0.f, 0.f};

  #pragma unroll
  for (int bf = 0; bf < 4; ++bf) {
    int n = base + bf * 16 + ln;
    int xx = n & 127, y = (n >> 7) & 127, b = n >> 14;
    const bf16* hb = hp + (long)b * 1081600 + (long)y * 8320 + (long)xx * 64;
    #pragma unroll
    for (int kc = 0; kc < 18; ++kc) {
      int d = kc >> 1;
      const bf16* bp = hb + (long)(d / 3) * 8320 + (d % 3) * 64 + (kc & 1) * 32 + quad * 8;
      short8 bv = *(const short8*)bp;
      acc[bf] = __builtin_amdgcn_mfma_f32_16x16x32_bf16(afr[kc], bv, acc[bf], 0, 0, 0);
    }
  }

  const int p = quad >> 1, q = quad & 1;
  float b0 = bf_[0], b1 = bf_[1], b2 = bf_[2];
  #pragma unroll
  for (int bf = 0; bf < 4; ++bf) {
    int n = base + bf * 16 + ln;
    int xx = n & 127, y = (n >> 7) & 127, b = n >> 14;
    long ob = (long)b * 196608 + (long)(2 * y + p) * 256 + (2 * xx + q);
    float v0 = acc[bf][0] + b0, v1 = acc[bf][1] + b1, v2 = acc[bf][2] + b2;
    out[ob]          = 1.f / (1.f + expf(-v0));
    out[ob + 65536]  = 1.f / (1.f + expf(-v1));
    out[ob + 131072] = 1.f / (1.f + expf(-v2));
  }
}

__global__ void finalize_loss_kernel(const float* __restrict__ lacc, float* __restrict__ out) {
  if (threadIdx.x == 0) {
    float lt = lacc[0] * (1.5f / 2097152.f);
    float lb = lacc[1] * (1.5f / 8388608.f);
    *out = lt + lb;
  }
}

// ------------------------------------------------------------------ launch
extern "C" void kernel_launch(void* const* d_in, const int* in_sizes, int n_in,
                              void* d_out, int out_size, void* d_ws, size_t ws_size,
                              hipStream_t stream) {
  float* out = (float*)d_out;
  char* base = (char*)d_ws;
  size_t off = 0;
  auto alloc = [&](size_t bytes) {
    void* pp = base + off;
    off = (off + bytes + 255) & ~(size_t)255;
    return pp;
  };

  int* flag = (int*)alloc(256);
  float* biasAll = (float*)alloc(515 * 4);
  float* beB1f = biasAll + 0;
  float* beB2f = biasAll + 64;
  float* beTf  = biasAll + 192;
  float* bdTf  = biasAll + 320;
  float* bd1f  = biasAll + 448;
  float* bd2f  = biasAll + 512;
  float* sqAll = (float*)alloc(1024 * 4);
  float* sqT = sqAll, *sqB = sqAll + 512;
  float* lacc = (float*)alloc(2 * 4);
  bf16* Wc1  = (bf16*)alloc((size_t)4096 * 2);
  bf16* Wt2f = (bf16*)alloc((size_t)131072 * 2);
  bf16* Wttf = (bf16*)alloc((size_t)262144 * 2);
  bf16* Wdtf = (bf16*)alloc((size_t)262144 * 2);
  bf16* Wd1f = (bf16*)alloc((size_t)262144 * 2);
  bf16* Wfin = (bf16*)alloc((size_t)9216 * 2);
  bf16* embTB = (bf16*)alloc((size_t)131072 * 2);
  bf16* embT = embTB, *embB = embTB + 65536;
  bf16* act1p = (bf16*)alloc((size_t)17305600 * 2);  // [16][130][2][65][64] parity
  bf16* zbp   = (bf16*)alloc((size_t)8921088 * 2);   // [16][66][2][33][128] parity
  bf16* zqtp  = (bf16*)alloc((size_t)2367488 * 2);   // [16][34][34][128]
  bf16* eup   = (bf16*)alloc((size_t)8921088 * 2);   // [16][66][66][128]
  bf16* fqp   = (bf16*)alloc((size_t)8921088 * 2);   // [16][66][66][128]
  bf16* hp    = (bf16*)alloc((size_t)17305600 * 2);  // [16][130][130][64]
  bf16* ztp   = (bf16*)alloc((size_t)2097152 * 2);   // [16][32][32][128]

  // 3 setup launches
  detect_dtype_kernel<<<1, 256, 0, stream>>>(d_in[0], flag, lacc);
  zero_halo_all<<<1428, 256, 0, stream>>>(act1p, hp, zbp, eup, fqp, zqtp);
  setup_all<<<4155, 256, 0, stream>>>(
      d_in[2], d_in[4], d_in[6], d_in[10], d_in[12], d_in[14],
      d_in[7], d_in[8], d_in[1], d_in[13], d_in[11], d_in[3],
      d_in[5], d_in[9],
      biasAll, embTB, sqAll, Wc1, Wfin, Wd1f, Wt2f, Wttf, Wdtf, flag);

  // encoder: conv1 = fused im2col gather + MFMA GEMM (parity-split store)
  gemm1_fused<<<2048, 256, 0, stream>>>(d_in[0], flag, Wc1, beB1f, act1p);
  // conv2: LDS-staged, wave M64xN64, 1024 blocks x 128 threads
  conv2_lds<<<dim3(64, 1, 16), 128, 0, stream>>>(act1p, Wt2f, beB2f, zbp);
  // conv_t: PXW=33 (zbp parity), output ztp row-major
  mfma_conv<128, 128, 32, 2, 16, 128, 2, 33><<<dim3(16, 2, 16), 256, 0, stream>>>(
      zbp, zbp, 557568, 8448, Wttf, beTf, ztp, 131072, 4096, 128, 30, 0, 0, 0);

  // VQ top (16384 positions, row-major)
  vq_mfma<<<64, 256, 0, stream>>>(ztp, 131072, 4096, embT, sqT,
                                  zqtp + 4480, 147968, 4352, lacc + 0, 5, 10, 0);

  // decoder_top upsample: 4 classes in one launch (row-major in/out)
  mfma_conv<128, 128, 32, 1, 4, 128, 2, 0><<<dim3(64, 2, 16), 256, 0, stream>>>(
      zqtp, zqtp, 147968, 4352, Wdtf, bdTf, eup, 557568, 16896, 256, 4, 8448, 128, 0);

  // VQ bottom (65536 positions; zbp parity-split input, fqp row-major out)
  vq_mfma<<<256, 256, 0, stream>>>(zbp + 8448, 557568, 8448, embB, sqB,
                                   fqp + 8576, 557568, 8448, lacc + 1, 6, 12, 33);

  // decoder conv d1: LDS-staged (XOR-swizzled, 3 blocks/CU), 1024 blocks
  mfma_d1_lds<<<dim3(64, 1, 16), 256, 0, stream>>>(fqp, eup, Wd1f, bd1f, hp);

  // final convT + sigmoid via MFMA -> fp32 NCHW output
  final_convt_mfma<<<1024, 256, 0, stream>>>(hp, Wfin, bd2f, out);
  finalize_loss_kernel<<<1, 64, 0, stream>>>(lacc, out + 3145728);
}

// Round 5
// 476.845 us; speedup vs baseline: 1.0799x; 1.0212x over previous
//
#include <hip/hip_runtime.h>
#include <hip/hip_bf16.h>
#include <cstddef>

typedef __hip_bfloat16 bf16;
typedef __attribute__((ext_vector_type(8))) short short8;
typedef __attribute__((ext_vector_type(4))) float float4v;
typedef __attribute__((ext_vector_type(4))) unsigned short ushort4v;

static __device__ __forceinline__ float b2f(bf16 v) { return __bfloat162float(v); }
static __device__ __forceinline__ float bits2f(unsigned int u) { return __uint_as_float(u); }
static __device__ __forceinline__ unsigned short f2bfbits(float f) {
  bf16 h = __float2bfloat16(f);
  return *reinterpret_cast<unsigned short*>(&h);
}
static __device__ __forceinline__ float ld_any(const void* p, long i, int flag) {
  return flag ? b2f(((const bf16*)p)[i]) : ((const float*)p)[i];
}
static __device__ __forceinline__ void unpack_u4(uint4 u, float* f) {
  f[0] = bits2f(u.x << 16); f[1] = bits2f(u.x & 0xffff0000u);
  f[2] = bits2f(u.y << 16); f[3] = bits2f(u.y & 0xffff0000u);
  f[4] = bits2f(u.z << 16); f[5] = bits2f(u.z & 0xffff0000u);
  f[6] = bits2f(u.w << 16); f[7] = bits2f(u.w & 0xffff0000u);
}

// --------------------------------- dtype detection (+ loss accumulator zero)
__global__ void detect_dtype_kernel(const void* __restrict__ x, int* __restrict__ flag,
                                    float* __restrict__ lacc) {
  if (threadIdx.x < 2) lacc[threadIdx.x] = 0.f;
  __shared__ int ok;
  if (threadIdx.x == 0) ok = 1;
  __syncthreads();
  float v = b2f(((const bf16*)x)[threadIdx.x]);
  if (!(v >= 0.f && v <= 1.0009765625f)) ok = 0;
  __syncthreads();
  if (threadIdx.x == 0) *flag = ok;
}

// ------------------------------------------------- fused halo-ring zeroing
static __device__ __forceinline__ void halo_seg(bf16* p0, bf16* p1, bf16* p2,
                                                int np, int H, int W, int C8,
                                                long imgS, int gpi, int r) {
  int total = 16 * gpi;
  int which = r / total;
  if (which >= np) return;
  int rr = r - which * total;
  int img = rr / gpi, g = rr % gpi;
  int pos = g / C8, c8 = g % C8;
  int row, col;
  if (pos < W) { row = 0; col = pos; }
  else if (pos < 2 * W) { row = H - 1; col = pos - W; }
  else { int s = pos - 2 * W; row = 1 + (s >> 1); col = (s & 1) ? (W - 1) : 0; }
  bf16* base = (which == 0) ? p0 : ((which == 1) ? p1 : p2);
  uint4* dst = (uint4*)(base + (long)img * imgS + ((long)row * W + col) * (C8 * 8) + (long)c8 * 8);
  *dst = uint4{0u, 0u, 0u, 0u};
}

__global__ __launch_bounds__(256) void zero_halo_all(bf16* act1p, bf16* hp,
                                                     bf16* zbp, bf16* eup, bf16* fqp,
                                                     bf16* zqtp) {
  int tid = blockIdx.x * 256 + threadIdx.x;
  if (tid < 132096) { halo_seg(act1p, hp, nullptr, 2, 130, 130, 8, 1081600, 4128, tid); return; }
  tid -= 132096;
  if (tid < 199680) { halo_seg(zbp, eup, fqp, 3, 66, 66, 16, 557568, 4160, tid); return; }
  tid -= 199680;
  if (tid < 33792)  { halo_seg(zqtp, nullptr, nullptr, 1, 34, 34, 16, 147968, 2112, tid); }
}

// ---------------- all converts / repacks fused into one kernel (segmented).
__global__ __launch_bounds__(256) void setup_all(
    const void* s2, const void* s4, const void* s6,
    const void* s10, const void* s12, const void* s14,
    const void* sT, const void* sB, const void* c1s,
    const void* fins, const void* d1s, const void* t2s,
    const void* tts, const void* dts,
    float* __restrict__ biasAll, bf16* __restrict__ embTB,
    float* __restrict__ sqAll, bf16* __restrict__ Wc1,
    bf16* __restrict__ Wfin, bf16* __restrict__ Wd1f,
    bf16* __restrict__ Wt2f, bf16* __restrict__ Wttf,
    bf16* __restrict__ Wdtf, const int* __restrict__ flag) {
  long i = (long)blockIdx.x * 256 + threadIdx.x;
  const int fl = *flag;
  // seg0: 6 conv biases -> one fp32 buffer [515]
  if (i < 515) {
    const void* s; long off;
    if (i < 64)       { s = s2;  off = i; }
    else if (i < 192) { s = s4;  off = i - 64; }
    else if (i < 320) { s = s6;  off = i - 192; }
    else if (i < 448) { s = s10; off = i - 320; }
    else if (i < 512) { s = s12; off = i - 448; }
    else              { s = s14; off = i - 512; }
    biasAll[i] = ld_any(s, off, fl);
    return;
  }
  i -= 515;
  // seg1: both codebooks -> contiguous bf16 [1024][128]
  if (i < 131072) {
    const void* s = (i < 65536) ? sT : sB;
    long off = i & 65535;
    embTB[i] = fl ? ((const bf16*)s)[off] : __float2bfloat16(((const float*)s)[off]);
    return;
  }
  i -= 131072;
  // seg2: emb row sum-of-squares from RAW src through identical bf16 rounding
  if (i < 1024) {
    const void* s = (i < 512) ? sT : sB;
    long base = (i & 511) * 128;
    float acc = 0.f;
    for (int c = 0; c < 128; ++c) {
      float v = b2f(__float2bfloat16(ld_any(s, base + c, fl)));
      acc = fmaf(v, v, acc);
    }
    sqAll[i] = acc;
    return;
  }
  i -= 1024;
  // seg3: conv1 weights [64][3][4][4] -> [co][k], K padded 48->64 [4096]
  if (i < 4096) {
    int co = (int)i >> 6, k = (int)i & 63;
    float v = (k < 48) ? ld_any(c1s, co * 48 + k, fl) : 0.f;
    Wc1[i] = __float2bfloat16(v);
    return;
  }
  i -= 4096;
  // seg4: final convT weights -> A[m=cls*4+co][d=dy*3+dx][64ci] [9216]
  if (i < 9216) {
    int m = (int)i / 576, rem = (int)i % 576;
    int d = rem >> 6, ci = rem & 63;
    int cls = m >> 2, co = m & 3;
    int p = cls >> 1, q = cls & 1;
    int dy = d / 3, dx = d % 3;
    int s_ = p - dy + 1, t_ = q - dx + 1;
    float v = 0.f;
    if (co < 3 && s_ >= 0 && s_ <= 1 && t_ >= 0 && t_ <= 1) {
      int kh = 2 * s_ + 1 - p, kw = 2 * t_ + 1 - q;
      v = ld_any(fins, ci * 48 + co * 16 + kh * 4 + kw, fl);
    }
    Wfin[i] = __float2bfloat16(v);
    return;
  }
  i -= 9216;
  // seg5: d1 weights [256ci][64co][4][4] -> frag [262144]
  if (i < 262144) {
    int low = (int)i & 511;
    int ln = low >> 5, cl = low & 31;
    int c2 = (int)(i >> 9);
    int j = c2 & 3;
    int kc = (c2 >> 2) & 7;
    int t = (c2 >> 5) & 3;
    int cls = c2 >> 7;
    int p = cls >> 1, q = cls & 1;
    int s_ = t >> 1, t2 = t & 1;
    int kh = 2 * s_ + 1 - p, kw = 2 * t2 + 1 - q;
    int co = j * 16 + ln, ci = kc * 32 + cl;
    Wd1f[i] = __float2bfloat16(ld_any(d1s, (long)ci * 1024 + co * 16 + kh * 4 + kw, fl));
    return;
  }
  i -= 262144;
  // seg6: conv2 weights OIHW[128][64][4][4] -> frag direct (MC=4,KC=2) [131072]
  if (i < 131072) {
    int low = (int)i & 511;
    int ln = low >> 5, cl = low & 31;
    int c2 = (int)(i >> 9);
    int j = c2 & 1, c3 = c2 >> 1;
    int kc = c3 & 1, c4 = c3 >> 1;
    int mc = c4 & 3, tg = c4 >> 2;
    int co = mc * 32 + j * 16 + ln, ci = kc * 32 + cl;
    Wt2f[i] = __float2bfloat16(ld_any(t2s, (long)co * 1024 + ci * 16 + tg, fl));
    return;
  }
  i -= 131072;
  // seg7: conv_t weights OIHW[128][128][4][4] -> frag direct (MC=4,KC=4) [262144]
  if (i < 262144) {
    int low = (int)i & 511;
    int ln = low >> 5, cl = low & 31;
    int c2 = (int)(i >> 9);
    int j = c2 & 1, c3 = c2 >> 1;
    int kc = c3 & 3, c4 = c3 >> 2;
    int mc = c4 & 3, tg = c4 >> 2;
    int co = mc * 32 + j * 16 + ln, ci = kc * 32 + cl;
    Wttf[i] = __float2bfloat16(ld_any(tts, (long)co * 2048 + ci * 16 + tg, fl));
    return;
  }
  i -= 262144;
  // seg8: convT dt weights [128ci][128co][4][4] -> class frag direct [262144]
  if (i < 262144) {
    int low = (int)i & 511;
    int ln = low >> 5, cl = low & 31;
    int c2 = (int)(i >> 9);
    int j = c2 & 1, c3 = c2 >> 1;
    int kc = c3 & 3, c4 = c3 >> 2;
    int mc = c4 & 3, tg = c4 >> 2;
    int co = mc * 32 + j * 16 + ln, ci = kc * 32 + cl;
    int cls = tg >> 2, st = tg & 3;
    int p = cls >> 1, q = cls & 1;
    int s_ = st >> 1, tt_ = st & 1;
    int kh = 2 * s_ + 1 - p, kw = 2 * tt_ + 1 - q;
    Wdtf[i] = __float2bfloat16(ld_any(dts, (long)ci * 2048 + co * 16 + kh * 4 + kw, fl));
    return;
  }
}

// -------------------- conv1 fused: inline im2col gather + MFMA GEMM
__global__ __launch_bounds__(256) void gemm1_fused(
    const void* __restrict__ x, const int* __restrict__ flag,
    const bf16* __restrict__ w, const float* __restrict__ bias,
    bf16* __restrict__ act1p) {
  const int lane = threadIdx.x & 63, wv = threadIdx.x >> 6;
  const int wm = wv & 1, wn = wv >> 1;
  const int ln = lane & 15, quad = lane >> 4;
  const int n0 = blockIdx.x * 128 + wn * 64;
  const int fl = *flag;
  float4v acc[2][4];
  #pragma unroll
  for (int i = 0; i < 2; ++i)
    #pragma unroll
    for (int j = 0; j < 4; ++j) acc[i][j] = {0.f, 0.f, 0.f, 0.f};
  #pragma unroll
  for (int kc = 0; kc < 2; ++kc) {
    const bf16* wk = w + (wm * 32 + ln) * 64 + kc * 32 + quad * 8;
    short8 a0 = *(const short8*)(wk);
    short8 a1 = *(const short8*)(wk + 16 * 64);
    const int k0 = kc * 32 + quad * 8;      // 0,8,...,56; >=48 is zero-pad
    #pragma unroll
    for (int bf = 0; bf < 4; ++bf) {
      short8 bv;
      if (k0 >= 48) {
        bv = (short8){0, 0, 0, 0, 0, 0, 0, 0};
      } else {
        int n = n0 + bf * 16 + ln;
        int ow = n & 127, oh = (n >> 7) & 127, b = n >> 14;
        int ci = k0 >> 4;
        int kh0 = (k0 & 15) >> 2;           // 0 or 2
        long pbase = ((long)(b * 3 + ci)) << 16;
        int iw0 = ow * 2 - 1;
        unsigned short tmp[8];
        #pragma unroll
        for (int r = 0; r < 2; ++r) {
          int ih = oh * 2 - 1 + kh0 + r;
          bool okh = (unsigned)ih < 256u;
          long rbase = pbase + ((long)ih << 8);
          #pragma unroll
          for (int c = 0; c < 4; ++c) {
            int iw = iw0 + c;
            float v = (okh && (unsigned)iw < 256u) ? ld_any(x, rbase + iw, fl) : 0.f;
            tmp[r * 4 + c] = f2bfbits(v);
          }
        }
        bv = *(const short8*)tmp;
      }
      acc[0][bf] = __builtin_amdgcn_mfma_f32_16x16x32_bf16(a0, bv, acc[0][bf], 0, 0, 0);
      acc[1][bf] = __builtin_amdgcn_mfma_f32_16x16x32_bf16(a1, bv, acc[1][bf], 0, 0, 0);
    }
  }
  #pragma unroll
  for (int mf = 0; mf < 2; ++mf) {
    int coB = wm * 32 + mf * 16 + quad * 4;
    float4v bv4 = *(const float4v*)(bias + coB);
    #pragma unroll
    for (int bf = 0; bf < 4; ++bf) {
      int n = n0 + bf * 16 + ln;
      int ow = n & 127; int t2 = n >> 7;
      int oh = t2 & 127; int b = t2 >> 7;
      int xx = ow + 1;   // parity-split column
      long oaddr = ((long)(b * 130 + oh + 1)) * 8320 +
                   (long)(((xx & 1) * 65) + (xx >> 1)) * 64 + coB;
      float4v v = acc[mf][bf];
      ushort4v o;
      #pragma unroll
      for (int e = 0; e < 4; ++e) o[e] = f2bfbits(fmaxf(v[e] + bv4[e], 0.f));
      *(ushort4v*)(act1p + oaddr) = o;
    }
  }
}

// ------------------------------------------- MFMA implicit-GEMM tap conv
template <int COUT, int CINT, int TC, int S, int NT, int INC, int NBF, int PXW>
__global__ __launch_bounds__(256) void mfma_conv(
    const bf16* __restrict__ in1, const bf16* __restrict__ in2,
    long inImgS, int inRowS,
    const bf16* __restrict__ wf, const float* __restrict__ bias,
    bf16* __restrict__ outp, long outImgS, int oRS, int oCS,
    int nxb, long po, long qo, int oPXW) {
  constexpr int TR = (2 * NBF * 16) / TC;
  constexpr int KC = CINT / 32;
  constexpr int MC = COUT / 32;
  constexpr int KSPLIT = (CINT > INC) ? (INC / 32) : KC;
  const int lane = threadIdx.x & 63;
  const int wv = threadIdx.x >> 6;
  const int wm = wv & 1, wn = wv >> 1;
  const int ln = lane & 15, quad = lane >> 4;
  const int cls = blockIdx.x >> nxb;
  const int xb = blockIdx.x & ((1u << nxb) - 1u);
  const int mTile = blockIdx.y * 64;
  const int mc = blockIdx.y * 2 + wm;
  const int oh0 = xb * TR;
  const int b = blockIdx.z;
  const int p = cls >> 1, q = cls & 1;
  const long ooff = (long)(p + 1) * po + (long)(q + 1) * qo;

  long posOff[NBF];
  int rr[NBF], cc[NBF];
  #pragma unroll
  for (int bf = 0; bf < NBF; ++bf) {
    int n = wn * (NBF * 16) + bf * 16 + ln;
    int r = n / TC, c = n % TC;
    rr[bf] = r; cc[bf] = c;
    posOff[bf] = (long)(S * (oh0 + r)) * inRowS +
                 (PXW ? (long)c * INC : (long)(S * c) * INC);
  }
  const bf16* inb1 = in1 + (long)b * inImgS;
  const bf16* inb2 = in2 + (long)b * inImgS;

  float4v acc[2][NBF];
  #pragma unroll
  for (int i = 0; i < 2; ++i)
    #pragma unroll
    for (int j = 0; j < NBF; ++j) acc[i][j] = {0.f, 0.f, 0.f, 0.f};

  for (int t = 0; t < NT; ++t) {
    int dy, dx;
    if (S == 2) { dy = t >> 2; dx = t & 3; }
    else        { dy = p - (t >> 1) + 1; dx = q - (t & 1) + 1; }
    const int dxo = PXW ? ((dx & 1) * PXW + (dx >> 1)) : dx;
    const long tapOff = (long)dy * inRowS + (long)dxo * INC;
    const bf16* wt = wf + ((long)(cls * NT + t) * MC + mc) * (KC * 1024) + ln * 32 + quad * 8;
    #pragma unroll
    for (int kc = 0; kc < KC; ++kc) {
      short8 a0 = *(const short8*)(wt + kc * 1024);
      short8 a1 = *(const short8*)(wt + kc * 1024 + 512);
      const bf16* bp = (kc < KSPLIT) ? inb1 : inb2;
      int kOff = (kc < KSPLIT ? kc : kc - KSPLIT) * 32 + quad * 8;
      #pragma unroll
      for (int bf = 0; bf < NBF; ++bf) {
        short8 bv = *(const short8*)(bp + posOff[bf] + tapOff + kOff);
        acc[0][bf] = __builtin_amdgcn_mfma_f32_16x16x32_bf16(a0, bv, acc[0][bf], 0, 0, 0);
        acc[1][bf] = __builtin_amdgcn_mfma_f32_16x16x32_bf16(a1, bv, acc[1][bf], 0, 0, 0);
      }
    }
  }

  bf16* outb = outp + (long)b * outImgS + ooff;
  #pragma unroll
  for (int mf = 0; mf < 2; ++mf) {
    int coB = mTile + wm * 32 + mf * 16 + quad * 4;
    float4v bv4 = *(const float4v*)(bias + coB);
    #pragma unroll
    for (int bf = 0; bf < NBF; ++bf) {
      float4v v = acc[mf][bf];
      ushort4v o;
      #pragma unroll
      for (int e = 0; e < 4; ++e)
        o[e] = f2bfbits(fmaxf(v[e] + bv4[e], 0.f));
      long coff = oPXW ? (long)((((cc[bf] + 1) & 1) * oPXW) + ((cc[bf] + 1) >> 1)) * oCS
                       : (long)cc[bf] * oCS;
      long oaddr = (long)(oh0 + rr[bf]) * oRS + coff + oCS * 0 + coB;
      *(ushort4v*)(outb + oaddr) = o;
    }
  }
}

// ---------- conv2 (64 -> 128, s2) LDS-staged + T14 async-stage split:
// phase-1 rows are prefetched into registers during phase-0 compute, so the
// second stage's HBM latency hides under MFMA; only the ds_writes remain
// between the barriers.
__global__ __launch_bounds__(128) void conv2_lds(
    const bf16* __restrict__ in, const bf16* __restrict__ wf,
    const float* __restrict__ bias, bf16* __restrict__ outp) {
  __shared__ short8 lds8[2 * 130 * 9];   // 37440 B
  const int lane = threadIdx.x & 63;
  const int h = threadIdx.x >> 6;        // co-half (wave id)
  const int ln = lane & 15, quad = lane >> 4;
  const int oh = blockIdx.x;             // output row 0..63
  const int b = blockIdx.z;

  const bf16* img = in + (long)b * 1081600;
  const short8* s0 = (const short8*)(img + (long)(2 * oh) * 8320);      // rows 2oh,2oh+1
  const short8* s1 = (const short8*)(img + (long)(2 * oh + 2) * 8320);  // rows 2oh+2,2oh+3

  float4v acc[4][4];   // [j4 (co chunk)][bf (pos chunk)]
  #pragma unroll
  for (int j = 0; j < 4; ++j)
    #pragma unroll
    for (int bf = 0; bf < 4; ++bf) acc[j][bf] = {0.f, 0.f, 0.f, 0.f};

  auto compute = [&](int f) {
    #pragma unroll
    for (int tl = 0; tl < 8; ++tl) {
      const int t = 8 * f + tl;
      const int r = (t >> 2) & 1;        // row within phase
      const int dx = t & 3;
      const int pp = dx & 1, cb = dx >> 1;
      const int lbase = (r * 130 + pp * 65 + cb) * 9 + quad;
      const bf16* wt = wf + (long)(t * 4) * 2048 + (long)(2 * h) * 2048 +
                       ln * 32 + quad * 8;
      #pragma unroll
      for (int kc = 0; kc < 2; ++kc) {
        const bf16* wk = wt + kc * 1024;
        short8 a0 = *(const short8*)(wk);          // mc=2h,   j=0
        short8 a1 = *(const short8*)(wk + 512);    // mc=2h,   j=1
        short8 a2 = *(const short8*)(wk + 2048);   // mc=2h+1, j=0
        short8 a3 = *(const short8*)(wk + 2560);   // mc=2h+1, j=1
        #pragma unroll
        for (int bf = 0; bf < 4; ++bf) {
          short8 bv = lds8[lbase + (bf * 16 + ln) * 9 + kc * 4];
          acc[0][bf] = __builtin_amdgcn_mfma_f32_16x16x32_bf16(a0, bv, acc[0][bf], 0, 0, 0);
          acc[1][bf] = __builtin_amdgcn_mfma_f32_16x16x32_bf16(a1, bv, acc[1][bf], 0, 0, 0);
          acc[2][bf] = __builtin_amdgcn_mfma_f32_16x16x32_bf16(a2, bv, acc[2][bf], 0, 0, 0);
          acc[3][bf] = __builtin_amdgcn_mfma_f32_16x16x32_bf16(a3, bv, acc[3][bf], 0, 0, 0);
        }
      }
    }
  };

  // stage phase 0 directly
  for (int i = threadIdx.x; i < 2080; i += 128) {   // 2 rows x 130 pos x 8
    lds8[(i >> 3) * 9 + (i & 7)] = s0[i];
  }
  // T14: issue phase-1 loads now (17 x 16B regs); latency hides under compute(0)
  short8 pre[17];
  #pragma unroll
  for (int it = 0; it < 17; ++it) {
    int i = threadIdx.x + it * 128;
    if (i < 2080) pre[it] = s1[i];
  }
  __syncthreads();
  compute(0);
  __syncthreads();
  #pragma unroll
  for (int it = 0; it < 17; ++it) {
    int i = threadIdx.x + it * 128;
    if (i < 2080) lds8[(i >> 3) * 9 + (i & 7)] = pre[it];
  }
  __syncthreads();
  compute(1);

  // store: zbp parity layout, row oh+1, col map x -> ((x+1)&1)*33 + ((x+1)>>1)
  bf16* outb = outp + (long)b * 557568 + (long)(oh + 1) * 8448;
  #pragma unroll
  for (int j4 = 0; j4 < 4; ++j4) {
    int co = h * 64 + (j4 >> 1) * 32 + (j4 & 1) * 16 + quad * 4;
    float4v bv4 = *(const float4v*)(bias + co);
    #pragma unroll
    for (int bf = 0; bf < 4; ++bf) {
      int x = bf * 16 + ln;
      int col = (((x + 1) & 1) * 33) + ((x + 1) >> 1);
      float4v v = acc[j4][bf];
      ushort4v o;
      #pragma unroll
      for (int e = 0; e < 4; ++e)
        o[e] = f2bfbits(fmaxf(v[e] + bv4[e], 0.f));
      *(ushort4v*)(outb + (long)col * 128 + co) = o;
    }
  }
}

// ------ d1 (concat 256 -> 64): proven R2 structure (17-stride padded LDS,
// 4 classes/block, 1 row) + T14 async-stage split: phase-1 (eup) loads issue
// into registers before phase-0 (fqp) compute; only ds_writes sit between
// the barriers. +52 VGPR, no layout change.
__global__ __launch_bounds__(256) void mfma_d1_lds(
    const bf16* __restrict__ in1, const bf16* __restrict__ in2,
    const bf16* __restrict__ wf, const float* __restrict__ bias,
    bf16* __restrict__ outp) {
  __shared__ short8 lds8[198 * 17];   // 53856 B
  const int lane = threadIdx.x & 63, wv = threadIdx.x >> 6;
  const int ln = lane & 15, quad = lane >> 4;
  const int r = blockIdx.x;          // output class-row 0..63
  const int b = blockIdx.z;
  const int cls = wv, p = cls >> 1, q = cls & 1;

  const bf16* src1 = in1 + (long)b * 557568 + (long)r * 8448;  // rows r..r+2
  const bf16* src2 = in2 + (long)b * 557568 + (long)r * 8448;

  float4v acc[4][4];
  #pragma unroll
  for (int j = 0; j < 4; ++j)
    #pragma unroll
    for (int bf = 0; bf < 4; ++bf) acc[j][bf] = {0.f, 0.f, 0.f, 0.f};

  auto compute = [&](int phase) {
    #pragma unroll
    for (int t = 0; t < 4; ++t) {
      int dy = p - (t >> 1) + 1, dx = q - (t & 1) + 1;
      const bf16* wt = wf + (long)(cls * 4 + t) * 16384 + (long)(phase * 4) * 2048 +
                       ln * 32 + quad * 8;
      const int lbase = (dy * 66 + dx) * 17 + quad;
      #pragma unroll
      for (int kc = 0; kc < 4; ++kc) {
        const bf16* wk = wt + kc * 2048;
        short8 a0 = *(const short8*)(wk);
        short8 a1 = *(const short8*)(wk + 512);
        short8 a2 = *(const short8*)(wk + 1024);
        short8 a3 = *(const short8*)(wk + 1536);
        #pragma unroll
        for (int bf = 0; bf < 4; ++bf) {
          short8 bv = lds8[lbase + kc * 4 + (bf * 16 + ln) * 17];
          acc[0][bf] = __builtin_amdgcn_mfma_f32_16x16x32_bf16(a0, bv, acc[0][bf], 0, 0, 0);
          acc[1][bf] = __builtin_amdgcn_mfma_f32_16x16x32_bf16(a1, bv, acc[1][bf], 0, 0, 0);
          acc[2][bf] = __builtin_amdgcn_mfma_f32_16x16x32_bf16(a2, bv, acc[2][bf], 0, 0, 0);
          acc[3][bf] = __builtin_amdgcn_mfma_f32_16x16x32_bf16(a3, bv, acc[3][bf], 0, 0, 0);
        }
      }
    }
  };

  // stage phase 0 (fqp) directly
  for (int i = threadIdx.x; i < 3168; i += 256) {   // 198 pos x 16 chunks
    lds8[(i >> 4) * 17 + (i & 15)] = *(const short8*)(src1 + (long)(i >> 4) * 128 + (i & 15) * 8);
  }
  // T14: issue phase-1 (eup) loads now; latency hides under compute(0)
  short8 pre[13];
  #pragma unroll
  for (int it = 0; it < 13; ++it) {
    int i = threadIdx.x + it * 256;
    if (i < 3168) pre[it] = *(const short8*)(src2 + (long)(i >> 4) * 128 + (i & 15) * 8);
  }
  __syncthreads();
  compute(0);
  __syncthreads();
  #pragma unroll
  for (int it = 0; it < 13; ++it) {
    int i = threadIdx.x + it * 256;
    if (i < 3168) lds8[(i >> 4) * 17 + (i & 15)] = pre[it];
  }
  __syncthreads();
  compute(1);

  bf16* outb = outp + (long)b * 1081600 + (long)(p + 1) * 8320 + (long)(q + 1) * 64 +
               (long)r * 16640;
  #pragma unroll
  for (int j = 0; j < 4; ++j) {
    int co = j * 16 + quad * 4;
    float4v bv4 = *(const float4v*)(bias + co);
    #pragma unroll
    for (int bf = 0; bf < 4; ++bf) {
      float4v v = acc[j][bf];
      ushort4v o;
      #pragma unroll
      for (int e = 0; e < 4; ++e)
        o[e] = f2bfbits(fmaxf(v[e] + bv4[e], 0.f));
      *(ushort4v*)(outb + (long)(bf * 16 + ln) * 128 + co) = o;
    }
  }
}

// ---------------------------------------------------- VQ via MFMA GEMM
__global__ __launch_bounds__(256) void vq_mfma(
    const bf16* __restrict__ z, long zImgS, int zRowS,
    const bf16* __restrict__ emb, const float* __restrict__ embsq,
    bf16* __restrict__ zq, long qImgS, int qRowS,
    float* __restrict__ loss_acc, int wb, int hwb, int ipxw) {
  const int lane = threadIdx.x & 63, wv = threadIdx.x >> 6;
  const int ln = lane & 15, quad = lane >> 4;
  const int base = blockIdx.x * 256 + wv * 64;

  short8 bfrag[4][4];
  #pragma unroll
  for (int bf = 0; bf < 4; ++bf) {
    int n = base + bf * 16 + ln;
    int b = n >> hwb;
    int rem = n & ((1 << hwb) - 1);
    int y = rem >> wb, x = rem & ((1 << wb) - 1);
    int xcol = ipxw ? ((((x + 1) & 1) * ipxw) + ((x + 1) >> 1)) : x;
    const bf16* zrow = z + (long)b * zImgS + (long)y * zRowS + (long)xcol * 128;
    #pragma unroll
    for (int kc = 0; kc < 4; ++kc)
      bfrag[bf][kc] = *(const short8*)(zrow + kc * 32 + quad * 8);
  }

  float best0 = 3.4e38f, best1 = 3.4e38f, best2 = 3.4e38f, best3 = 3.4e38f;
  int bk0 = 0, bk1 = 0, bk2 = 0, bk3 = 0;
  for (int ct = 0; ct < 32; ++ct) {
    const bf16* erow = emb + (long)(ct * 16 + ln) * 128 + quad * 8;
    short8 a0 = *(const short8*)(erow);
    short8 a1 = *(const short8*)(erow + 32);
    short8 a2 = *(const short8*)(erow + 64);
    short8 a3 = *(const short8*)(erow + 96);
    float4v sq4 = *(const float4v*)(embsq + ct * 16 + quad * 4);
    #pragma unroll
    for (int bf = 0; bf < 4; ++bf) {
      float4v acc = {0.f, 0.f, 0.f, 0.f};
      acc = __builtin_amdgcn_mfma_f32_16x16x32_bf16(a0, bfrag[bf][0], acc, 0, 0, 0);
      acc = __builtin_amdgcn_mfma_f32_16x16x32_bf16(a1, bfrag[bf][1], acc, 0, 0, 0);
      acc = __builtin_amdgcn_mfma_f32_16x16x32_bf16(a2, bfrag[bf][2], acc, 0, 0, 0);
      acc = __builtin_amdgcn_mfma_f32_16x16x32_bf16(a3, bfrag[bf][3], acc, 0, 0, 0);
      int kb = ct * 16 + quad * 4;
      #pragma unroll
      for (int r = 0; r < 4; ++r) {
        float s = fmaf(-2.f, acc[r], sq4[r]);
        if (bf == 0) { if (s < best0) { best0 = s; bk0 = kb + r; } }
        if (bf == 1) { if (s < best1) { best1 = s; bk1 = kb + r; } }
        if (bf == 2) { if (s < best2) { best2 = s; bk2 = kb + r; } }
        if (bf == 3) { if (s < best3) { best3 = s; bk3 = kb + r; } }
      }
    }
  }
  float bs[4] = {best0, best1, best2, best3};
  int bk[4] = {bk0, bk1, bk2, bk3};
  #pragma unroll
  for (int bf = 0; bf < 4; ++bf) {
    #pragma unroll
    for (int m = 16; m <= 32; m <<= 1) {
      float os = __shfl_xor(bs[bf], m, 64);
      int ok = __shfl_xor(bk[bf], m, 64);
      if (os < bs[bf] || (os == bs[bf] && ok < bk[bf])) { bs[bf] = os; bk[bf] = ok; }
    }
  }
  int myk = (quad == 0) ? bk[0] : (quad == 1) ? bk[1] : (quad == 2) ? bk[2] : bk[3];
  int n = base + quad * 16 + ln;
  int b = n >> hwb;
  int rem = n & ((1 << hwb) - 1);
  int y = rem >> wb, x = rem & ((1 << wb) - 1);
  int xcol = ipxw ? ((((x + 1) & 1) * ipxw) + ((x + 1) >> 1)) : x;
  const uint4* zr = (const uint4*)(z + (long)b * zImgS + (long)y * zRowS + (long)xcol * 128);
  uint4* qr = (uint4*)(zq + (long)b * qImgS + (long)y * qRowS + (long)x * 128);
  const uint4* er = (const uint4*)(emb + (long)myk * 128);
  float lsum = 0.f;
  #pragma unroll
  for (int j = 0; j < 16; ++j) {
    uint4 ue = er[j];
    uint4 uz = zr[j];
    qr[j] = ue;
    float ev[8], zv[8];
    unpack_u4(ue, ev);
    unpack_u4(uz, zv);
    #pragma unroll
    for (int e = 0; e < 8; ++e) {
      float dv = ev[e] - zv[e];
      lsum = fmaf(dv, dv, lsum);
    }
  }
  for (int o = 32; o > 0; o >>= 1) lsum += __shfl_down(lsum, o, 64);
  if (lane == 0) atomicAdd(loss_acc, lsum);
}

// --------------------- final convT(64->3)+sigmoid via class-packed MFMA
__global__ __launch_bounds__(256) void final_convt_mfma(
    const bf16* __restrict__ hp, const bf16* __restrict__ wfin,
    const float* __restrict__ bf_, float* __restrict__ out) {
  const int lane = threadIdx.x & 63, wv = threadIdx.x >> 6;
  const int ln = lane & 15, quad = lane >> 4;
  const int base = blockIdx.x * 256 + wv * 64;   // 262144 positions total

  short8 afr[18];
  #pragma unroll
  for (int kc = 0; kc < 18; ++kc)
    afr[kc] = *(const short8*)(wfin + ln * 576 + kc * 32 + quad * 8);

  float4v acc[4];
  #pragma unroll
  for (int bf = 0; bf < 4; ++bf) acc[bf] = {0.f, 0.f, 0.f, 0.f};

  #pragma unroll
  for (int bf = 0; bf < 4; ++bf) {
    int n = base + bf * 16 + ln;
    int xx = n & 127, y = (n >> 7) & 127, b = n >> 14;
    const bf16* hb = hp + (long)b * 1081600 + (long)y * 8320 + (long)xx * 64;
    #pragma unroll
    for (int kc = 0; kc < 18; ++kc) {
      int d = kc >> 1;
      const bf16* bp = hb + (long)(d / 3) * 8320 + (d % 3) * 64 + (kc & 1) * 32 + quad * 8;
      short8 bv = *(const short8*)bp;
      acc[bf] = __builtin_amdgcn_mfma_f32_16x16x32_bf16(afr[kc], bv, acc[bf], 0, 0, 0);
    }
  }

  const int p = quad >> 1, q = quad & 1;
  float b0 = bf_[0], b1 = bf_[1], b2 = bf_[2];
  #pragma unroll
  for (int bf = 0; bf < 4; ++bf) {
    int n = base + bf * 16 + ln;
    int xx = n & 127, y = (n >> 7) & 127, b = n >> 14;
    long ob = (long)b * 196608 + (long)(2 * y + p) * 256 + (2 * xx + q);
    float v0 = acc[bf][0] + b0, v1 = acc[bf][1] + b1, v2 = acc[bf][2] + b2;
    out[ob]          = 1.f / (1.f + expf(-v0));
    out[ob + 65536]  = 1.f / (1.f + expf(-v1));
    out[ob + 131072] = 1.f / (1.f + expf(-v2));
  }
}

__global__ void finalize_loss_kernel(const float* __restrict__ lacc, float* __restrict__ out) {
  if (threadIdx.x == 0) {
    float lt = lacc[0] * (1.5f / 2097152.f);
    float lb = lacc[1] * (1.5f / 8388608.f);
    *out = lt + lb;
  }
}

// ------------------------------------------------------------------ launch
extern "C" void kernel_launch(void* const* d_in, const int* in_sizes, int n_in,
                              void* d_out, int out_size, void* d_ws, size_t ws_size,
                              hipStream_t stream) {
  float* out = (float*)d_out;
  char* base = (char*)d_ws;
  size_t off = 0;
  auto alloc = [&](size_t bytes) {
    void* pp = base + off;
    off = (off + bytes + 255) & ~(size_t)255;
    return pp;
  };

  int* flag = (int*)alloc(256);
  float* biasAll = (float*)alloc(515 * 4);
  float* beB1f = biasAll + 0;
  float* beB2f = biasAll + 64;
  float* beTf  = biasAll + 192;
  float* bdTf  = biasAll + 320;
  float* bd1f  = biasAll + 448;
  float* bd2f  = biasAll + 512;
  float* sqAll = (float*)alloc(1024 * 4);
  float* sqT = sqAll, *sqB = sqAll + 512;
  float* lacc = (float*)alloc(2 * 4);
  bf16* Wc1  = (bf16*)alloc((size_t)4096 * 2);
  bf16* Wt2f = (bf16*)alloc((size_t)131072 * 2);
  bf16* Wttf = (bf16*)alloc((size_t)262144 * 2);
  bf16* Wdtf = (bf16*)alloc((size_t)262144 * 2);
  bf16* Wd1f = (bf16*)alloc((size_t)262144 * 2);
  bf16* Wfin = (bf16*)alloc((size_t)9216 * 2);
  bf16* embTB = (bf16*)alloc((size_t)131072 * 2);
  bf16* embT = embTB, *embB = embTB + 65536;
  bf16* act1p = (bf16*)alloc((size_t)17305600 * 2);  // [16][130][2][65][64] parity
  bf16* zbp   = (bf16*)alloc((size_t)8921088 * 2);   // [16][66][2][33][128] parity
  bf16* zqtp  = (bf16*)alloc((size_t)2367488 * 2);   // [16][34][34][128]
  bf16* eup   = (bf16*)alloc((size_t)8921088 * 2);   // [16][66][66][128]
  bf16* fqp   = (bf16*)alloc((size_t)8921088 * 2);   // [16][66][66][128]
  bf16* hp    = (bf16*)alloc((size_t)17305600 * 2);  // [16][130][130][64]
  bf16* ztp   = (bf16*)alloc((size_t)2097152 * 2);   // [16][32][32][128]

  // 3 setup launches
  detect_dtype_kernel<<<1, 256, 0, stream>>>(d_in[0], flag, lacc);
  zero_halo_all<<<1428, 256, 0, stream>>>(act1p, hp, zbp, eup, fqp, zqtp);
  setup_all<<<4155, 256, 0, stream>>>(
      d_in[2], d_in[4], d_in[6], d_in[10], d_in[12], d_in[14],
      d_in[7], d_in[8], d_in[1], d_in[13], d_in[11], d_in[3],
      d_in[5], d_in[9],
      biasAll, embTB, sqAll, Wc1, Wfin, Wd1f, Wt2f, Wttf, Wdtf, flag);

  // encoder: conv1 = fused im2col gather + MFMA GEMM (parity-split store)
  gemm1_fused<<<2048, 256, 0, stream>>>(d_in[0], flag, Wc1, beB1f, act1p);
  // conv2: LDS-staged + T14, wave M64xN64, 1024 blocks x 128 threads
  conv2_lds<<<dim3(64, 1, 16), 128, 0, stream>>>(act1p, Wt2f, beB2f, zbp);
  // conv_t: PXW=33 (zbp parity), output ztp row-major
  mfma_conv<128, 128, 32, 2, 16, 128, 2, 33><<<dim3(16, 2, 16), 256, 0, stream>>>(
      zbp, zbp, 557568, 8448, Wttf, beTf, ztp, 131072, 4096, 128, 30, 0, 0, 0);

  // VQ top (16384 positions, row-major)
  vq_mfma<<<64, 256, 0, stream>>>(ztp, 131072, 4096, embT, sqT,
                                  zqtp + 4480, 147968, 4352, lacc + 0, 5, 10, 0);

  // decoder_top upsample: 4 classes in one launch (row-major in/out)
  mfma_conv<128, 128, 32, 1, 4, 128, 2, 0><<<dim3(64, 2, 16), 256, 0, stream>>>(
      zqtp, zqtp, 147968, 4352, Wdtf, bdTf, eup, 557568, 16896, 256, 4, 8448, 128, 0);

  // VQ bottom (65536 positions; zbp parity-split input, fqp row-major out)
  vq_mfma<<<256, 256, 0, stream>>>(zbp + 8448, 557568, 8448, embB, sqB,
                                   fqp + 8576, 557568, 8448, lacc + 1, 6, 12, 33);

  // decoder conv d1: LDS-staged + T14, 4 classes per block, 1024 blocks
  mfma_d1_lds<<<dim3(64, 1, 16), 256, 0, stream>>>(fqp, eup, Wd1f, bd1f, hp);

  // final convT + sigmoid via MFMA -> fp32 NCHW output
  final_convt_mfma<<<1024, 256, 0, stream>>>(hp, Wfin, bd2f, out);
  finalize_loss_kernel<<<1, 64, 0, stream>>>(lacc, out + 3145728);
}

// Round 6
// 465.054 us; speedup vs baseline: 1.1073x; 1.0254x over previous
//
#include <hip/hip_runtime.h>
#include <hip/hip_bf16.h>
#include <cstddef>

typedef __hip_bfloat16 bf16;
typedef __attribute__((ext_vector_type(8))) short short8;
typedef __attribute__((ext_vector_type(4))) float float4v;
typedef __attribute__((ext_vector_type(4))) unsigned short ushort4v;

static __device__ __forceinline__ float b2f(bf16 v) { return __bfloat162float(v); }
static __device__ __forceinline__ float bits2f(unsigned int u) { return __uint_as_float(u); }
static __device__ __forceinline__ unsigned short f2bfbits(float f) {
  bf16 h = __float2bfloat16(f);
  return *reinterpret_cast<unsigned short*>(&h);
}
static __device__ __forceinline__ float ld_any(const void* p, long i, int flag) {
  return flag ? b2f(((const bf16*)p)[i]) : ((const float*)p)[i];
}
static __device__ __forceinline__ void unpack_u4(uint4 u, float* f) {
  f[0] = bits2f(u.x << 16); f[1] = bits2f(u.x & 0xffff0000u);
  f[2] = bits2f(u.y << 16); f[3] = bits2f(u.y & 0xffff0000u);
  f[4] = bits2f(u.z << 16); f[5] = bits2f(u.z & 0xffff0000u);
  f[6] = bits2f(u.w << 16); f[7] = bits2f(u.w & 0xffff0000u);
}

// --------------------------------- dtype detection (+ loss accumulator zero)
__global__ void detect_dtype_kernel(const void* __restrict__ x, int* __restrict__ flag,
                                    float* __restrict__ lacc) {
  if (threadIdx.x < 2) lacc[threadIdx.x] = 0.f;
  __shared__ int ok;
  if (threadIdx.x == 0) ok = 1;
  __syncthreads();
  float v = b2f(((const bf16*)x)[threadIdx.x]);
  if (!(v >= 0.f && v <= 1.0009765625f)) ok = 0;
  __syncthreads();
  if (threadIdx.x == 0) *flag = ok;
}

// ------------------------------------------------- fused halo-ring zeroing
static __device__ __forceinline__ void halo_seg(bf16* p0, bf16* p1, bf16* p2,
                                                int np, int H, int W, int C8,
                                                long imgS, int gpi, int r) {
  int total = 16 * gpi;
  int which = r / total;
  if (which >= np) return;
  int rr = r - which * total;
  int img = rr / gpi, g = rr % gpi;
  int pos = g / C8, c8 = g % C8;
  int row, col;
  if (pos < W) { row = 0; col = pos; }
  else if (pos < 2 * W) { row = H - 1; col = pos - W; }
  else { int s = pos - 2 * W; row = 1 + (s >> 1); col = (s & 1) ? (W - 1) : 0; }
  bf16* base = (which == 0) ? p0 : ((which == 1) ? p1 : p2);
  uint4* dst = (uint4*)(base + (long)img * imgS + ((long)row * W + col) * (C8 * 8) + (long)c8 * 8);
  *dst = uint4{0u, 0u, 0u, 0u};
}

__global__ __launch_bounds__(256) void zero_halo_all(bf16* act1p, bf16* hp,
                                                     bf16* zbp, bf16* eup, bf16* fqp,
                                                     bf16* zqtp) {
  int tid = blockIdx.x * 256 + threadIdx.x;
  if (tid < 132096) { halo_seg(act1p, hp, nullptr, 2, 130, 130, 8, 1081600, 4128, tid); return; }
  tid -= 132096;
  if (tid < 199680) { halo_seg(zbp, eup, fqp, 3, 66, 66, 16, 557568, 4160, tid); return; }
  tid -= 199680;
  if (tid < 33792)  { halo_seg(zqtp, nullptr, nullptr, 1, 34, 34, 16, 147968, 2112, tid); }
}

// ---------------- all converts / repacks fused into one kernel (segmented).
__global__ __launch_bounds__(256) void setup_all(
    const void* s2, const void* s4, const void* s6,
    const void* s10, const void* s12, const void* s14,
    const void* sT, const void* sB, const void* c1s,
    const void* fins, const void* d1s, const void* t2s,
    const void* tts, const void* dts,
    float* __restrict__ biasAll, bf16* __restrict__ embTB,
    float* __restrict__ sqAll, bf16* __restrict__ Wc1,
    bf16* __restrict__ Wfin, bf16* __restrict__ Wd1f,
    bf16* __restrict__ Wt2f, bf16* __restrict__ Wttf,
    bf16* __restrict__ Wdtf, const int* __restrict__ flag) {
  long i = (long)blockIdx.x * 256 + threadIdx.x;
  const int fl = *flag;
  // seg0: 6 conv biases -> one fp32 buffer [515]
  if (i < 515) {
    const void* s; long off;
    if (i < 64)       { s = s2;  off = i; }
    else if (i < 192) { s = s4;  off = i - 64; }
    else if (i < 320) { s = s6;  off = i - 192; }
    else if (i < 448) { s = s10; off = i - 320; }
    else if (i < 512) { s = s12; off = i - 448; }
    else              { s = s14; off = i - 512; }
    biasAll[i] = ld_any(s, off, fl);
    return;
  }
  i -= 515;
  // seg1: both codebooks -> contiguous bf16 [1024][128]
  if (i < 131072) {
    const void* s = (i < 65536) ? sT : sB;
    long off = i & 65535;
    embTB[i] = fl ? ((const bf16*)s)[off] : __float2bfloat16(((const float*)s)[off]);
    return;
  }
  i -= 131072;
  // seg2: emb row sum-of-squares from RAW src through identical bf16 rounding
  if (i < 1024) {
    const void* s = (i < 512) ? sT : sB;
    long base = (i & 511) * 128;
    float acc = 0.f;
    for (int c = 0; c < 128; ++c) {
      float v = b2f(__float2bfloat16(ld_any(s, base + c, fl)));
      acc = fmaf(v, v, acc);
    }
    sqAll[i] = acc;
    return;
  }
  i -= 1024;
  // seg3: conv1 weights [64][3][4][4] -> [co][k], K padded 48->64 [4096]
  if (i < 4096) {
    int co = (int)i >> 6, k = (int)i & 63;
    float v = (k < 48) ? ld_any(c1s, co * 48 + k, fl) : 0.f;
    Wc1[i] = __float2bfloat16(v);
    return;
  }
  i -= 4096;
  // seg4: final convT weights -> A[m=cls*4+co][d=dy*3+dx][64ci] [9216]
  if (i < 9216) {
    int m = (int)i / 576, rem = (int)i % 576;
    int d = rem >> 6, ci = rem & 63;
    int cls = m >> 2, co = m & 3;
    int p = cls >> 1, q = cls & 1;
    int dy = d / 3, dx = d % 3;
    int s_ = p - dy + 1, t_ = q - dx + 1;
    float v = 0.f;
    if (co < 3 && s_ >= 0 && s_ <= 1 && t_ >= 0 && t_ <= 1) {
      int kh = 2 * s_ + 1 - p, kw = 2 * t_ + 1 - q;
      v = ld_any(fins, ci * 48 + co * 16 + kh * 4 + kw, fl);
    }
    Wfin[i] = __float2bfloat16(v);
    return;
  }
  i -= 9216;
  // seg5: d1 weights [256ci][64co][4][4] -> frag [262144]
  if (i < 262144) {
    int low = (int)i & 511;
    int ln = low >> 5, cl = low & 31;
    int c2 = (int)(i >> 9);
    int j = c2 & 3;
    int kc = (c2 >> 2) & 7;
    int t = (c2 >> 5) & 3;
    int cls = c2 >> 7;
    int p = cls >> 1, q = cls & 1;
    int s_ = t >> 1, t2 = t & 1;
    int kh = 2 * s_ + 1 - p, kw = 2 * t2 + 1 - q;
    int co = j * 16 + ln, ci = kc * 32 + cl;
    Wd1f[i] = __float2bfloat16(ld_any(d1s, (long)ci * 1024 + co * 16 + kh * 4 + kw, fl));
    return;
  }
  i -= 262144;
  // seg6: conv2 weights OIHW[128][64][4][4] -> frag direct (MC=4,KC=2) [131072]
  if (i < 131072) {
    int low = (int)i & 511;
    int ln = low >> 5, cl = low & 31;
    int c2 = (int)(i >> 9);
    int j = c2 & 1, c3 = c2 >> 1;
    int kc = c3 & 1, c4 = c3 >> 1;
    int mc = c4 & 3, tg = c4 >> 2;
    int co = mc * 32 + j * 16 + ln, ci = kc * 32 + cl;
    Wt2f[i] = __float2bfloat16(ld_any(t2s, (long)co * 1024 + ci * 16 + tg, fl));
    return;
  }
  i -= 131072;
  // seg7: conv_t weights OIHW[128][128][4][4] -> frag direct (MC=4,KC=4) [262144]
  if (i < 262144) {
    int low = (int)i & 511;
    int ln = low >> 5, cl = low & 31;
    int c2 = (int)(i >> 9);
    int j = c2 & 1, c3 = c2 >> 1;
    int kc = c3 & 3, c4 = c3 >> 2;
    int mc = c4 & 3, tg = c4 >> 2;
    int co = mc * 32 + j * 16 + ln, ci = kc * 32 + cl;
    Wttf[i] = __float2bfloat16(ld_any(tts, (long)co * 2048 + ci * 16 + tg, fl));
    return;
  }
  i -= 262144;
  // seg8: convT dt weights [128ci][128co][4][4] -> class frag direct [262144]
  if (i < 262144) {
    int low = (int)i & 511;
    int ln = low >> 5, cl = low & 31;
    int c2 = (int)(i >> 9);
    int j = c2 & 1, c3 = c2 >> 1;
    int kc = c3 & 3, c4 = c3 >> 2;
    int mc = c4 & 3, tg = c4 >> 2;
    int co = mc * 32 + j * 16 + ln, ci = kc * 32 + cl;
    int cls = tg >> 2, st = tg & 3;
    int p = cls >> 1, q = cls & 1;
    int s_ = st >> 1, tt_ = st & 1;
    int kh = 2 * s_ + 1 - p, kw = 2 * tt_ + 1 - q;
    Wdtf[i] = __float2bfloat16(ld_any(dts, (long)ci * 2048 + co * 16 + kh * 4 + kw, fl));
    return;
  }
}

// -------------------- conv1 fused: inline im2col gather + MFMA GEMM
__global__ __launch_bounds__(256) void gemm1_fused(
    const void* __restrict__ x, const int* __restrict__ flag,
    const bf16* __restrict__ w, const float* __restrict__ bias,
    bf16* __restrict__ act1p) {
  const int lane = threadIdx.x & 63, wv = threadIdx.x >> 6;
  const int wm = wv & 1, wn = wv >> 1;
  const int ln = lane & 15, quad = lane >> 4;
  const int n0 = blockIdx.x * 128 + wn * 64;
  const int fl = *flag;
  float4v acc[2][4];
  #pragma unroll
  for (int i = 0; i < 2; ++i)
    #pragma unroll
    for (int j = 0; j < 4; ++j) acc[i][j] = {0.f, 0.f, 0.f, 0.f};
  #pragma unroll
  for (int kc = 0; kc < 2; ++kc) {
    const bf16* wk = w + (wm * 32 + ln) * 64 + kc * 32 + quad * 8;
    short8 a0 = *(const short8*)(wk);
    short8 a1 = *(const short8*)(wk + 16 * 64);
    const int k0 = kc * 32 + quad * 8;      // 0,8,...,56; >=48 is zero-pad
    #pragma unroll
    for (int bf = 0; bf < 4; ++bf) {
      short8 bv;
      if (k0 >= 48) {
        bv = (short8){0, 0, 0, 0, 0, 0, 0, 0};
      } else {
        int n = n0 + bf * 16 + ln;
        int ow = n & 127, oh = (n >> 7) & 127, b = n >> 14;
        int ci = k0 >> 4;
        int kh0 = (k0 & 15) >> 2;           // 0 or 2
        long pbase = ((long)(b * 3 + ci)) << 16;
        int iw0 = ow * 2 - 1;
        unsigned short tmp[8];
        #pragma unroll
        for (int r = 0; r < 2; ++r) {
          int ih = oh * 2 - 1 + kh0 + r;
          bool okh = (unsigned)ih < 256u;
          long rbase = pbase + ((long)ih << 8);
          #pragma unroll
          for (int c = 0; c < 4; ++c) {
            int iw = iw0 + c;
            float v = (okh && (unsigned)iw < 256u) ? ld_any(x, rbase + iw, fl) : 0.f;
            tmp[r * 4 + c] = f2bfbits(v);
          }
        }
        bv = *(const short8*)tmp;
      }
      acc[0][bf] = __builtin_amdgcn_mfma_f32_16x16x32_bf16(a0, bv, acc[0][bf], 0, 0, 0);
      acc[1][bf] = __builtin_amdgcn_mfma_f32_16x16x32_bf16(a1, bv, acc[1][bf], 0, 0, 0);
    }
  }
  #pragma unroll
  for (int mf = 0; mf < 2; ++mf) {
    int coB = wm * 32 + mf * 16 + quad * 4;
    float4v bv4 = *(const float4v*)(bias + coB);
    #pragma unroll
    for (int bf = 0; bf < 4; ++bf) {
      int n = n0 + bf * 16 + ln;
      int ow = n & 127; int t2 = n >> 7;
      int oh = t2 & 127; int b = t2 >> 7;
      int xx = ow + 1;   // parity-split column
      long oaddr = ((long)(b * 130 + oh + 1)) * 8320 +
                   (long)(((xx & 1) * 65) + (xx >> 1)) * 64 + coB;
      float4v v = acc[mf][bf];
      ushort4v o;
      #pragma unroll
      for (int e = 0; e < 4; ++e) o[e] = f2bfbits(fmaxf(v[e] + bv4[e], 0.f));
      *(ushort4v*)(act1p + oaddr) = o;
    }
  }
}

// ------------------------------------------- MFMA implicit-GEMM tap conv
template <int COUT, int CINT, int TC, int S, int NT, int INC, int NBF, int PXW>
__global__ __launch_bounds__(256) void mfma_conv(
    const bf16* __restrict__ in1, const bf16* __restrict__ in2,
    long inImgS, int inRowS,
    const bf16* __restrict__ wf, const float* __restrict__ bias,
    bf16* __restrict__ outp, long outImgS, int oRS, int oCS,
    int nxb, long po, long qo, int oPXW) {
  constexpr int TR = (2 * NBF * 16) / TC;
  constexpr int KC = CINT / 32;
  constexpr int MC = COUT / 32;
  constexpr int KSPLIT = (CINT > INC) ? (INC / 32) : KC;
  const int lane = threadIdx.x & 63;
  const int wv = threadIdx.x >> 6;
  const int wm = wv & 1, wn = wv >> 1;
  const int ln = lane & 15, quad = lane >> 4;
  const int cls = blockIdx.x >> nxb;
  const int xb = blockIdx.x & ((1u << nxb) - 1u);
  const int mTile = blockIdx.y * 64;
  const int mc = blockIdx.y * 2 + wm;
  const int oh0 = xb * TR;
  const int b = blockIdx.z;
  const int p = cls >> 1, q = cls & 1;
  const long ooff = (long)(p + 1) * po + (long)(q + 1) * qo;

  long posOff[NBF];
  int rr[NBF], cc[NBF];
  #pragma unroll
  for (int bf = 0; bf < NBF; ++bf) {
    int n = wn * (NBF * 16) + bf * 16 + ln;
    int r = n / TC, c = n % TC;
    rr[bf] = r; cc[bf] = c;
    posOff[bf] = (long)(S * (oh0 + r)) * inRowS +
                 (PXW ? (long)c * INC : (long)(S * c) * INC);
  }
  const bf16* inb1 = in1 + (long)b * inImgS;
  const bf16* inb2 = in2 + (long)b * inImgS;

  float4v acc[2][NBF];
  #pragma unroll
  for (int i = 0; i < 2; ++i)
    #pragma unroll
    for (int j = 0; j < NBF; ++j) acc[i][j] = {0.f, 0.f, 0.f, 0.f};

  for (int t = 0; t < NT; ++t) {
    int dy, dx;
    if (S == 2) { dy = t >> 2; dx = t & 3; }
    else        { dy = p - (t >> 1) + 1; dx = q - (t & 1) + 1; }
    const int dxo = PXW ? ((dx & 1) * PXW + (dx >> 1)) : dx;
    const long tapOff = (long)dy * inRowS + (long)dxo * INC;
    const bf16* wt = wf + ((long)(cls * NT + t) * MC + mc) * (KC * 1024) + ln * 32 + quad * 8;
    #pragma unroll
    for (int kc = 0; kc < KC; ++kc) {
      short8 a0 = *(const short8*)(wt + kc * 1024);
      short8 a1 = *(const short8*)(wt + kc * 1024 + 512);
      const bf16* bp = (kc < KSPLIT) ? inb1 : inb2;
      int kOff = (kc < KSPLIT ? kc : kc - KSPLIT) * 32 + quad * 8;
      #pragma unroll
      for (int bf = 0; bf < NBF; ++bf) {
        short8 bv = *(const short8*)(bp + posOff[bf] + tapOff + kOff);
        acc[0][bf] = __builtin_amdgcn_mfma_f32_16x16x32_bf16(a0, bv, acc[0][bf], 0, 0, 0);
        acc[1][bf] = __builtin_amdgcn_mfma_f32_16x16x32_bf16(a1, bv, acc[1][bf], 0, 0, 0);
      }
    }
  }

  bf16* outb = outp + (long)b * outImgS + ooff;
  #pragma unroll
  for (int mf = 0; mf < 2; ++mf) {
    int coB = mTile + wm * 32 + mf * 16 + quad * 4;
    float4v bv4 = *(const float4v*)(bias + coB);
    #pragma unroll
    for (int bf = 0; bf < NBF; ++bf) {
      float4v v = acc[mf][bf];
      ushort4v o;
      #pragma unroll
      for (int e = 0; e < 4; ++e)
        o[e] = f2bfbits(fmaxf(v[e] + bv4[e], 0.f));
      long coff = oPXW ? (long)((((cc[bf] + 1) & 1) * oPXW) + ((cc[bf] + 1) >> 1)) * oCS
                       : (long)cc[bf] * oCS;
      long oaddr = (long)(oh0 + rr[bf]) * oRS + coff + oCS * 0 + coB;
      *(ushort4v*)(outb + oaddr) = o;
    }
  }
}

// ---------- conv2 (64 -> 128, s2): LDS-staged + T14, now 256 threads /
// 4 waves (wave w owns co-quarter mc=w) -> 16 waves/CU at 4 blocks/CU
// (was 8 with 128-thread blocks). Same LDS, weights, traffic; 2x waves
// to hide L2/HBM latency. acc[2][4] (32 VGPR) per wave.
__global__ __launch_bounds__(256) void conv2_lds(
    const bf16* __restrict__ in, const bf16* __restrict__ wf,
    const float* __restrict__ bias, bf16* __restrict__ outp) {
  __shared__ short8 lds8[2 * 130 * 9];   // 37440 B
  const int lane = threadIdx.x & 63;
  const int w = threadIdx.x >> 6;        // co-quarter (wave id, mc=w)
  const int ln = lane & 15, quad = lane >> 4;
  const int oh = blockIdx.x;             // output row 0..63
  const int b = blockIdx.z;

  const bf16* img = in + (long)b * 1081600;
  const short8* s0 = (const short8*)(img + (long)(2 * oh) * 8320);      // rows 2oh,2oh+1
  const short8* s1 = (const short8*)(img + (long)(2 * oh + 2) * 8320);  // rows 2oh+2,2oh+3

  float4v acc[2][4];   // [j (16-co frag)][bf (pos chunk)]
  #pragma unroll
  for (int j = 0; j < 2; ++j)
    #pragma unroll
    for (int bf = 0; bf < 4; ++bf) acc[j][bf] = {0.f, 0.f, 0.f, 0.f};

  auto compute = [&](int f) {
    #pragma unroll
    for (int tl = 0; tl < 8; ++tl) {
      const int t = 8 * f + tl;
      const int r = (t >> 2) & 1;        // row within phase
      const int dx = t & 3;
      const int pp = dx & 1, cb = dx >> 1;
      const int lbase = (r * 130 + pp * 65 + cb) * 9 + quad;
      #pragma unroll
      for (int kc = 0; kc < 2; ++kc) {
        // frag element offset: ((t*4 + mc)*2 + kc)*1024 + j*512
        const bf16* wk = wf + (long)((t * 4 + w) * 2 + kc) * 1024 + ln * 32 + quad * 8;
        short8 a0 = *(const short8*)(wk);          // j=0
        short8 a1 = *(const short8*)(wk + 512);    // j=1
        #pragma unroll
        for (int bf = 0; bf < 4; ++bf) {
          short8 bv = lds8[lbase + (bf * 16 + ln) * 9 + kc * 4];
          acc[0][bf] = __builtin_amdgcn_mfma_f32_16x16x32_bf16(a0, bv, acc[0][bf], 0, 0, 0);
          acc[1][bf] = __builtin_amdgcn_mfma_f32_16x16x32_bf16(a1, bv, acc[1][bf], 0, 0, 0);
        }
      }
    }
  };

  // stage phase 0 directly
  for (int i = threadIdx.x; i < 2080; i += 256) {   // 2 rows x 130 pos x 8
    lds8[(i >> 3) * 9 + (i & 7)] = s0[i];
  }
  // T14: issue phase-1 loads now (9 x 16B regs); latency hides under compute(0)
  short8 pre[9];
  #pragma unroll
  for (int it = 0; it < 9; ++it) {
    int i = threadIdx.x + it * 256;
    if (i < 2080) pre[it] = s1[i];
  }
  __syncthreads();
  compute(0);
  __syncthreads();
  #pragma unroll
  for (int it = 0; it < 9; ++it) {
    int i = threadIdx.x + it * 256;
    if (i < 2080) lds8[(i >> 3) * 9 + (i & 7)] = pre[it];
  }
  __syncthreads();
  compute(1);

  // store: zbp parity layout, row oh+1, col map x -> ((x+1)&1)*33 + ((x+1)>>1)
  bf16* outb = outp + (long)b * 557568 + (long)(oh + 1) * 8448;
  #pragma unroll
  for (int j = 0; j < 2; ++j) {
    int co = w * 32 + j * 16 + quad * 4;
    float4v bv4 = *(const float4v*)(bias + co);
    #pragma unroll
    for (int bf = 0; bf < 4; ++bf) {
      int x = bf * 16 + ln;
      int col = (((x + 1) & 1) * 33) + ((x + 1) >> 1);
      float4v v = acc[j][bf];
      ushort4v o;
      #pragma unroll
      for (int e = 0; e < 4; ++e)
        o[e] = f2bfbits(fmaxf(v[e] + bv4[e], 0.f));
      *(ushort4v*)(outb + (long)col * 128 + co) = o;
    }
  }
}

// ------ d1 (concat 256 -> 64): R2 structure + T14 (frozen; see R3-R5 data)
__global__ __launch_bounds__(256) void mfma_d1_lds(
    const bf16* __restrict__ in1, const bf16* __restrict__ in2,
    const bf16* __restrict__ wf, const float* __restrict__ bias,
    bf16* __restrict__ outp) {
  __shared__ short8 lds8[198 * 17];   // 53856 B
  const int lane = threadIdx.x & 63, wv = threadIdx.x >> 6;
  const int ln = lane & 15, quad = lane >> 4;
  const int r = blockIdx.x;          // output class-row 0..63
  const int b = blockIdx.z;
  const int cls = wv, p = cls >> 1, q = cls & 1;

  const bf16* src1 = in1 + (long)b * 557568 + (long)r * 8448;  // rows r..r+2
  const bf16* src2 = in2 + (long)b * 557568 + (long)r * 8448;

  float4v acc[4][4];
  #pragma unroll
  for (int j = 0; j < 4; ++j)
    #pragma unroll
    for (int bf = 0; bf < 4; ++bf) acc[j][bf] = {0.f, 0.f, 0.f, 0.f};

  auto compute = [&](int phase) {
    #pragma unroll
    for (int t = 0; t < 4; ++t) {
      int dy = p - (t >> 1) + 1, dx = q - (t & 1) + 1;
      const bf16* wt = wf + (long)(cls * 4 + t) * 16384 + (long)(phase * 4) * 2048 +
                       ln * 32 + quad * 8;
      const int lbase = (dy * 66 + dx) * 17 + quad;
      #pragma unroll
      for (int kc = 0; kc < 4; ++kc) {
        const bf16* wk = wt + kc * 2048;
        short8 a0 = *(const short8*)(wk);
        short8 a1 = *(const short8*)(wk + 512);
        short8 a2 = *(const short8*)(wk + 1024);
        short8 a3 = *(const short8*)(wk + 1536);
        #pragma unroll
        for (int bf = 0; bf < 4; ++bf) {
          short8 bv = lds8[lbase + kc * 4 + (bf * 16 + ln) * 17];
          acc[0][bf] = __builtin_amdgcn_mfma_f32_16x16x32_bf16(a0, bv, acc[0][bf], 0, 0, 0);
          acc[1][bf] = __builtin_amdgcn_mfma_f32_16x16x32_bf16(a1, bv, acc[1][bf], 0, 0, 0);
          acc[2][bf] = __builtin_amdgcn_mfma_f32_16x16x32_bf16(a2, bv, acc[2][bf], 0, 0, 0);
          acc[3][bf] = __builtin_amdgcn_mfma_f32_16x16x32_bf16(a3, bv, acc[3][bf], 0, 0, 0);
        }
      }
    }
  };

  // stage phase 0 (fqp) directly
  for (int i = threadIdx.x; i < 3168; i += 256) {   // 198 pos x 16 chunks
    lds8[(i >> 4) * 17 + (i & 15)] = *(const short8*)(src1 + (long)(i >> 4) * 128 + (i & 15) * 8);
  }
  // T14: issue phase-1 (eup) loads now; latency hides under compute(0)
  short8 pre[13];
  #pragma unroll
  for (int it = 0; it < 13; ++it) {
    int i = threadIdx.x + it * 256;
    if (i < 3168) pre[it] = *(const short8*)(src2 + (long)(i >> 4) * 128 + (i & 15) * 8);
  }
  __syncthreads();
  compute(0);
  __syncthreads();
  #pragma unroll
  for (int it = 0; it < 13; ++it) {
    int i = threadIdx.x + it * 256;
    if (i < 3168) lds8[(i >> 4) * 17 + (i & 15)] = pre[it];
  }
  __syncthreads();
  compute(1);

  bf16* outb = outp + (long)b * 1081600 + (long)(p + 1) * 8320 + (long)(q + 1) * 64 +
               (long)r * 16640;
  #pragma unroll
  for (int j = 0; j < 4; ++j) {
    int co = j * 16 + quad * 4;
    float4v bv4 = *(const float4v*)(bias + co);
    #pragma unroll
    for (int bf = 0; bf < 4; ++bf) {
      float4v v = acc[j][bf];
      ushort4v o;
      #pragma unroll
      for (int e = 0; e < 4; ++e)
        o[e] = f2bfbits(fmaxf(v[e] + bv4[e], 0.f));
      *(ushort4v*)(outb + (long)(bf * 16 + ln) * 128 + co) = o;
    }
  }
}

// ---------------------------------------------------- VQ via MFMA GEMM
__global__ __launch_bounds__(256) void vq_mfma(
    const bf16* __restrict__ z, long zImgS, int zRowS,
    const bf16* __restrict__ emb, const float* __restrict__ embsq,
    bf16* __restrict__ zq, long qImgS, int qRowS,
    float* __restrict__ loss_acc, int wb, int hwb, int ipxw) {
  const int lane = threadIdx.x & 63, wv = threadIdx.x >> 6;
  const int ln = lane & 15, quad = lane >> 4;
  const int base = blockIdx.x * 256 + wv * 64;

  short8 bfrag[4][4];
  #pragma unroll
  for (int bf = 0; bf < 4; ++bf) {
    int n = base + bf * 16 + ln;
    int b = n >> hwb;
    int rem = n & ((1 << hwb) - 1);
    int y = rem >> wb, x = rem & ((1 << wb) - 1);
    int xcol = ipxw ? ((((x + 1) & 1) * ipxw) + ((x + 1) >> 1)) : x;
    const bf16* zrow = z + (long)b * zImgS + (long)y * zRowS + (long)xcol * 128;
    #pragma unroll
    for (int kc = 0; kc < 4; ++kc)
      bfrag[bf][kc] = *(const short8*)(zrow + kc * 32 + quad * 8);
  }

  float best0 = 3.4e38f, best1 = 3.4e38f, best2 = 3.4e38f, best3 = 3.4e38f;
  int bk0 = 0, bk1 = 0, bk2 = 0, bk3 = 0;
  for (int ct = 0; ct < 32; ++ct) {
    const bf16* erow = emb + (long)(ct * 16 + ln) * 128 + quad * 8;
    short8 a0 = *(const short8*)(erow);
    short8 a1 = *(const short8*)(erow + 32);
    short8 a2 = *(const short8*)(erow + 64);
    short8 a3 = *(const short8*)(erow + 96);
    float4v sq4 = *(const float4v*)(embsq + ct * 16 + quad * 4);
    #pragma unroll
    for (int bf = 0; bf < 4; ++bf) {
      float4v acc = {0.f, 0.f, 0.f, 0.f};
      acc = __builtin_amdgcn_mfma_f32_16x16x32_bf16(a0, bfrag[bf][0], acc, 0, 0, 0);
      acc = __builtin_amdgcn_mfma_f32_16x16x32_bf16(a1, bfrag[bf][1], acc, 0, 0, 0);
      acc = __builtin_amdgcn_mfma_f32_16x16x32_bf16(a2, bfrag[bf][2], acc, 0, 0, 0);
      acc = __builtin_amdgcn_mfma_f32_16x16x32_bf16(a3, bfrag[bf][3], acc, 0, 0, 0);
      int kb = ct * 16 + quad * 4;
      #pragma unroll
      for (int r = 0; r < 4; ++r) {
        float s = fmaf(-2.f, acc[r], sq4[r]);
        if (bf == 0) { if (s < best0) { best0 = s; bk0 = kb + r; } }
        if (bf == 1) { if (s < best1) { best1 = s; bk1 = kb + r; } }
        if (bf == 2) { if (s < best2) { best2 = s; bk2 = kb + r; } }
        if (bf == 3) { if (s < best3) { best3 = s; bk3 = kb + r; } }
      }
    }
  }
  float bs[4] = {best0, best1, best2, best3};
  int bk[4] = {bk0, bk1, bk2, bk3};
  #pragma unroll
  for (int bf = 0; bf < 4; ++bf) {
    #pragma unroll
    for (int m = 16; m <= 32; m <<= 1) {
      float os = __shfl_xor(bs[bf], m, 64);
      int ok = __shfl_xor(bk[bf], m, 64);
      if (os < bs[bf] || (os == bs[bf] && ok < bk[bf])) { bs[bf] = os; bk[bf] = ok; }
    }
  }
  int myk = (quad == 0) ? bk[0] : (quad == 1) ? bk[1] : (quad == 2) ? bk[2] : bk[3];
  int n = base + quad * 16 + ln;
  int b = n >> hwb;
  int rem = n & ((1 << hwb) - 1);
  int y = rem >> wb, x = rem & ((1 << wb) - 1);
  int xcol = ipxw ? ((((x + 1) & 1) * ipxw) + ((x + 1) >> 1)) : x;
  const uint4* zr = (const uint4*)(z + (long)b * zImgS + (long)y * zRowS + (long)xcol * 128);
  uint4* qr = (uint4*)(zq + (long)b * qImgS + (long)y * qRowS + (long)x * 128);
  const uint4* er = (const uint4*)(emb + (long)myk * 128);
  float lsum = 0.f;
  #pragma unroll
  for (int j = 0; j < 16; ++j) {
    uint4 ue = er[j];
    uint4 uz = zr[j];
    qr[j] = ue;
    float ev[8], zv[8];
    unpack_u4(ue, ev);
    unpack_u4(uz, zv);
    #pragma unroll
    for (int e = 0; e < 8; ++e) {
      float dv = ev[e] - zv[e];
      lsum = fmaf(dv, dv, lsum);
    }
  }
  for (int o = 32; o > 0; o >>= 1) lsum += __shfl_down(lsum, o, 64);
  if (lane == 0) atomicAdd(loss_acc, lsum);
}

// ---------- VQ, 16 positions/wave variant (full-chip grid for small N).
// Wave handles 16 positions (one B fragment); quads split the code subsets
// as in vq_mfma; cross-quad shuffle reduce; copy/loss split 4 chunks/lane.
__global__ __launch_bounds__(256) void vq_mfma16(
    const bf16* __restrict__ z, long zImgS, int zRowS,
    const bf16* __restrict__ emb, const float* __restrict__ embsq,
    bf16* __restrict__ zq, long qImgS, int qRowS,
    float* __restrict__ loss_acc, int wb, int hwb) {
  const int lane = threadIdx.x & 63, wv = threadIdx.x >> 6;
  const int ln = lane & 15, quad = lane >> 4;
  const int base = blockIdx.x * 64 + wv * 16;   // 16 positions per wave

  const int n = base + ln;
  const int b = n >> hwb;
  const int rem = n & ((1 << hwb) - 1);
  const int y = rem >> wb, x = rem & ((1 << wb) - 1);
  const bf16* zrow = z + (long)b * zImgS + (long)y * zRowS + (long)x * 128;
  short8 bfrag[4];
  #pragma unroll
  for (int kc = 0; kc < 4; ++kc)
    bfrag[kc] = *(const short8*)(zrow + kc * 32 + quad * 8);

  float best = 3.4e38f;
  int bk = 0;
  for (int ct = 0; ct < 32; ++ct) {
    const bf16* erow = emb + (long)(ct * 16 + ln) * 128 + quad * 8;
    short8 a0 = *(const short8*)(erow);
    short8 a1 = *(const short8*)(erow + 32);
    short8 a2 = *(const short8*)(erow + 64);
    short8 a3 = *(const short8*)(erow + 96);
    float4v sq4 = *(const float4v*)(embsq + ct * 16 + quad * 4);
    float4v acc = {0.f, 0.f, 0.f, 0.f};
    acc = __builtin_amdgcn_mfma_f32_16x16x32_bf16(a0, bfrag[0], acc, 0, 0, 0);
    acc = __builtin_amdgcn_mfma_f32_16x16x32_bf16(a1, bfrag[1], acc, 0, 0, 0);
    acc = __builtin_amdgcn_mfma_f32_16x16x32_bf16(a2, bfrag[2], acc, 0, 0, 0);
    acc = __builtin_amdgcn_mfma_f32_16x16x32_bf16(a3, bfrag[3], acc, 0, 0, 0);
    int kb = ct * 16 + quad * 4;
    #pragma unroll
    for (int r = 0; r < 4; ++r) {
      float s = fmaf(-2.f, acc[r], sq4[r]);
      if (s < best) { best = s; bk = kb + r; }
    }
  }
  // reduce across quads (lanes sharing ln)
  #pragma unroll
  for (int m = 16; m <= 32; m <<= 1) {
    float os = __shfl_xor(best, m, 64);
    int ok = __shfl_xor(bk, m, 64);
    if (os < best || (os == best && ok < bk)) { best = os; bk = ok; }
  }
  // copy + loss: quads split the 16 uint4 chunks of position n
  const uint4* zr = (const uint4*)zrow;
  uint4* qr = (uint4*)(zq + (long)b * qImgS + (long)y * qRowS + (long)x * 128);
  const uint4* er = (const uint4*)(emb + (long)bk * 128);
  float lsum = 0.f;
  #pragma unroll
  for (int t = 0; t < 4; ++t) {
    int j = quad * 4 + t;
    uint4 ue = er[j];
    uint4 uz = zr[j];
    qr[j] = ue;
    float ev[8], zv[8];
    unpack_u4(ue, ev);
    unpack_u4(uz, zv);
    #pragma unroll
    for (int e = 0; e < 8; ++e) {
      float dv = ev[e] - zv[e];
      lsum = fmaf(dv, dv, lsum);
    }
  }
  for (int o = 32; o > 0; o >>= 1) lsum += __shfl_down(lsum, o, 64);
  if (lane == 0) atomicAdd(loss_acc, lsum);
}

// --------------------- final convT(64->3)+sigmoid via class-packed MFMA
__global__ __launch_bounds__(256) void final_convt_mfma(
    const bf16* __restrict__ hp, const bf16* __restrict__ wfin,
    const float* __restrict__ bf_, float* __restrict__ out) {
  const int lane = threadIdx.x & 63, wv = threadIdx.x >> 6;
  const int ln = lane & 15, quad = lane >> 4;
  const int base = blockIdx.x * 256 + wv * 64;   // 262144 positions total

  short8 afr[18];
  #pragma unroll
  for (int kc = 0; kc < 18; ++kc)
    afr[kc] = *(const short8*)(wfin + ln * 576 + kc * 32 + quad * 8);

  float4v acc[4];
  #pragma unroll
  for (int bf = 0; bf < 4; ++bf) acc[bf] = {0.f, 0.f, 0.f, 0.f};

  #pragma unroll
  for (int bf = 0; bf < 4; ++bf) {
    int n = base + bf * 16 + ln;
    int xx = n & 127, y = (n >> 7) & 127, b = n >> 14;
    const bf16* hb = hp + (long)b * 1081600 + (long)y * 8320 + (long)xx * 64;
    #pragma unroll
    for (int kc = 0; kc < 18; ++kc) {
      int d = kc >> 1;
      const bf16* bp = hb + (long)(d / 3) * 8320 + (d % 3) * 64 + (kc & 1) * 32 + quad * 8;
      short8 bv = *(const short8*)bp;
      acc[bf] = __builtin_amdgcn_mfma_f32_16x16x32_bf16(afr[kc], bv, acc[bf], 0, 0, 0);
    }
  }

  const int p = quad >> 1, q = quad & 1;
  float b0 = bf_[0], b1 = bf_[1], b2 = bf_[2];
  #pragma unroll
  for (int bf = 0; bf < 4; ++bf) {
    int n = base + bf * 16 + ln;
    int xx = n & 127, y = (n >> 7) & 127, b = n >> 14;
    long ob = (long)b * 196608 + (long)(2 * y + p) * 256 + (2 * xx + q);
    float v0 = acc[bf][0] + b0, v1 = acc[bf][1] + b1, v2 = acc[bf][2] + b2;
    out[ob]          = 1.f / (1.f + expf(-v0));
    out[ob + 65536]  = 1.f / (1.f + expf(-v1));
    out[ob + 131072] = 1.f / (1.f + expf(-v2));
  }
}

__global__ void finalize_loss_kernel(const float* __restrict__ lacc, float* __restrict__ out) {
  if (threadIdx.x == 0) {
    float lt = lacc[0] * (1.5f / 2097152.f);
    float lb = lacc[1] * (1.5f / 8388608.f);
    *out = lt + lb;
  }
}

// ------------------------------------------------------------------ launch
extern "C" void kernel_launch(void* const* d_in, const int* in_sizes, int n_in,
                              void* d_out, int out_size, void* d_ws, size_t ws_size,
                              hipStream_t stream) {
  float* out = (float*)d_out;
  char* base = (char*)d_ws;
  size_t off = 0;
  auto alloc = [&](size_t bytes) {
    void* pp = base + off;
    off = (off + bytes + 255) & ~(size_t)255;
    return pp;
  };

  int* flag = (int*)alloc(256);
  float* biasAll = (float*)alloc(515 * 4);
  float* beB1f = biasAll + 0;
  float* beB2f = biasAll + 64;
  float* beTf  = biasAll + 192;
  float* bdTf  = biasAll + 320;
  float* bd1f  = biasAll + 448;
  float* bd2f  = biasAll + 512;
  float* sqAll = (float*)alloc(1024 * 4);
  float* sqT = sqAll, *sqB = sqAll + 512;
  float* lacc = (float*)alloc(2 * 4);
  bf16* Wc1  = (bf16*)alloc((size_t)4096 * 2);
  bf16* Wt2f = (bf16*)alloc((size_t)131072 * 2);
  bf16* Wttf = (bf16*)alloc((size_t)262144 * 2);
  bf16* Wdtf = (bf16*)alloc((size_t)262144 * 2);
  bf16* Wd1f = (bf16*)alloc((size_t)262144 * 2);
  bf16* Wfin = (bf16*)alloc((size_t)9216 * 2);
  bf16* embTB = (bf16*)alloc((size_t)131072 * 2);
  bf16* embT = embTB, *embB = embTB + 65536;
  bf16* act1p = (bf16*)alloc((size_t)17305600 * 2);  // [16][130][2][65][64] parity
  bf16* zbp   = (bf16*)alloc((size_t)8921088 * 2);   // [16][66][2][33][128] parity
  bf16* zqtp  = (bf16*)alloc((size_t)2367488 * 2);   // [16][34][34][128]
  bf16* eup   = (bf16*)alloc((size_t)8921088 * 2);   // [16][66][66][128]
  bf16* fqp   = (bf16*)alloc((size_t)8921088 * 2);   // [16][66][66][128]
  bf16* hp    = (bf16*)alloc((size_t)17305600 * 2);  // [16][130][130][64]
  bf16* ztp   = (bf16*)alloc((size_t)2097152 * 2);   // [16][32][32][128]

  // 3 setup launches
  detect_dtype_kernel<<<1, 256, 0, stream>>>(d_in[0], flag, lacc);
  zero_halo_all<<<1428, 256, 0, stream>>>(act1p, hp, zbp, eup, fqp, zqtp);
  setup_all<<<4155, 256, 0, stream>>>(
      d_in[2], d_in[4], d_in[6], d_in[10], d_in[12], d_in[14],
      d_in[7], d_in[8], d_in[1], d_in[13], d_in[11], d_in[3],
      d_in[5], d_in[9],
      biasAll, embTB, sqAll, Wc1, Wfin, Wd1f, Wt2f, Wttf, Wdtf, flag);

  // encoder: conv1 = fused im2col gather + MFMA GEMM (parity-split store)
  gemm1_fused<<<2048, 256, 0, stream>>>(d_in[0], flag, Wc1, beB1f, act1p);
  // conv2: LDS-staged + T14, 4 waves/block (co-quartered), 1024 x 256 thr
  conv2_lds<<<dim3(64, 1, 16), 256, 0, stream>>>(act1p, Wt2f, beB2f, zbp);
  // conv_t: PXW=33 (zbp parity), output ztp row-major
  mfma_conv<128, 128, 32, 2, 16, 128, 2, 33><<<dim3(16, 2, 16), 256, 0, stream>>>(
      zbp, zbp, 557568, 8448, Wttf, beTf, ztp, 131072, 4096, 128, 30, 0, 0, 0);

  // VQ top (16384 positions, row-major): 16 pos/wave -> 256 blocks, all CUs
  vq_mfma16<<<256, 256, 0, stream>>>(ztp, 131072, 4096, embT, sqT,
                                     zqtp + 4480, 147968, 4352, lacc + 0, 5, 10);

  // decoder_top upsample: 4 classes in one launch (row-major in/out)
  mfma_conv<128, 128, 32, 1, 4, 128, 2, 0><<<dim3(64, 2, 16), 256, 0, stream>>>(
      zqtp, zqtp, 147968, 4352, Wdtf, bdTf, eup, 557568, 16896, 256, 4, 8448, 128, 0);

  // VQ bottom (65536 positions; zbp parity-split input, fqp row-major out)
  vq_mfma<<<256, 256, 0, stream>>>(zbp + 8448, 557568, 8448, embB, sqB,
                                   fqp + 8576, 557568, 8448, lacc + 1, 6, 12, 33);

  // decoder conv d1: LDS-staged + T14, 4 classes per block, 1024 blocks
  mfma_d1_lds<<<dim3(64, 1, 16), 256, 0, stream>>>(fqp, eup, Wd1f, bd1f, hp);

  // final convT + sigmoid via MFMA -> fp32 NCHW output
  final_convt_mfma<<<1024, 256, 0, stream>>>(hp, Wfin, bd2f, out);
  finalize_loss_kernel<<<1, 64, 0, stream>>>(lacc, out + 3145728);
}

// Round 7
// 446.477 us; speedup vs baseline: 1.1534x; 1.0416x over previous
//
#include <hip/hip_runtime.h>
#include <hip/hip_bf16.h>
#include <cstddef>

typedef __hip_bfloat16 bf16;
typedef __attribute__((ext_vector_type(8))) short short8;
typedef __attribute__((ext_vector_type(4))) float float4v;
typedef __attribute__((ext_vector_type(4))) unsigned short ushort4v;

static __device__ __forceinline__ float b2f(bf16 v) { return __bfloat162float(v); }
static __device__ __forceinline__ float bits2f(unsigned int u) { return __uint_as_float(u); }
static __device__ __forceinline__ unsigned short f2bfbits(float f) {
  bf16 h = __float2bfloat16(f);
  return *reinterpret_cast<unsigned short*>(&h);
}
static __device__ __forceinline__ float ld_any(const void* p, long i, int flag) {
  return flag ? b2f(((const bf16*)p)[i]) : ((const float*)p)[i];
}
static __device__ __forceinline__ void unpack_u4(uint4 u, float* f) {
  f[0] = bits2f(u.x << 16); f[1] = bits2f(u.x & 0xffff0000u);
  f[2] = bits2f(u.y << 16); f[3] = bits2f(u.y & 0xffff0000u);
  f[4] = bits2f(u.z << 16); f[5] = bits2f(u.z & 0xffff0000u);
  f[6] = bits2f(u.w << 16); f[7] = bits2f(u.w & 0xffff0000u);
}

// --------------------------------- dtype detection (+ loss accumulator zero)
__global__ void detect_dtype_kernel(const void* __restrict__ x, int* __restrict__ flag,
                                    float* __restrict__ lacc) {
  if (threadIdx.x < 2) lacc[threadIdx.x] = 0.f;
  __shared__ int ok;
  if (threadIdx.x == 0) ok = 1;
  __syncthreads();
  float v = b2f(((const bf16*)x)[threadIdx.x]);
  if (!(v >= 0.f && v <= 1.0009765625f)) ok = 0;
  __syncthreads();
  if (threadIdx.x == 0) *flag = ok;
}

// ------------------------------------------------- halo-ring zeroing helper
static __device__ __forceinline__ void halo_seg(bf16* p0, bf16* p1, bf16* p2,
                                                int np, int H, int W, int C8,
                                                long imgS, int gpi, int r) {
  int total = 16 * gpi;
  int which = r / total;
  if (which >= np) return;
  int rr = r - which * total;
  int img = rr / gpi, g = rr % gpi;
  int pos = g / C8, c8 = g % C8;
  int row, col;
  if (pos < W) { row = 0; col = pos; }
  else if (pos < 2 * W) { row = H - 1; col = pos - W; }
  else { int s = pos - 2 * W; row = 1 + (s >> 1); col = (s & 1) ? (W - 1) : 0; }
  bf16* base = (which == 0) ? p0 : ((which == 1) ? p1 : p2);
  uint4* dst = (uint4*)(base + (long)img * imgS + ((long)row * W + col) * (C8 * 8) + (long)c8 * 8);
  *dst = uint4{0u, 0u, 0u, 0u};
}

// ---------------- all converts / repacks + halo zeroing in one kernel.
__global__ __launch_bounds__(256) void setup_all(
    const void* s2, const void* s4, const void* s6,
    const void* s10, const void* s12, const void* s14,
    const void* sT, const void* sB, const void* c1s,
    const void* fins, const void* d1s, const void* t2s,
    const void* tts, const void* dts,
    float* __restrict__ biasAll, bf16* __restrict__ embTB,
    float* __restrict__ sqAll, bf16* __restrict__ Wc1,
    bf16* __restrict__ Wfin, bf16* __restrict__ Wd1f,
    bf16* __restrict__ Wt2f, bf16* __restrict__ Wttf,
    bf16* __restrict__ Wdtf, const int* __restrict__ flag,
    bf16* act1p, bf16* hp, bf16* zbp, bf16* eup, bf16* fqp, bf16* zqtp) {
  long i = (long)blockIdx.x * 256 + threadIdx.x;
  const int fl = *flag;
  // seg0: 6 conv biases -> one fp32 buffer [515]
  if (i < 515) {
    const void* s; long off;
    if (i < 64)       { s = s2;  off = i; }
    else if (i < 192) { s = s4;  off = i - 64; }
    else if (i < 320) { s = s6;  off = i - 192; }
    else if (i < 448) { s = s10; off = i - 320; }
    else if (i < 512) { s = s12; off = i - 448; }
    else              { s = s14; off = i - 512; }
    biasAll[i] = ld_any(s, off, fl);
    return;
  }
  i -= 515;
  // seg1: both codebooks -> contiguous bf16 [1024][128]
  if (i < 131072) {
    const void* s = (i < 65536) ? sT : sB;
    long off = i & 65535;
    embTB[i] = fl ? ((const bf16*)s)[off] : __float2bfloat16(((const float*)s)[off]);
    return;
  }
  i -= 131072;
  // seg2: emb row sum-of-squares from RAW src through identical bf16 rounding
  if (i < 1024) {
    const void* s = (i < 512) ? sT : sB;
    long base = (i & 511) * 128;
    float acc = 0.f;
    for (int c = 0; c < 128; ++c) {
      float v = b2f(__float2bfloat16(ld_any(s, base + c, fl)));
      acc = fmaf(v, v, acc);
    }
    sqAll[i] = acc;
    return;
  }
  i -= 1024;
  // seg3: conv1 weights [64][3][4][4] -> [co][k], K padded 48->64 [4096]
  if (i < 4096) {
    int co = (int)i >> 6, k = (int)i & 63;
    float v = (k < 48) ? ld_any(c1s, co * 48 + k, fl) : 0.f;
    Wc1[i] = __float2bfloat16(v);
    return;
  }
  i -= 4096;
  // seg4: final convT weights -> A[m=cls*4+co][d=dy*3+dx][64ci] [9216]
  if (i < 9216) {
    int m = (int)i / 576, rem = (int)i % 576;
    int d = rem >> 6, ci = rem & 63;
    int cls = m >> 2, co = m & 3;
    int p = cls >> 1, q = cls & 1;
    int dy = d / 3, dx = d % 3;
    int s_ = p - dy + 1, t_ = q - dx + 1;
    float v = 0.f;
    if (co < 3 && s_ >= 0 && s_ <= 1 && t_ >= 0 && t_ <= 1) {
      int kh = 2 * s_ + 1 - p, kw = 2 * t_ + 1 - q;
      v = ld_any(fins, ci * 48 + co * 16 + kh * 4 + kw, fl);
    }
    Wfin[i] = __float2bfloat16(v);
    return;
  }
  i -= 9216;
  // seg5: d1 weights [256ci][64co][4][4] -> frag [262144]
  if (i < 262144) {
    int low = (int)i & 511;
    int ln = low >> 5, cl = low & 31;
    int c2 = (int)(i >> 9);
    int j = c2 & 3;
    int kc = (c2 >> 2) & 7;
    int t = (c2 >> 5) & 3;
    int cls = c2 >> 7;
    int p = cls >> 1, q = cls & 1;
    int s_ = t >> 1, t2 = t & 1;
    int kh = 2 * s_ + 1 - p, kw = 2 * t2 + 1 - q;
    int co = j * 16 + ln, ci = kc * 32 + cl;
    Wd1f[i] = __float2bfloat16(ld_any(d1s, (long)ci * 1024 + co * 16 + kh * 4 + kw, fl));
    return;
  }
  i -= 262144;
  // seg6: conv2 weights OIHW[128][64][4][4] -> frag direct (MC=4,KC=2) [131072]
  if (i < 131072) {
    int low = (int)i & 511;
    int ln = low >> 5, cl = low & 31;
    int c2 = (int)(i >> 9);
    int j = c2 & 1, c3 = c2 >> 1;
    int kc = c3 & 1, c4 = c3 >> 1;
    int mc = c4 & 3, tg = c4 >> 2;
    int co = mc * 32 + j * 16 + ln, ci = kc * 32 + cl;
    Wt2f[i] = __float2bfloat16(ld_any(t2s, (long)co * 1024 + ci * 16 + tg, fl));
    return;
  }
  i -= 131072;
  // seg7: conv_t weights OIHW[128][128][4][4] -> frag direct (MC=4,KC=4) [262144]
  if (i < 262144) {
    int low = (int)i & 511;
    int ln = low >> 5, cl = low & 31;
    int c2 = (int)(i >> 9);
    int j = c2 & 1, c3 = c2 >> 1;
    int kc = c3 & 3, c4 = c3 >> 2;
    int mc = c4 & 3, tg = c4 >> 2;
    int co = mc * 32 + j * 16 + ln, ci = kc * 32 + cl;
    Wttf[i] = __float2bfloat16(ld_any(tts, (long)co * 2048 + ci * 16 + tg, fl));
    return;
  }
  i -= 262144;
  // seg8: convT dt weights [128ci][128co][4][4] -> class frag direct [262144]
  if (i < 262144) {
    int low = (int)i & 511;
    int ln = low >> 5, cl = low & 31;
    int c2 = (int)(i >> 9);
    int j = c2 & 1, c3 = c2 >> 1;
    int kc = c3 & 3, c4 = c3 >> 2;
    int mc = c4 & 3, tg = c4 >> 2;
    int co = mc * 32 + j * 16 + ln, ci = kc * 32 + cl;
    int cls = tg >> 2, st = tg & 3;
    int p = cls >> 1, q = cls & 1;
    int s_ = st >> 1, tt_ = st & 1;
    int kh = 2 * s_ + 1 - p, kw = 2 * tt_ + 1 - q;
    Wdtf[i] = __float2bfloat16(ld_any(dts, (long)ci * 2048 + co * 16 + kh * 4 + kw, fl));
    return;
  }
  i -= 262144;
  // seg9-11: halo-ring zeroing (independent of flag)
  if (i < 132096) { halo_seg(act1p, hp, nullptr, 2, 130, 130, 8, 1081600, 4128, (int)i); return; }
  i -= 132096;
  if (i < 199680) { halo_seg(zbp, eup, fqp, 3, 66, 66, 16, 557568, 4160, (int)i); return; }
  i -= 199680;
  if (i < 33792)  { halo_seg(zqtp, nullptr, nullptr, 1, 34, 34, 16, 147968, 2112, (int)i); }
}

// -------------------- conv1: LDS-staged im2col + MFMA GEMM.
// Block = one (b, oh) row of 128 ow outputs. Stage input rows 2oh-1..2oh+2
// x 3 ch x 260 px (+1 column shift, zero-padded halo) as bf16 in 6.2 KB LDS;
// each B fragment = 2 aligned ds_read_b64 (was 8 bounds-checked scalar
// global loads). 2048 blocks, full occupancy.
__global__ __launch_bounds__(256) void gemm1_lds(
    const void* __restrict__ x, const int* __restrict__ flag,
    const bf16* __restrict__ w, const float* __restrict__ bias,
    bf16* __restrict__ act1p) {
  __shared__ unsigned short xs[3 * 4 * 260];   // [ci][r][px], px = iw+1
  const int lane = threadIdx.x & 63, wv = threadIdx.x >> 6;
  const int wm = wv & 1, wn = wv >> 1;
  const int ln = lane & 15, quad = lane >> 4;
  const int n0 = blockIdx.x * 128;
  const int oh = (n0 >> 7) & 127, b = n0 >> 14;
  const int fl = *flag;
  const int ih0 = 2 * oh - 1;

  for (int i = threadIdx.x; i < 3120; i += 256) {
    int px = i % 260;
    int t = i / 260;
    int r = t & 3, ci = t >> 2;
    int ih = ih0 + r;
    int iw = px - 1;
    float v = ((unsigned)ih < 256u && (unsigned)iw < 256u)
                ? ld_any(x, (((long)(b * 3 + ci)) << 16) + ((long)ih << 8) + iw, fl) : 0.f;
    xs[i] = f2bfbits(v);
  }
  __syncthreads();

  float4v acc[2][4];
  #pragma unroll
  for (int i = 0; i < 2; ++i)
    #pragma unroll
    for (int j = 0; j < 4; ++j) acc[i][j] = {0.f, 0.f, 0.f, 0.f};

  const int ow_base = wn * 64;
  #pragma unroll
  for (int kc = 0; kc < 2; ++kc) {
    const bf16* wk = w + (wm * 32 + ln) * 64 + kc * 32 + quad * 8;
    short8 a0 = *(const short8*)(wk);
    short8 a1 = *(const short8*)(wk + 16 * 64);
    const int k0 = kc * 32 + quad * 8;      // 0,8,...,56; >=48 is zero-pad
    const int ci = k0 >> 4;
    const int kh0 = (k0 & 15) >> 2;         // 0 or 2
    #pragma unroll
    for (int bf = 0; bf < 4; ++bf) {
      short8 bv;
      if (k0 >= 48) {
        bv = (short8){0, 0, 0, 0, 0, 0, 0, 0};
      } else {
        int ow = ow_base + bf * 16 + ln;
        // px = iw0+1 = ow*2 (even -> 4B-aligned b64 reads)
        union { uint2 u2[2]; short8 s8; } u;
        u.u2[0] = *(const uint2*)(xs + (ci * 4 + kh0) * 260 + ow * 2);
        u.u2[1] = *(const uint2*)(xs + (ci * 4 + kh0 + 1) * 260 + ow * 2);
        bv = u.s8;
      }
      acc[0][bf] = __builtin_amdgcn_mfma_f32_16x16x32_bf16(a0, bv, acc[0][bf], 0, 0, 0);
      acc[1][bf] = __builtin_amdgcn_mfma_f32_16x16x32_bf16(a1, bv, acc[1][bf], 0, 0, 0);
    }
  }
  #pragma unroll
  for (int mf = 0; mf < 2; ++mf) {
    int coB = wm * 32 + mf * 16 + quad * 4;
    float4v bv4 = *(const float4v*)(bias + coB);
    #pragma unroll
    for (int bf = 0; bf < 4; ++bf) {
      int ow = ow_base + bf * 16 + ln;
      int xx = ow + 1;   // parity-split column
      long oaddr = ((long)(b * 130 + oh + 1)) * 8320 +
                   (long)(((xx & 1) * 65) + (xx >> 1)) * 64 + coB;
      float4v v = acc[mf][bf];
      ushort4v o;
      #pragma unroll
      for (int e = 0; e < 4; ++e) o[e] = f2bfbits(fmaxf(v[e] + bv4[e], 0.f));
      *(ushort4v*)(act1p + oaddr) = o;
    }
  }
}

// ------------------------------------------- MFMA implicit-GEMM tap conv
template <int COUT, int CINT, int TC, int S, int NT, int INC, int NBF, int PXW>
__global__ __launch_bounds__(256) void mfma_conv(
    const bf16* __restrict__ in1, const bf16* __restrict__ in2,
    long inImgS, int inRowS,
    const bf16* __restrict__ wf, const float* __restrict__ bias,
    bf16* __restrict__ outp, long outImgS, int oRS, int oCS,
    int nxb, long po, long qo, int oPXW) {
  constexpr int TR = (2 * NBF * 16) / TC;
  constexpr int KC = CINT / 32;
  constexpr int MC = COUT / 32;
  constexpr int KSPLIT = (CINT > INC) ? (INC / 32) : KC;
  const int lane = threadIdx.x & 63;
  const int wv = threadIdx.x >> 6;
  const int wm = wv & 1, wn = wv >> 1;
  const int ln = lane & 15, quad = lane >> 4;
  const int cls = blockIdx.x >> nxb;
  const int xb = blockIdx.x & ((1u << nxb) - 1u);
  const int mTile = blockIdx.y * 64;
  const int mc = blockIdx.y * 2 + wm;
  const int oh0 = xb * TR;
  const int b = blockIdx.z;
  const int p = cls >> 1, q = cls & 1;
  const long ooff = (long)(p + 1) * po + (long)(q + 1) * qo;

  long posOff[NBF];
  int rr[NBF], cc[NBF];
  #pragma unroll
  for (int bf = 0; bf < NBF; ++bf) {
    int n = wn * (NBF * 16) + bf * 16 + ln;
    int r = n / TC, c = n % TC;
    rr[bf] = r; cc[bf] = c;
    posOff[bf] = (long)(S * (oh0 + r)) * inRowS +
                 (PXW ? (long)c * INC : (long)(S * c) * INC);
  }
  const bf16* inb1 = in1 + (long)b * inImgS;
  const bf16* inb2 = in2 + (long)b * inImgS;

  float4v acc[2][NBF];
  #pragma unroll
  for (int i = 0; i < 2; ++i)
    #pragma unroll
    for (int j = 0; j < NBF; ++j) acc[i][j] = {0.f, 0.f, 0.f, 0.f};

  for (int t = 0; t < NT; ++t) {
    int dy, dx;
    if (S == 2) { dy = t >> 2; dx = t & 3; }
    else        { dy = p - (t >> 1) + 1; dx = q - (t & 1) + 1; }
    const int dxo = PXW ? ((dx & 1) * PXW + (dx >> 1)) : dx;
    const long tapOff = (long)dy * inRowS + (long)dxo * INC;
    const bf16* wt = wf + ((long)(cls * NT + t) * MC + mc) * (KC * 1024) + ln * 32 + quad * 8;
    #pragma unroll
    for (int kc = 0; kc < KC; ++kc) {
      short8 a0 = *(const short8*)(wt + kc * 1024);
      short8 a1 = *(const short8*)(wt + kc * 1024 + 512);
      const bf16* bp = (kc < KSPLIT) ? inb1 : inb2;
      int kOff = (kc < KSPLIT ? kc : kc - KSPLIT) * 32 + quad * 8;
      #pragma unroll
      for (int bf = 0; bf < NBF; ++bf) {
        short8 bv = *(const short8*)(bp + posOff[bf] + tapOff + kOff);
        acc[0][bf] = __builtin_amdgcn_mfma_f32_16x16x32_bf16(a0, bv, acc[0][bf], 0, 0, 0);
        acc[1][bf] = __builtin_amdgcn_mfma_f32_16x16x32_bf16(a1, bv, acc[1][bf], 0, 0, 0);
      }
    }
  }

  bf16* outb = outp + (long)b * outImgS + ooff;
  #pragma unroll
  for (int mf = 0; mf < 2; ++mf) {
    int coB = mTile + wm * 32 + mf * 16 + quad * 4;
    float4v bv4 = *(const float4v*)(bias + coB);
    #pragma unroll
    for (int bf = 0; bf < NBF; ++bf) {
      float4v v = acc[mf][bf];
      ushort4v o;
      #pragma unroll
      for (int e = 0; e < 4; ++e)
        o[e] = f2bfbits(fmaxf(v[e] + bv4[e], 0.f));
      long coff = oPXW ? (long)((((cc[bf] + 1) & 1) * oPXW) + ((cc[bf] + 1) >> 1)) * oCS
                       : (long)cc[bf] * oCS;
      long oaddr = (long)(oh0 + rr[bf]) * oRS + coff + oCS * 0 + coB;
      *(ushort4v*)(outb + oaddr) = o;
    }
  }
}

// ---------- conv2 (64 -> 128, s2): LDS-staged + T14, 4 waves (co-quartered)
__global__ __launch_bounds__(256) void conv2_lds(
    const bf16* __restrict__ in, const bf16* __restrict__ wf,
    const float* __restrict__ bias, bf16* __restrict__ outp) {
  __shared__ short8 lds8[2 * 130 * 9];   // 37440 B
  const int lane = threadIdx.x & 63;
  const int w = threadIdx.x >> 6;        // co-quarter (wave id, mc=w)
  const int ln = lane & 15, quad = lane >> 4;
  const int oh = blockIdx.x;             // output row 0..63
  const int b = blockIdx.z;

  const bf16* img = in + (long)b * 1081600;
  const short8* s0 = (const short8*)(img + (long)(2 * oh) * 8320);      // rows 2oh,2oh+1
  const short8* s1 = (const short8*)(img + (long)(2 * oh + 2) * 8320);  // rows 2oh+2,2oh+3

  float4v acc[2][4];   // [j (16-co frag)][bf (pos chunk)]
  #pragma unroll
  for (int j = 0; j < 2; ++j)
    #pragma unroll
    for (int bf = 0; bf < 4; ++bf) acc[j][bf] = {0.f, 0.f, 0.f, 0.f};

  auto compute = [&](int f) {
    #pragma unroll
    for (int tl = 0; tl < 8; ++tl) {
      const int t = 8 * f + tl;
      const int r = (t >> 2) & 1;        // row within phase
      const int dx = t & 3;
      const int pp = dx & 1, cb = dx >> 1;
      const int lbase = (r * 130 + pp * 65 + cb) * 9 + quad;
      #pragma unroll
      for (int kc = 0; kc < 2; ++kc) {
        const bf16* wk = wf + (long)((t * 4 + w) * 2 + kc) * 1024 + ln * 32 + quad * 8;
        short8 a0 = *(const short8*)(wk);          // j=0
        short8 a1 = *(const short8*)(wk + 512);    // j=1
        #pragma unroll
        for (int bf = 0; bf < 4; ++bf) {
          short8 bv = lds8[lbase + (bf * 16 + ln) * 9 + kc * 4];
          acc[0][bf] = __builtin_amdgcn_mfma_f32_16x16x32_bf16(a0, bv, acc[0][bf], 0, 0, 0);
          acc[1][bf] = __builtin_amdgcn_mfma_f32_16x16x32_bf16(a1, bv, acc[1][bf], 0, 0, 0);
        }
      }
    }
  };

  // stage phase 0 directly
  for (int i = threadIdx.x; i < 2080; i += 256) {   // 2 rows x 130 pos x 8
    lds8[(i >> 3) * 9 + (i & 7)] = s0[i];
  }
  // T14: issue phase-1 loads now (9 x 16B regs); latency hides under compute(0)
  short8 pre[9];
  #pragma unroll
  for (int it = 0; it < 9; ++it) {
    int i = threadIdx.x + it * 256;
    if (i < 2080) pre[it] = s1[i];
  }
  __syncthreads();
  compute(0);
  __syncthreads();
  #pragma unroll
  for (int it = 0; it < 9; ++it) {
    int i = threadIdx.x + it * 256;
    if (i < 2080) lds8[(i >> 3) * 9 + (i & 7)] = pre[it];
  }
  __syncthreads();
  compute(1);

  // store: zbp parity layout, row oh+1, col map x -> ((x+1)&1)*33 + ((x+1)>>1)
  bf16* outb = outp + (long)b * 557568 + (long)(oh + 1) * 8448;
  #pragma unroll
  for (int j = 0; j < 2; ++j) {
    int co = w * 32 + j * 16 + quad * 4;
    float4v bv4 = *(const float4v*)(bias + co);
    #pragma unroll
    for (int bf = 0; bf < 4; ++bf) {
      int x = bf * 16 + ln;
      int col = (((x + 1) & 1) * 33) + ((x + 1) >> 1);
      float4v v = acc[j][bf];
      ushort4v o;
      #pragma unroll
      for (int e = 0; e < 4; ++e)
        o[e] = f2bfbits(fmaxf(v[e] + bv4[e], 0.f));
      *(ushort4v*)(outb + (long)col * 128 + co) = o;
    }
  }
}

// ------ d1 (concat 256 -> 64): R2 structure + T14 (frozen; see R3-R5 data)
__global__ __launch_bounds__(256) void mfma_d1_lds(
    const bf16* __restrict__ in1, const bf16* __restrict__ in2,
    const bf16* __restrict__ wf, const float* __restrict__ bias,
    bf16* __restrict__ outp) {
  __shared__ short8 lds8[198 * 17];   // 53856 B
  const int lane = threadIdx.x & 63, wv = threadIdx.x >> 6;
  const int ln = lane & 15, quad = lane >> 4;
  const int r = blockIdx.x;          // output class-row 0..63
  const int b = blockIdx.z;
  const int cls = wv, p = cls >> 1, q = cls & 1;

  const bf16* src1 = in1 + (long)b * 557568 + (long)r * 8448;  // rows r..r+2
  const bf16* src2 = in2 + (long)b * 557568 + (long)r * 8448;

  float4v acc[4][4];
  #pragma unroll
  for (int j = 0; j < 4; ++j)
    #pragma unroll
    for (int bf = 0; bf < 4; ++bf) acc[j][bf] = {0.f, 0.f, 0.f, 0.f};

  auto compute = [&](int phase) {
    #pragma unroll
    for (int t = 0; t < 4; ++t) {
      int dy = p - (t >> 1) + 1, dx = q - (t & 1) + 1;
      const bf16* wt = wf + (long)(cls * 4 + t) * 16384 + (long)(phase * 4) * 2048 +
                       ln * 32 + quad * 8;
      const int lbase = (dy * 66 + dx) * 17 + quad;
      #pragma unroll
      for (int kc = 0; kc < 4; ++kc) {
        const bf16* wk = wt + kc * 2048;
        short8 a0 = *(const short8*)(wk);
        short8 a1 = *(const short8*)(wk + 512);
        short8 a2 = *(const short8*)(wk + 1024);
        short8 a3 = *(const short8*)(wk + 1536);
        #pragma unroll
        for (int bf = 0; bf < 4; ++bf) {
          short8 bv = lds8[lbase + kc * 4 + (bf * 16 + ln) * 17];
          acc[0][bf] = __builtin_amdgcn_mfma_f32_16x16x32_bf16(a0, bv, acc[0][bf], 0, 0, 0);
          acc[1][bf] = __builtin_amdgcn_mfma_f32_16x16x32_bf16(a1, bv, acc[1][bf], 0, 0, 0);
          acc[2][bf] = __builtin_amdgcn_mfma_f32_16x16x32_bf16(a2, bv, acc[2][bf], 0, 0, 0);
          acc[3][bf] = __builtin_amdgcn_mfma_f32_16x16x32_bf16(a3, bv, acc[3][bf], 0, 0, 0);
        }
      }
    }
  };

  // stage phase 0 (fqp) directly
  for (int i = threadIdx.x; i < 3168; i += 256) {   // 198 pos x 16 chunks
    lds8[(i >> 4) * 17 + (i & 15)] = *(const short8*)(src1 + (long)(i >> 4) * 128 + (i & 15) * 8);
  }
  // T14: issue phase-1 (eup) loads now; latency hides under compute(0)
  short8 pre[13];
  #pragma unroll
  for (int it = 0; it < 13; ++it) {
    int i = threadIdx.x + it * 256;
    if (i < 3168) pre[it] = *(const short8*)(src2 + (long)(i >> 4) * 128 + (i & 15) * 8);
  }
  __syncthreads();
  compute(0);
  __syncthreads();
  #pragma unroll
  for (int it = 0; it < 13; ++it) {
    int i = threadIdx.x + it * 256;
    if (i < 3168) lds8[(i >> 4) * 17 + (i & 15)] = pre[it];
  }
  __syncthreads();
  compute(1);

  bf16* outb = outp + (long)b * 1081600 + (long)(p + 1) * 8320 + (long)(q + 1) * 64 +
               (long)r * 16640;
  #pragma unroll
  for (int j = 0; j < 4; ++j) {
    int co = j * 16 + quad * 4;
    float4v bv4 = *(const float4v*)(bias + co);
    #pragma unroll
    for (int bf = 0; bf < 4; ++bf) {
      float4v v = acc[j][bf];
      ushort4v o;
      #pragma unroll
      for (int e = 0; e < 4; ++e)
        o[e] = f2bfbits(fmaxf(v[e] + bv4[e], 0.f));
      *(ushort4v*)(outb + (long)(bf * 16 + ln) * 128 + co) = o;
    }
  }
}

// ---------------------------------------------------- VQ via MFMA GEMM
__global__ __launch_bounds__(256) void vq_mfma(
    const bf16* __restrict__ z, long zImgS, int zRowS,
    const bf16* __restrict__ emb, const float* __restrict__ embsq,
    bf16* __restrict__ zq, long qImgS, int qRowS,
    float* __restrict__ loss_acc, int wb, int hwb, int ipxw) {
  const int lane = threadIdx.x & 63, wv = threadIdx.x >> 6;
  const int ln = lane & 15, quad = lane >> 4;
  const int base = blockIdx.x * 256 + wv * 64;

  short8 bfrag[4][4];
  #pragma unroll
  for (int bf = 0; bf < 4; ++bf) {
    int n = base + bf * 16 + ln;
    int b = n >> hwb;
    int rem = n & ((1 << hwb) - 1);
    int y = rem >> wb, x = rem & ((1 << wb) - 1);
    int xcol = ipxw ? ((((x + 1) & 1) * ipxw) + ((x + 1) >> 1)) : x;
    const bf16* zrow = z + (long)b * zImgS + (long)y * zRowS + (long)xcol * 128;
    #pragma unroll
    for (int kc = 0; kc < 4; ++kc)
      bfrag[bf][kc] = *(const short8*)(zrow + kc * 32 + quad * 8);
  }

  float best0 = 3.4e38f, best1 = 3.4e38f, best2 = 3.4e38f, best3 = 3.4e38f;
  int bk0 = 0, bk1 = 0, bk2 = 0, bk3 = 0;
  for (int ct = 0; ct < 32; ++ct) {
    const bf16* erow = emb + (long)(ct * 16 + ln) * 128 + quad * 8;
    short8 a0 = *(const short8*)(erow);
    short8 a1 = *(const short8*)(erow + 32);
    short8 a2 = *(const short8*)(erow + 64);
    short8 a3 = *(const short8*)(erow + 96);
    float4v sq4 = *(const float4v*)(embsq + ct * 16 + quad * 4);
    #pragma unroll
    for (int bf = 0; bf < 4; ++bf) {
      float4v acc = {0.f, 0.f, 0.f, 0.f};
      acc = __builtin_amdgcn_mfma_f32_16x16x32_bf16(a0, bfrag[bf][0], acc, 0, 0, 0);
      acc = __builtin_amdgcn_mfma_f32_16x16x32_bf16(a1, bfrag[bf][1], acc, 0, 0, 0);
      acc = __builtin_amdgcn_mfma_f32_16x16x32_bf16(a2, bfrag[bf][2], acc, 0, 0, 0);
      acc = __builtin_amdgcn_mfma_f32_16x16x32_bf16(a3, bfrag[bf][3], acc, 0, 0, 0);
      int kb = ct * 16 + quad * 4;
      #pragma unroll
      for (int r = 0; r < 4; ++r) {
        float s = fmaf(-2.f, acc[r], sq4[r]);
        if (bf == 0) { if (s < best0) { best0 = s; bk0 = kb + r; } }
        if (bf == 1) { if (s < best1) { best1 = s; bk1 = kb + r; } }
        if (bf == 2) { if (s < best2) { best2 = s; bk2 = kb + r; } }
        if (bf == 3) { if (s < best3) { best3 = s; bk3 = kb + r; } }
      }
    }
  }
  float bs[4] = {best0, best1, best2, best3};
  int bk[4] = {bk0, bk1, bk2, bk3};
  #pragma unroll
  for (int bf = 0; bf < 4; ++bf) {
    #pragma unroll
    for (int m = 16; m <= 32; m <<= 1) {
      float os = __shfl_xor(bs[bf], m, 64);
      int ok = __shfl_xor(bk[bf], m, 64);
      if (os < bs[bf] || (os == bs[bf] && ok < bk[bf])) { bs[bf] = os; bk[bf] = ok; }
    }
  }
  int myk = (quad == 0) ? bk[0] : (quad == 1) ? bk[1] : (quad == 2) ? bk[2] : bk[3];
  int n = base + quad * 16 + ln;
  int b = n >> hwb;
  int rem = n & ((1 << hwb) - 1);
  int y = rem >> wb, x = rem & ((1 << wb) - 1);
  int xcol = ipxw ? ((((x + 1) & 1) * ipxw) + ((x + 1) >> 1)) : x;
  const uint4* zr = (const uint4*)(z + (long)b * zImgS + (long)y * zRowS + (long)xcol * 128);
  uint4* qr = (uint4*)(zq + (long)b * qImgS + (long)y * qRowS + (long)x * 128);
  const uint4* er = (const uint4*)(emb + (long)myk * 128);
  float lsum = 0.f;
  #pragma unroll
  for (int j = 0; j < 16; ++j) {
    uint4 ue = er[j];
    uint4 uz = zr[j];
    qr[j] = ue;
    float ev[8], zv[8];
    unpack_u4(ue, ev);
    unpack_u4(uz, zv);
    #pragma unroll
    for (int e = 0; e < 8; ++e) {
      float dv = ev[e] - zv[e];
      lsum = fmaf(dv, dv, lsum);
    }
  }
  for (int o = 32; o > 0; o >>= 1) lsum += __shfl_down(lsum, o, 64);
  if (lane == 0) atomicAdd(loss_acc, lsum);
}

// ---------- VQ, 16 positions/wave variant (full-chip grid for small N).
__global__ __launch_bounds__(256) void vq_mfma16(
    const bf16* __restrict__ z, long zImgS, int zRowS,
    const bf16* __restrict__ emb, const float* __restrict__ embsq,
    bf16* __restrict__ zq, long qImgS, int qRowS,
    float* __restrict__ loss_acc, int wb, int hwb) {
  const int lane = threadIdx.x & 63, wv = threadIdx.x >> 6;
  const int ln = lane & 15, quad = lane >> 4;
  const int base = blockIdx.x * 64 + wv * 16;   // 16 positions per wave

  const int n = base + ln;
  const int b = n >> hwb;
  const int rem = n & ((1 << hwb) - 1);
  const int y = rem >> wb, x = rem & ((1 << wb) - 1);
  const bf16* zrow = z + (long)b * zImgS + (long)y * zRowS + (long)x * 128;
  short8 bfrag[4];
  #pragma unroll
  for (int kc = 0; kc < 4; ++kc)
    bfrag[kc] = *(const short8*)(zrow + kc * 32 + quad * 8);

  float best = 3.4e38f;
  int bk = 0;
  for (int ct = 0; ct < 32; ++ct) {
    const bf16* erow = emb + (long)(ct * 16 + ln) * 128 + quad * 8;
    short8 a0 = *(const short8*)(erow);
    short8 a1 = *(const short8*)(erow + 32);
    short8 a2 = *(const short8*)(erow + 64);
    short8 a3 = *(const short8*)(erow + 96);
    float4v sq4 = *(const float4v*)(embsq + ct * 16 + quad * 4);
    float4v acc = {0.f, 0.f, 0.f, 0.f};
    acc = __builtin_amdgcn_mfma_f32_16x16x32_bf16(a0, bfrag[0], acc, 0, 0, 0);
    acc = __builtin_amdgcn_mfma_f32_16x16x32_bf16(a1, bfrag[1], acc, 0, 0, 0);
    acc = __builtin_amdgcn_mfma_f32_16x16x32_bf16(a2, bfrag[2], acc, 0, 0, 0);
    acc = __builtin_amdgcn_mfma_f32_16x16x32_bf16(a3, bfrag[3], acc, 0, 0, 0);
    int kb = ct * 16 + quad * 4;
    #pragma unroll
    for (int r = 0; r < 4; ++r) {
      float s = fmaf(-2.f, acc[r], sq4[r]);
      if (s < best) { best = s; bk = kb + r; }
    }
  }
  #pragma unroll
  for (int m = 16; m <= 32; m <<= 1) {
    float os = __shfl_xor(best, m, 64);
    int ok = __shfl_xor(bk, m, 64);
    if (os < best || (os == best && ok < bk)) { best = os; bk = ok; }
  }
  const uint4* zr = (const uint4*)zrow;
  uint4* qr = (uint4*)(zq + (long)b * qImgS + (long)y * qRowS + (long)x * 128);
  const uint4* er = (const uint4*)(emb + (long)bk * 128);
  float lsum = 0.f;
  #pragma unroll
  for (int t = 0; t < 4; ++t) {
    int j = quad * 4 + t;
    uint4 ue = er[j];
    uint4 uz = zr[j];
    qr[j] = ue;
    float ev[8], zv[8];
    unpack_u4(ue, ev);
    unpack_u4(uz, zv);
    #pragma unroll
    for (int e = 0; e < 8; ++e) {
      float dv = ev[e] - zv[e];
      lsum = fmaf(dv, dv, lsum);
    }
  }
  for (int o = 32; o > 0; o >>= 1) lsum += __shfl_down(lsum, o, 64);
  if (lane == 0) atomicAdd(loss_acc, lsum);
}

// --------------------- final convT(64->3)+sigmoid via class-packed MFMA
__global__ __launch_bounds__(256) void final_convt_mfma(
    const bf16* __restrict__ hp, const bf16* __restrict__ wfin,
    const float* __restrict__ bf_, float* __restrict__ out) {
  const int lane = threadIdx.x & 63, wv = threadIdx.x >> 6;
  const int ln = lane & 15, quad = lane >> 4;
  const int base = blockIdx.x * 256 + wv * 64;   // 262144 positions total

  short8 afr[18];
  #pragma unroll
  for (int kc = 0; kc < 18; ++kc)
    afr[kc] = *(const short8*)(wfin + ln * 576 + kc * 32 + quad * 8);

  float4v acc[4];
  #pragma unroll
  for (int bf = 0; bf < 4; ++bf) acc[bf] = {0.f, 0.f, 0.f, 0.f};

  #pragma unroll
  for (int bf = 0; bf < 4; ++bf) {
    int n = base + bf * 16 + ln;
    int xx = n & 127, y = (n >> 7) & 127, b = n >> 14;
    const bf16* hb = hp + (long)b * 1081600 + (long)y * 8320 + (long)xx * 64;
    #pragma unroll
    for (int kc = 0; kc < 18; ++kc) {
      int d = kc >> 1;
      const bf16* bp = hb + (long)(d / 3) * 8320 + (d % 3) * 64 + (kc & 1) * 32 + quad * 8;
      short8 bv = *(const short8*)bp;
      acc[bf] = __builtin_amdgcn_mfma_f32_16x16x32_bf16(afr[kc], bv, acc[bf], 0, 0, 0);
    }
  }

  const int p = quad >> 1, q = quad & 1;
  float b0 = bf_[0], b1 = bf_[1], b2 = bf_[2];
  #pragma unroll
  for (int bf = 0; bf < 4; ++bf) {
    int n = base + bf * 16 + ln;
    int xx = n & 127, y = (n >> 7) & 127, b = n >> 14;
    long ob = (long)b * 196608 + (long)(2 * y + p) * 256 + (2 * xx + q);
    float v0 = acc[bf][0] + b0, v1 = acc[bf][1] + b1, v2 = acc[bf][2] + b2;
    out[ob]          = 1.f / (1.f + expf(-v0));
    out[ob + 65536]  = 1.f / (1.f + expf(-v1));
    out[ob + 131072] = 1.f / (1.f + expf(-v2));
  }
}

__global__ void finalize_loss_kernel(const float* __restrict__ lacc, float* __restrict__ out) {
  if (threadIdx.x == 0) {
    float lt = lacc[0] * (1.5f / 2097152.f);
    float lb = lacc[1] * (1.5f / 8388608.f);
    *out = lt + lb;
  }
}

// ------------------------------------------------------------------ launch
extern "C" void kernel_launch(void* const* d_in, const int* in_sizes, int n_in,
                              void* d_out, int out_size, void* d_ws, size_t ws_size,
                              hipStream_t stream) {
  float* out = (float*)d_out;
  char* base = (char*)d_ws;
  size_t off = 0;
  auto alloc = [&](size_t bytes) {
    void* pp = base + off;
    off = (off + bytes + 255) & ~(size_t)255;
    return pp;
  };

  int* flag = (int*)alloc(256);
  float* biasAll = (float*)alloc(515 * 4);
  float* beB1f = biasAll + 0;
  float* beB2f = biasAll + 64;
  float* beTf  = biasAll + 192;
  float* bdTf  = biasAll + 320;
  float* bd1f  = biasAll + 448;
  float* bd2f  = biasAll + 512;
  float* sqAll = (float*)alloc(1024 * 4);
  float* sqT = sqAll, *sqB = sqAll + 512;
  float* lacc = (float*)alloc(2 * 4);
  bf16* Wc1  = (bf16*)alloc((size_t)4096 * 2);
  bf16* Wt2f = (bf16*)alloc((size_t)131072 * 2);
  bf16* Wttf = (bf16*)alloc((size_t)262144 * 2);
  bf16* Wdtf = (bf16*)alloc((size_t)262144 * 2);
  bf16* Wd1f = (bf16*)alloc((size_t)262144 * 2);
  bf16* Wfin = (bf16*)alloc((size_t)9216 * 2);
  bf16* embTB = (bf16*)alloc((size_t)131072 * 2);
  bf16* embT = embTB, *embB = embTB + 65536;
  bf16* act1p = (bf16*)alloc((size_t)17305600 * 2);  // [16][130][2][65][64] parity
  bf16* zbp   = (bf16*)alloc((size_t)8921088 * 2);   // [16][66][2][33][128] parity
  bf16* zqtp  = (bf16*)alloc((size_t)2367488 * 2);   // [16][34][34][128]
  bf16* eup   = (bf16*)alloc((size_t)8921088 * 2);   // [16][66][66][128]
  bf16* fqp   = (bf16*)alloc((size_t)8921088 * 2);   // [16][66][66][128]
  bf16* hp    = (bf16*)alloc((size_t)17305600 * 2);  // [16][130][130][64]
  bf16* ztp   = (bf16*)alloc((size_t)2097152 * 2);   // [16][32][32][128]

  // 2 setup launches (halo zeroing folded into setup_all)
  detect_dtype_kernel<<<1, 256, 0, stream>>>(d_in[0], flag, lacc);
  setup_all<<<5583, 256, 0, stream>>>(
      d_in[2], d_in[4], d_in[6], d_in[10], d_in[12], d_in[14],
      d_in[7], d_in[8], d_in[1], d_in[13], d_in[11], d_in[3],
      d_in[5], d_in[9],
      biasAll, embTB, sqAll, Wc1, Wfin, Wd1f, Wt2f, Wttf, Wdtf, flag,
      act1p, hp, zbp, eup, fqp, zqtp);

  // encoder: conv1 = LDS-staged im2col + MFMA GEMM (parity-split store)
  gemm1_lds<<<2048, 256, 0, stream>>>(d_in[0], flag, Wc1, beB1f, act1p);
  // conv2: LDS-staged + T14, 4 waves/block (co-quartered), 1024 x 256 thr
  conv2_lds<<<dim3(64, 1, 16), 256, 0, stream>>>(act1p, Wt2f, beB2f, zbp);
  // conv_t: PXW=33 (zbp parity), output ztp row-major
  mfma_conv<128, 128, 32, 2, 16, 128, 2, 33><<<dim3(16, 2, 16), 256, 0, stream>>>(
      zbp, zbp, 557568, 8448, Wttf, beTf, ztp, 131072, 4096, 128, 30, 0, 0, 0);

  // VQ top (16384 positions, row-major): 16 pos/wave -> 256 blocks, all CUs
  vq_mfma16<<<256, 256, 0, stream>>>(ztp, 131072, 4096, embT, sqT,
                                     zqtp + 4480, 147968, 4352, lacc + 0, 5, 10);

  // decoder_top upsample: 4 classes in one launch (row-major in/out)
  mfma_conv<128, 128, 32, 1, 4, 128, 2, 0><<<dim3(64, 2, 16), 256, 0, stream>>>(
      zqtp, zqtp, 147968, 4352, Wdtf, bdTf, eup, 557568, 16896, 256, 4, 8448, 128, 0);

  // VQ bottom (65536 positions; zbp parity-split input, fqp row-major out)
  vq_mfma<<<256, 256, 0, stream>>>(zbp + 8448, 557568, 8448, embB, sqB,
                                   fqp + 8576, 557568, 8448, lacc + 1, 6, 12, 33);

  // decoder conv d1: LDS-staged + T14, 4 classes per block, 1024 blocks
  mfma_d1_lds<<<dim3(64, 1, 16), 256, 0, stream>>>(fqp, eup, Wd1f, bd1f, hp);

  // final convT + sigmoid via MFMA -> fp32 NCHW output
  final_convt_mfma<<<1024, 256, 0, stream>>>(hp, Wfin, bd2f, out);
  finalize_loss_kernel<<<1, 64, 0, stream>>>(lacc, out + 3145728);
}

// Round 8
// 445.246 us; speedup vs baseline: 1.1565x; 1.0028x over previous
//
#include <hip/hip_runtime.h>
#include <hip/hip_bf16.h>
#include <cstddef>

typedef __hip_bfloat16 bf16;
typedef __attribute__((ext_vector_type(8))) short short8;
typedef __attribute__((ext_vector_type(4))) float float4v;
typedef __attribute__((ext_vector_type(4))) unsigned short ushort4v;

static __device__ __forceinline__ float b2f(bf16 v) { return __bfloat162float(v); }
static __device__ __forceinline__ float bits2f(unsigned int u) { return __uint_as_float(u); }
static __device__ __forceinline__ unsigned short f2bfbits(float f) {
  bf16 h = __float2bfloat16(f);
  return *reinterpret_cast<unsigned short*>(&h);
}
static __device__ __forceinline__ float ld_any(const void* p, long i, int flag) {
  return flag ? b2f(((const bf16*)p)[i]) : ((const float*)p)[i];
}
static __device__ __forceinline__ void unpack_u4(uint4 u, float* f) {
  f[0] = bits2f(u.x << 16); f[1] = bits2f(u.x & 0xffff0000u);
  f[2] = bits2f(u.y << 16); f[3] = bits2f(u.y & 0xffff0000u);
  f[4] = bits2f(u.z << 16); f[5] = bits2f(u.z & 0xffff0000u);
  f[6] = bits2f(u.w << 16); f[7] = bits2f(u.w & 0xffff0000u);
}

// --------------------------------- dtype detection (+ loss accumulator zero)
__global__ void detect_dtype_kernel(const void* __restrict__ x, int* __restrict__ flag,
                                    float* __restrict__ lacc) {
  if (threadIdx.x < 2) lacc[threadIdx.x] = 0.f;
  __shared__ int ok;
  if (threadIdx.x == 0) ok = 1;
  __syncthreads();
  float v = b2f(((const bf16*)x)[threadIdx.x]);
  if (!(v >= 0.f && v <= 1.0009765625f)) ok = 0;
  __syncthreads();
  if (threadIdx.x == 0) *flag = ok;
}

// ------------------------------------------------- halo-ring zeroing helper
static __device__ __forceinline__ void halo_seg(bf16* p0, bf16* p1, bf16* p2,
                                                int np, int H, int W, int C8,
                                                long imgS, int gpi, int r) {
  int total = 16 * gpi;
  int which = r / total;
  if (which >= np) return;
  int rr = r - which * total;
  int img = rr / gpi, g = rr % gpi;
  int pos = g / C8, c8 = g % C8;
  int row, col;
  if (pos < W) { row = 0; col = pos; }
  else if (pos < 2 * W) { row = H - 1; col = pos - W; }
  else { int s = pos - 2 * W; row = 1 + (s >> 1); col = (s & 1) ? (W - 1) : 0; }
  bf16* base = (which == 0) ? p0 : ((which == 1) ? p1 : p2);
  uint4* dst = (uint4*)(base + (long)img * imgS + ((long)row * W + col) * (C8 * 8) + (long)c8 * 8);
  *dst = uint4{0u, 0u, 0u, 0u};
}

// ---------------- all converts / repacks + halo zeroing in one kernel.
__global__ __launch_bounds__(256) void setup_all(
    const void* s2, const void* s4, const void* s6,
    const void* s10, const void* s12, const void* s14,
    const void* sT, const void* sB, const void* c1s,
    const void* fins, const void* d1s, const void* t2s,
    const void* tts, const void* dts,
    float* __restrict__ biasAll, bf16* __restrict__ embTB,
    float* __restrict__ sqAll, bf16* __restrict__ Wc1,
    bf16* __restrict__ Wfin, bf16* __restrict__ Wd1f,
    bf16* __restrict__ Wt2f, bf16* __restrict__ Wttf,
    bf16* __restrict__ Wdtf, const int* __restrict__ flag,
    bf16* act1p, bf16* hp, bf16* zbp, bf16* eup, bf16* fqp, bf16* zqtp) {
  long i = (long)blockIdx.x * 256 + threadIdx.x;
  const int fl = *flag;
  // seg0: 6 conv biases -> one fp32 buffer [515]
  if (i < 515) {
    const void* s; long off;
    if (i < 64)       { s = s2;  off = i; }
    else if (i < 192) { s = s4;  off = i - 64; }
    else if (i < 320) { s = s6;  off = i - 192; }
    else if (i < 448) { s = s10; off = i - 320; }
    else if (i < 512) { s = s12; off = i - 448; }
    else              { s = s14; off = i - 512; }
    biasAll[i] = ld_any(s, off, fl);
    return;
  }
  i -= 515;
  // seg1: both codebooks -> contiguous bf16 [1024][128]
  if (i < 131072) {
    const void* s = (i < 65536) ? sT : sB;
    long off = i & 65535;
    embTB[i] = fl ? ((const bf16*)s)[off] : __float2bfloat16(((const float*)s)[off]);
    return;
  }
  i -= 131072;
  // seg2: emb row sum-of-squares from RAW src through identical bf16 rounding
  if (i < 1024) {
    const void* s = (i < 512) ? sT : sB;
    long base = (i & 511) * 128;
    float acc = 0.f;
    for (int c = 0; c < 128; ++c) {
      float v = b2f(__float2bfloat16(ld_any(s, base + c, fl)));
      acc = fmaf(v, v, acc);
    }
    sqAll[i] = acc;
    return;
  }
  i -= 1024;
  // seg3: conv1 weights [64][3][4][4] -> [co][k], K padded 48->64 [4096]
  if (i < 4096) {
    int co = (int)i >> 6, k = (int)i & 63;
    float v = (k < 48) ? ld_any(c1s, co * 48 + k, fl) : 0.f;
    Wc1[i] = __float2bfloat16(v);
    return;
  }
  i -= 4096;
  // seg4: final convT weights -> A[m=cls*4+co][d=dy*3+dx][64ci] [9216]
  if (i < 9216) {
    int m = (int)i / 576, rem = (int)i % 576;
    int d = rem >> 6, ci = rem & 63;
    int cls = m >> 2, co = m & 3;
    int p = cls >> 1, q = cls & 1;
    int dy = d / 3, dx = d % 3;
    int s_ = p - dy + 1, t_ = q - dx + 1;
    float v = 0.f;
    if (co < 3 && s_ >= 0 && s_ <= 1 && t_ >= 0 && t_ <= 1) {
      int kh = 2 * s_ + 1 - p, kw = 2 * t_ + 1 - q;
      v = ld_any(fins, ci * 48 + co * 16 + kh * 4 + kw, fl);
    }
    Wfin[i] = __float2bfloat16(v);
    return;
  }
  i -= 9216;
  // seg5: d1 weights [256ci][64co][4][4] -> frag [262144]
  if (i < 262144) {
    int low = (int)i & 511;
    int ln = low >> 5, cl = low & 31;
    int c2 = (int)(i >> 9);
    int j = c2 & 3;
    int kc = (c2 >> 2) & 7;
    int t = (c2 >> 5) & 3;
    int cls = c2 >> 7;
    int p = cls >> 1, q = cls & 1;
    int s_ = t >> 1, t2 = t & 1;
    int kh = 2 * s_ + 1 - p, kw = 2 * t2 + 1 - q;
    int co = j * 16 + ln, ci = kc * 32 + cl;
    Wd1f[i] = __float2bfloat16(ld_any(d1s, (long)ci * 1024 + co * 16 + kh * 4 + kw, fl));
    return;
  }
  i -= 262144;
  // seg6: conv2 weights OIHW[128][64][4][4] -> frag direct (MC=4,KC=2) [131072]
  if (i < 131072) {
    int low = (int)i & 511;
    int ln = low >> 5, cl = low & 31;
    int c2 = (int)(i >> 9);
    int j = c2 & 1, c3 = c2 >> 1;
    int kc = c3 & 1, c4 = c3 >> 1;
    int mc = c4 & 3, tg = c4 >> 2;
    int co = mc * 32 + j * 16 + ln, ci = kc * 32 + cl;
    Wt2f[i] = __float2bfloat16(ld_any(t2s, (long)co * 1024 + ci * 16 + tg, fl));
    return;
  }
  i -= 131072;
  // seg7: conv_t weights OIHW[128][128][4][4] -> frag direct (MC=4,KC=4) [262144]
  if (i < 262144) {
    int low = (int)i & 511;
    int ln = low >> 5, cl = low & 31;
    int c2 = (int)(i >> 9);
    int j = c2 & 1, c3 = c2 >> 1;
    int kc = c3 & 3, c4 = c3 >> 2;
    int mc = c4 & 3, tg = c4 >> 2;
    int co = mc * 32 + j * 16 + ln, ci = kc * 32 + cl;
    Wttf[i] = __float2bfloat16(ld_any(tts, (long)co * 2048 + ci * 16 + tg, fl));
    return;
  }
  i -= 262144;
  // seg8: convT dt weights [128ci][128co][4][4] -> class frag direct [262144]
  if (i < 262144) {
    int low = (int)i & 511;
    int ln = low >> 5, cl = low & 31;
    int c2 = (int)(i >> 9);
    int j = c2 & 1, c3 = c2 >> 1;
    int kc = c3 & 3, c4 = c3 >> 2;
    int mc = c4 & 3, tg = c4 >> 2;
    int co = mc * 32 + j * 16 + ln, ci = kc * 32 + cl;
    int cls = tg >> 2, st = tg & 3;
    int p = cls >> 1, q = cls & 1;
    int s_ = st >> 1, tt_ = st & 1;
    int kh = 2 * s_ + 1 - p, kw = 2 * tt_ + 1 - q;
    Wdtf[i] = __float2bfloat16(ld_any(dts, (long)ci * 2048 + co * 16 + kh * 4 + kw, fl));
    return;
  }
  i -= 262144;
  // seg9-11: halo-ring zeroing (independent of flag)
  if (i < 132096) { halo_seg(act1p, hp, nullptr, 2, 130, 130, 8, 1081600, 4128, (int)i); return; }
  i -= 132096;
  if (i < 199680) { halo_seg(zbp, eup, fqp, 3, 66, 66, 16, 557568, 4160, (int)i); return; }
  i -= 199680;
  if (i < 33792)  { halo_seg(zqtp, nullptr, nullptr, 1, 34, 34, 16, 147968, 2112, (int)i); }
}

// -------------------- conv1: LDS-staged im2col + MFMA GEMM.
__global__ __launch_bounds__(256) void gemm1_lds(
    const void* __restrict__ x, const int* __restrict__ flag,
    const bf16* __restrict__ w, const float* __restrict__ bias,
    bf16* __restrict__ act1p) {
  __shared__ unsigned short xs[3 * 4 * 260];   // [ci][r][px], px = iw+1
  const int lane = threadIdx.x & 63, wv = threadIdx.x >> 6;
  const int wm = wv & 1, wn = wv >> 1;
  const int ln = lane & 15, quad = lane >> 4;
  const int n0 = blockIdx.x * 128;
  const int oh = (n0 >> 7) & 127, b = n0 >> 14;
  const int fl = *flag;
  const int ih0 = 2 * oh - 1;

  for (int i = threadIdx.x; i < 3120; i += 256) {
    int px = i % 260;
    int t = i / 260;
    int r = t & 3, ci = t >> 2;
    int ih = ih0 + r;
    int iw = px - 1;
    float v = ((unsigned)ih < 256u && (unsigned)iw < 256u)
                ? ld_any(x, (((long)(b * 3 + ci)) << 16) + ((long)ih << 8) + iw, fl) : 0.f;
    xs[i] = f2bfbits(v);
  }
  __syncthreads();

  float4v acc[2][4];
  #pragma unroll
  for (int i = 0; i < 2; ++i)
    #pragma unroll
    for (int j = 0; j < 4; ++j) acc[i][j] = {0.f, 0.f, 0.f, 0.f};

  const int ow_base = wn * 64;
  #pragma unroll
  for (int kc = 0; kc < 2; ++kc) {
    const bf16* wk = w + (wm * 32 + ln) * 64 + kc * 32 + quad * 8;
    short8 a0 = *(const short8*)(wk);
    short8 a1 = *(const short8*)(wk + 16 * 64);
    const int k0 = kc * 32 + quad * 8;      // 0,8,...,56; >=48 is zero-pad
    const int ci = k0 >> 4;
    const int kh0 = (k0 & 15) >> 2;         // 0 or 2
    #pragma unroll
    for (int bf = 0; bf < 4; ++bf) {
      short8 bv;
      if (k0 >= 48) {
        bv = (short8){0, 0, 0, 0, 0, 0, 0, 0};
      } else {
        int ow = ow_base + bf * 16 + ln;
        union { uint2 u2[2]; short8 s8; } u;
        u.u2[0] = *(const uint2*)(xs + (ci * 4 + kh0) * 260 + ow * 2);
        u.u2[1] = *(const uint2*)(xs + (ci * 4 + kh0 + 1) * 260 + ow * 2);
        bv = u.s8;
      }
      acc[0][bf] = __builtin_amdgcn_mfma_f32_16x16x32_bf16(a0, bv, acc[0][bf], 0, 0, 0);
      acc[1][bf] = __builtin_amdgcn_mfma_f32_16x16x32_bf16(a1, bv, acc[1][bf], 0, 0, 0);
    }
  }
  #pragma unroll
  for (int mf = 0; mf < 2; ++mf) {
    int coB = wm * 32 + mf * 16 + quad * 4;
    float4v bv4 = *(const float4v*)(bias + coB);
    #pragma unroll
    for (int bf = 0; bf < 4; ++bf) {
      int ow = ow_base + bf * 16 + ln;
      int xx = ow + 1;   // parity-split column
      long oaddr = ((long)(b * 130 + oh + 1)) * 8320 +
                   (long)(((xx & 1) * 65) + (xx >> 1)) * 64 + coB;
      float4v v = acc[mf][bf];
      ushort4v o;
      #pragma unroll
      for (int e = 0; e < 4; ++e) o[e] = f2bfbits(fmaxf(v[e] + bv4[e], 0.f));
      *(ushort4v*)(act1p + oaddr) = o;
    }
  }
}

// ------------------------------------------- MFMA implicit-GEMM tap conv
template <int COUT, int CINT, int TC, int S, int NT, int INC, int NBF, int PXW>
__global__ __launch_bounds__(256) void mfma_conv(
    const bf16* __restrict__ in1, const bf16* __restrict__ in2,
    long inImgS, int inRowS,
    const bf16* __restrict__ wf, const float* __restrict__ bias,
    bf16* __restrict__ outp, long outImgS, int oRS, int oCS,
    int nxb, long po, long qo, int oPXW) {
  constexpr int TR = (2 * NBF * 16) / TC;
  constexpr int KC = CINT / 32;
  constexpr int MC = COUT / 32;
  constexpr int KSPLIT = (CINT > INC) ? (INC / 32) : KC;
  const int lane = threadIdx.x & 63;
  const int wv = threadIdx.x >> 6;
  const int wm = wv & 1, wn = wv >> 1;
  const int ln = lane & 15, quad = lane >> 4;
  const int cls = blockIdx.x >> nxb;
  const int xb = blockIdx.x & ((1u << nxb) - 1u);
  const int mTile = blockIdx.y * 64;
  const int mc = blockIdx.y * 2 + wm;
  const int oh0 = xb * TR;
  const int b = blockIdx.z;
  const int p = cls >> 1, q = cls & 1;
  const long ooff = (long)(p + 1) * po + (long)(q + 1) * qo;

  long posOff[NBF];
  int rr[NBF], cc[NBF];
  #pragma unroll
  for (int bf = 0; bf < NBF; ++bf) {
    int n = wn * (NBF * 16) + bf * 16 + ln;
    int r = n / TC, c = n % TC;
    rr[bf] = r; cc[bf] = c;
    posOff[bf] = (long)(S * (oh0 + r)) * inRowS +
                 (PXW ? (long)c * INC : (long)(S * c) * INC);
  }
  const bf16* inb1 = in1 + (long)b * inImgS;
  const bf16* inb2 = in2 + (long)b * inImgS;

  float4v acc[2][NBF];
  #pragma unroll
  for (int i = 0; i < 2; ++i)
    #pragma unroll
    for (int j = 0; j < NBF; ++j) acc[i][j] = {0.f, 0.f, 0.f, 0.f};

  for (int t = 0; t < NT; ++t) {
    int dy, dx;
    if (S == 2) { dy = t >> 2; dx = t & 3; }
    else        { dy = p - (t >> 1) + 1; dx = q - (t & 1) + 1; }
    const int dxo = PXW ? ((dx & 1) * PXW + (dx >> 1)) : dx;
    const long tapOff = (long)dy * inRowS + (long)dxo * INC;
    const bf16* wt = wf + ((long)(cls * NT + t) * MC + mc) * (KC * 1024) + ln * 32 + quad * 8;
    #pragma unroll
    for (int kc = 0; kc < KC; ++kc) {
      short8 a0 = *(const short8*)(wt + kc * 1024);
      short8 a1 = *(const short8*)(wt + kc * 1024 + 512);
      const bf16* bp = (kc < KSPLIT) ? inb1 : inb2;
      int kOff = (kc < KSPLIT ? kc : kc - KSPLIT) * 32 + quad * 8;
      #pragma unroll
      for (int bf = 0; bf < NBF; ++bf) {
        short8 bv = *(const short8*)(bp + posOff[bf] + tapOff + kOff);
        acc[0][bf] = __builtin_amdgcn_mfma_f32_16x16x32_bf16(a0, bv, acc[0][bf], 0, 0, 0);
        acc[1][bf] = __builtin_amdgcn_mfma_f32_16x16x32_bf16(a1, bv, acc[1][bf], 0, 0, 0);
      }
    }
  }

  bf16* outb = outp + (long)b * outImgS + ooff;
  #pragma unroll
  for (int mf = 0; mf < 2; ++mf) {
    int coB = mTile + wm * 32 + mf * 16 + quad * 4;
    float4v bv4 = *(const float4v*)(bias + coB);
    #pragma unroll
    for (int bf = 0; bf < NBF; ++bf) {
      float4v v = acc[mf][bf];
      ushort4v o;
      #pragma unroll
      for (int e = 0; e < 4; ++e)
        o[e] = f2bfbits(fmaxf(v[e] + bv4[e], 0.f));
      long coff = oPXW ? (long)((((cc[bf] + 1) & 1) * oPXW) + ((cc[bf] + 1) >> 1)) * oCS
                       : (long)cc[bf] * oCS;
      long oaddr = (long)(oh0 + rr[bf]) * oRS + coff + oCS * 0 + coB;
      *(ushort4v*)(outb + oaddr) = o;
    }
  }
}

// ---------- conv2 (64 -> 128, s2): LDS-staged + T14, 4 waves (co-quartered)
__global__ __launch_bounds__(256) void conv2_lds(
    const bf16* __restrict__ in, const bf16* __restrict__ wf,
    const float* __restrict__ bias, bf16* __restrict__ outp) {
  __shared__ short8 lds8[2 * 130 * 9];   // 37440 B
  const int lane = threadIdx.x & 63;
  const int w = threadIdx.x >> 6;        // co-quarter (wave id, mc=w)
  const int ln = lane & 15, quad = lane >> 4;
  const int oh = blockIdx.x;             // output row 0..63
  const int b = blockIdx.z;

  const bf16* img = in + (long)b * 1081600;
  const short8* s0 = (const short8*)(img + (long)(2 * oh) * 8320);      // rows 2oh,2oh+1
  const short8* s1 = (const short8*)(img + (long)(2 * oh + 2) * 8320);  // rows 2oh+2,2oh+3

  float4v acc[2][4];   // [j (16-co frag)][bf (pos chunk)]
  #pragma unroll
  for (int j = 0; j < 2; ++j)
    #pragma unroll
    for (int bf = 0; bf < 4; ++bf) acc[j][bf] = {0.f, 0.f, 0.f, 0.f};

  auto compute = [&](int f) {
    #pragma unroll
    for (int tl = 0; tl < 8; ++tl) {
      const int t = 8 * f + tl;
      const int r = (t >> 2) & 1;        // row within phase
      const int dx = t & 3;
      const int pp = dx & 1, cb = dx >> 1;
      const int lbase = (r * 130 + pp * 65 + cb) * 9 + quad;
      #pragma unroll
      for (int kc = 0; kc < 2; ++kc) {
        const bf16* wk = wf + (long)((t * 4 + w) * 2 + kc) * 1024 + ln * 32 + quad * 8;
        short8 a0 = *(const short8*)(wk);          // j=0
        short8 a1 = *(const short8*)(wk + 512);    // j=1
        #pragma unroll
        for (int bf = 0; bf < 4; ++bf) {
          short8 bv = lds8[lbase + (bf * 16 + ln) * 9 + kc * 4];
          acc[0][bf] = __builtin_amdgcn_mfma_f32_16x16x32_bf16(a0, bv, acc[0][bf], 0, 0, 0);
          acc[1][bf] = __builtin_amdgcn_mfma_f32_16x16x32_bf16(a1, bv, acc[1][bf], 0, 0, 0);
        }
      }
    }
  };

  // stage phase 0 directly
  for (int i = threadIdx.x; i < 2080; i += 256) {   // 2 rows x 130 pos x 8
    lds8[(i >> 3) * 9 + (i & 7)] = s0[i];
  }
  // T14: issue phase-1 loads now (9 x 16B regs); latency hides under compute(0)
  short8 pre[9];
  #pragma unroll
  for (int it = 0; it < 9; ++it) {
    int i = threadIdx.x + it * 256;
    if (i < 2080) pre[it] = s1[i];
  }
  __syncthreads();
  compute(0);
  __syncthreads();
  #pragma unroll
  for (int it = 0; it < 9; ++it) {
    int i = threadIdx.x + it * 256;
    if (i < 2080) lds8[(i >> 3) * 9 + (i & 7)] = pre[it];
  }
  __syncthreads();
  compute(1);

  // store: zbp parity layout, row oh+1, col map x -> ((x+1)&1)*33 + ((x+1)>>1)
  bf16* outb = outp + (long)b * 557568 + (long)(oh + 1) * 8448;
  #pragma unroll
  for (int j = 0; j < 2; ++j) {
    int co = w * 32 + j * 16 + quad * 4;
    float4v bv4 = *(const float4v*)(bias + co);
    #pragma unroll
    for (int bf = 0; bf < 4; ++bf) {
      int x = bf * 16 + ln;
      int col = (((x + 1) & 1) * 33) + ((x + 1) >> 1);
      float4v v = acc[j][bf];
      ushort4v o;
      #pragma unroll
      for (int e = 0; e < 4; ++e)
        o[e] = f2bfbits(fmaxf(v[e] + bv4[e], 0.f));
      *(ushort4v*)(outb + (long)col * 128 + co) = o;
    }
  }
}

// ------ d1 (concat 256 -> 64): 8-wave blocks, wave = (class, row).
// Block covers TWO class-rows (r0 = 2*bx, r0+1); each wave owns ONE
// (cls, rr) pair so per-wave acc stays [4][4] (64 VGPR) -- fixes R3's
// VGPR-doubling failure while keeping its verified traffic halving:
// weight L2 stream 536 -> 268 MB, stage re-read 3x -> 2x (203 -> 69 MB).
// LDS 71808 B -> 2 blocks/CU x 8 waves = 16 waves/CU (was 12).
__global__ __launch_bounds__(512) void mfma_d1_lds(
    const bf16* __restrict__ in1, const bf16* __restrict__ in2,
    const bf16* __restrict__ wf, const float* __restrict__ bias,
    bf16* __restrict__ outp) {
  __shared__ short8 lds8[264 * 17];   // 4 rows x 66 pos x 16 chunks, pad 17
  const int lane = threadIdx.x & 63, wv = threadIdx.x >> 6;   // 0..7
  const int ln = lane & 15, quad = lane >> 4;
  const int r0 = blockIdx.x * 2;     // output class-rows r0, r0+1
  const int b = blockIdx.z;
  const int cls = wv & 3, rr = wv >> 2;   // wave = (class, row)
  const int p = cls >> 1, q = cls & 1;

  const bf16* src1 = in1 + (long)b * 557568 + (long)r0 * 8448;  // rows r0..r0+3
  const bf16* src2 = in2 + (long)b * 557568 + (long)r0 * 8448;

  float4v acc[4][4];
  #pragma unroll
  for (int j = 0; j < 4; ++j)
    #pragma unroll
    for (int bf = 0; bf < 4; ++bf) acc[j][bf] = {0.f, 0.f, 0.f, 0.f};

  auto compute = [&](int phase) {
    #pragma unroll
    for (int t = 0; t < 4; ++t) {
      int dy = p - (t >> 1) + 1, dx = q - (t & 1) + 1;
      const bf16* wt = wf + (long)(cls * 4 + t) * 16384 + (long)(phase * 4) * 2048 +
                       ln * 32 + quad * 8;
      const int lbase = ((rr + dy) * 66 + dx) * 17 + quad;
      #pragma unroll
      for (int kc = 0; kc < 4; ++kc) {
        const bf16* wk = wt + kc * 2048;
        short8 a0 = *(const short8*)(wk);
        short8 a1 = *(const short8*)(wk + 512);
        short8 a2 = *(const short8*)(wk + 1024);
        short8 a3 = *(const short8*)(wk + 1536);
        #pragma unroll
        for (int bf = 0; bf < 4; ++bf) {
          short8 bv = lds8[lbase + kc * 4 + (bf * 16 + ln) * 17];
          acc[0][bf] = __builtin_amdgcn_mfma_f32_16x16x32_bf16(a0, bv, acc[0][bf], 0, 0, 0);
          acc[1][bf] = __builtin_amdgcn_mfma_f32_16x16x32_bf16(a1, bv, acc[1][bf], 0, 0, 0);
          acc[2][bf] = __builtin_amdgcn_mfma_f32_16x16x32_bf16(a2, bv, acc[2][bf], 0, 0, 0);
          acc[3][bf] = __builtin_amdgcn_mfma_f32_16x16x32_bf16(a3, bv, acc[3][bf], 0, 0, 0);
        }
      }
    }
  };

  // stage phase 0 (fqp): 264 pos x 16 chunks with 512 threads
  for (int i = threadIdx.x; i < 4224; i += 512) {
    lds8[(i >> 4) * 17 + (i & 15)] = *(const short8*)(src1 + (long)(i >> 4) * 128 + (i & 15) * 8);
  }
  // T14: issue phase-1 (eup) loads now; latency hides under compute(0)
  short8 pre[9];
  #pragma unroll
  for (int it = 0; it < 9; ++it) {
    int i = threadIdx.x + it * 512;
    if (i < 4224) pre[it] = *(const short8*)(src2 + (long)(i >> 4) * 128 + (i & 15) * 8);
  }
  __syncthreads();
  compute(0);
  __syncthreads();
  #pragma unroll
  for (int it = 0; it < 9; ++it) {
    int i = threadIdx.x + it * 512;
    if (i < 4224) lds8[(i >> 4) * 17 + (i & 15)] = pre[it];
  }
  __syncthreads();
  compute(1);

  bf16* outb = outp + (long)b * 1081600 + (long)(p + 1) * 8320 + (long)(q + 1) * 64 +
               (long)(r0 + rr) * 16640;
  #pragma unroll
  for (int j = 0; j < 4; ++j) {
    int co = j * 16 + quad * 4;
    float4v bv4 = *(const float4v*)(bias + co);
    #pragma unroll
    for (int bf = 0; bf < 4; ++bf) {
      float4v v = acc[j][bf];
      ushort4v o;
      #pragma unroll
      for (int e = 0; e < 4; ++e)
        o[e] = f2bfbits(fmaxf(v[e] + bv4[e], 0.f));
      *(ushort4v*)(outb + (long)(bf * 16 + ln) * 128 + co) = o;
    }
  }
}

// ---------------------------------------------------- VQ via MFMA GEMM
__global__ __launch_bounds__(256) void vq_mfma(
    const bf16* __restrict__ z, long zImgS, int zRowS,
    const bf16* __restrict__ emb, const float* __restrict__ embsq,
    bf16* __restrict__ zq, long qImgS, int qRowS,
    float* __restrict__ loss_acc, int wb, int hwb, int ipxw) {
  const int lane = threadIdx.x & 63, wv = threadIdx.x >> 6;
  const int ln = lane & 15, quad = lane >> 4;
  const int base = blockIdx.x * 256 + wv * 64;

  short8 bfrag[4][4];
  #pragma unroll
  for (int bf = 0; bf < 4; ++bf) {
    int n = base + bf * 16 + ln;
    int b = n >> hwb;
    int rem = n & ((1 << hwb) - 1);
    int y = rem >> wb, x = rem & ((1 << wb) - 1);
    int xcol = ipxw ? ((((x + 1) & 1) * ipxw) + ((x + 1) >> 1)) : x;
    const bf16* zrow = z + (long)b * zImgS + (long)y * zRowS + (long)xcol * 128;
    #pragma unroll
    for (int kc = 0; kc < 4; ++kc)
      bfrag[bf][kc] = *(const short8*)(zrow + kc * 32 + quad * 8);
  }

  float best0 = 3.4e38f, best1 = 3.4e38f, best2 = 3.4e38f, best3 = 3.4e38f;
  int bk0 = 0, bk1 = 0, bk2 = 0, bk3 = 0;
  for (int ct = 0; ct < 32; ++ct) {
    const bf16* erow = emb + (long)(ct * 16 + ln) * 128 + quad * 8;
    short8 a0 = *(const short8*)(erow);
    short8 a1 = *(const short8*)(erow + 32);
    short8 a2 = *(const short8*)(erow + 64);
    short8 a3 = *(const short8*)(erow + 96);
    float4v sq4 = *(const float4v*)(embsq + ct * 16 + quad * 4);
    #pragma unroll
    for (int bf = 0; bf < 4; ++bf) {
      float4v acc = {0.f, 0.f, 0.f, 0.f};
      acc = __builtin_amdgcn_mfma_f32_16x16x32_bf16(a0, bfrag[bf][0], acc, 0, 0, 0);
      acc = __builtin_amdgcn_mfma_f32_16x16x32_bf16(a1, bfrag[bf][1], acc, 0, 0, 0);
      acc = __builtin_amdgcn_mfma_f32_16x16x32_bf16(a2, bfrag[bf][2], acc, 0, 0, 0);
      acc = __builtin_amdgcn_mfma_f32_16x16x32_bf16(a3, bfrag[bf][3], acc, 0, 0, 0);
      int kb = ct * 16 + quad * 4;
      #pragma unroll
      for (int r = 0; r < 4; ++r) {
        float s = fmaf(-2.f, acc[r], sq4[r]);
        if (bf == 0) { if (s < best0) { best0 = s; bk0 = kb + r; } }
        if (bf == 1) { if (s < best1) { best1 = s; bk1 = kb + r; } }
        if (bf == 2) { if (s < best2) { best2 = s; bk2 = kb + r; } }
        if (bf == 3) { if (s < best3) { best3 = s; bk3 = kb + r; } }
      }
    }
  }
  float bs[4] = {best0, best1, best2, best3};
  int bk[4] = {bk0, bk1, bk2, bk3};
  #pragma unroll
  for (int bf = 0; bf < 4; ++bf) {
    #pragma unroll
    for (int m = 16; m <= 32; m <<= 1) {
      float os = __shfl_xor(bs[bf], m, 64);
      int ok = __shfl_xor(bk[bf], m, 64);
      if (os < bs[bf] || (os == bs[bf] && ok < bk[bf])) { bs[bf] = os; bk[bf] = ok; }
    }
  }
  int myk = (quad == 0) ? bk[0] : (quad == 1) ? bk[1] : (quad == 2) ? bk[2] : bk[3];
  int n = base + quad * 16 + ln;
  int b = n >> hwb;
  int rem = n & ((1 << hwb) - 1);
  int y = rem >> wb, x = rem & ((1 << wb) - 1);
  int xcol = ipxw ? ((((x + 1) & 1) * ipxw) + ((x + 1) >> 1)) : x;
  const uint4* zr = (const uint4*)(z + (long)b * zImgS + (long)y * zRowS + (long)xcol * 128);
  uint4* qr = (uint4*)(zq + (long)b * qImgS + (long)y * qRowS + (long)x * 128);
  const uint4* er = (const uint4*)(emb + (long)myk * 128);
  float lsum = 0.f;
  #pragma unroll
  for (int j = 0; j < 16; ++j) {
    uint4 ue = er[j];
    uint4 uz = zr[j];
    qr[j] = ue;
    float ev[8], zv[8];
    unpack_u4(ue, ev);
    unpack_u4(uz, zv);
    #pragma unroll
    for (int e = 0; e < 8; ++e) {
      float dv = ev[e] - zv[e];
      lsum = fmaf(dv, dv, lsum);
    }
  }
  for (int o = 32; o > 0; o >>= 1) lsum += __shfl_down(lsum, o, 64);
  if (lane == 0) atomicAdd(loss_acc, lsum);
}

// ---------- VQ, 16 positions/wave variant (full-chip grid for small N).
__global__ __launch_bounds__(256) void vq_mfma16(
    const bf16* __restrict__ z, long zImgS, int zRowS,
    const bf16* __restrict__ emb, const float* __restrict__ embsq,
    bf16* __restrict__ zq, long qImgS, int qRowS,
    float* __restrict__ loss_acc, int wb, int hwb) {
  const int lane = threadIdx.x & 63, wv = threadIdx.x >> 6;
  const int ln = lane & 15, quad = lane >> 4;
  const int base = blockIdx.x * 64 + wv * 16;   // 16 positions per wave

  const int n = base + ln;
  const int b = n >> hwb;
  const int rem = n & ((1 << hwb) - 1);
  const int y = rem >> wb, x = rem & ((1 << wb) - 1);
  const bf16* zrow = z + (long)b * zImgS + (long)y * zRowS + (long)x * 128;
  short8 bfrag[4];
  #pragma unroll
  for (int kc = 0; kc < 4; ++kc)
    bfrag[kc] = *(const short8*)(zrow + kc * 32 + quad * 8);

  float best = 3.4e38f;
  int bk = 0;
  for (int ct = 0; ct < 32; ++ct) {
    const bf16* erow = emb + (long)(ct * 16 + ln) * 128 + quad * 8;
    short8 a0 = *(const short8*)(erow);
    short8 a1 = *(const short8*)(erow + 32);
    short8 a2 = *(const short8*)(erow + 64);
    short8 a3 = *(const short8*)(erow + 96);
    float4v sq4 = *(const float4v*)(embsq + ct * 16 + quad * 4);
    float4v acc = {0.f, 0.f, 0.f, 0.f};
    acc = __builtin_amdgcn_mfma_f32_16x16x32_bf16(a0, bfrag[0], acc, 0, 0, 0);
    acc = __builtin_amdgcn_mfma_f32_16x16x32_bf16(a1, bfrag[1], acc, 0, 0, 0);
    acc = __builtin_amdgcn_mfma_f32_16x16x32_bf16(a2, bfrag[2], acc, 0, 0, 0);
    acc = __builtin_amdgcn_mfma_f32_16x16x32_bf16(a3, bfrag[3], acc, 0, 0, 0);
    int kb = ct * 16 + quad * 4;
    #pragma unroll
    for (int r = 0; r < 4; ++r) {
      float s = fmaf(-2.f, acc[r], sq4[r]);
      if (s < best) { best = s; bk = kb + r; }
    }
  }
  #pragma unroll
  for (int m = 16; m <= 32; m <<= 1) {
    float os = __shfl_xor(best, m, 64);
    int ok = __shfl_xor(bk, m, 64);
    if (os < best || (os == best && ok < bk)) { best = os; bk = ok; }
  }
  const uint4* zr = (const uint4*)zrow;
  uint4* qr = (uint4*)(zq + (long)b * qImgS + (long)y * qRowS + (long)x * 128);
  const uint4* er = (const uint4*)(emb + (long)bk * 128);
  float lsum = 0.f;
  #pragma unroll
  for (int t = 0; t < 4; ++t) {
    int j = quad * 4 + t;
    uint4 ue = er[j];
    uint4 uz = zr[j];
    qr[j] = ue;
    float ev[8], zv[8];
    unpack_u4(ue, ev);
    unpack_u4(uz, zv);
    #pragma unroll
    for (int e = 0; e < 8; ++e) {
      float dv = ev[e] - zv[e];
      lsum = fmaf(dv, dv, lsum);
    }
  }
  for (int o = 32; o > 0; o >>= 1) lsum += __shfl_down(lsum, o, 64);
  if (lane == 0) atomicAdd(loss_acc, lsum);
}

// --------------------- final convT(64->3)+sigmoid via class-packed MFMA
__global__ __launch_bounds__(256) void final_convt_mfma(
    const bf16* __restrict__ hp, const bf16* __restrict__ wfin,
    const float* __restrict__ bf_, float* __restrict__ out) {
  const int lane = threadIdx.x & 63, wv = threadIdx.x >> 6;
  const int ln = lane & 15, quad = lane >> 4;
  const int base = blockIdx.x * 256 + wv * 64;   // 262144 positions total

  short8 afr[18];
  #pragma unroll
  for (int kc = 0; kc < 18; ++kc)
    afr[kc] = *(const short8*)(wfin + ln * 576 + kc * 32 + quad * 8);

  float4v acc[4];
  #pragma unroll
  for (int bf = 0; bf < 4; ++bf) acc[bf] = {0.f, 0.f, 0.f, 0.f};

  #pragma unroll
  for (int bf = 0; bf < 4; ++bf) {
    int n = base + bf * 16 + ln;
    int xx = n & 127, y = (n >> 7) & 127, b = n >> 14;
    const bf16* hb = hp + (long)b * 1081600 + (long)y * 8320 + (long)xx * 64;
    #pragma unroll
    for (int kc = 0; kc < 18; ++kc) {
      int d = kc >> 1;
      const bf16* bp = hb + (long)(d / 3) * 8320 + (d % 3) * 64 + (kc & 1) * 32 + quad * 8;
      short8 bv = *(const short8*)bp;
      acc[bf] = __builtin_amdgcn_mfma_f32_16x16x32_bf16(afr[kc], bv, acc[bf], 0, 0, 0);
    }
  }

  const int p = quad >> 1, q = quad & 1;
  float b0 = bf_[0], b1 = bf_[1], b2 = bf_[2];
  #pragma unroll
  for (int bf = 0; bf < 4; ++bf) {
    int n = base + bf * 16 + ln;
    int xx = n & 127, y = (n >> 7) & 127, b = n >> 14;
    long ob = (long)b * 196608 + (long)(2 * y + p) * 256 + (2 * xx + q);
    float v0 = acc[bf][0] + b0, v1 = acc[bf][1] + b1, v2 = acc[bf][2] + b2;
    out[ob]          = 1.f / (1.f + expf(-v0));
    out[ob + 65536]  = 1.f / (1.f + expf(-v1));
    out[ob + 131072] = 1.f / (1.f + expf(-v2));
  }
}

__global__ void finalize_loss_kernel(const float* __restrict__ lacc, float* __restrict__ out) {
  if (threadIdx.x == 0) {
    float lt = lacc[0] * (1.5f / 2097152.f);
    float lb = lacc[1] * (1.5f / 8388608.f);
    *out = lt + lb;
  }
}

// ------------------------------------------------------------------ launch
extern "C" void kernel_launch(void* const* d_in, const int* in_sizes, int n_in,
                              void* d_out, int out_size, void* d_ws, size_t ws_size,
                              hipStream_t stream) {
  float* out = (float*)d_out;
  char* base = (char*)d_ws;
  size_t off = 0;
  auto alloc = [&](size_t bytes) {
    void* pp = base + off;
    off = (off + bytes + 255) & ~(size_t)255;
    return pp;
  };

  int* flag = (int*)alloc(256);
  float* biasAll = (float*)alloc(515 * 4);
  float* beB1f = biasAll + 0;
  float* beB2f = biasAll + 64;
  float* beTf  = biasAll + 192;
  float* bdTf  = biasAll + 320;
  float* bd1f  = biasAll + 448;
  float* bd2f  = biasAll + 512;
  float* sqAll = (float*)alloc(1024 * 4);
  float* sqT = sqAll, *sqB = sqAll + 512;
  float* lacc = (float*)alloc(2 * 4);
  bf16* Wc1  = (bf16*)alloc((size_t)4096 * 2);
  bf16* Wt2f = (bf16*)alloc((size_t)131072 * 2);
  bf16* Wttf = (bf16*)alloc((size_t)262144 * 2);
  bf16* Wdtf = (bf16*)alloc((size_t)262144 * 2);
  bf16* Wd1f = (bf16*)alloc((size_t)262144 * 2);
  bf16* Wfin = (bf16*)alloc((size_t)9216 * 2);
  bf16* embTB = (bf16*)alloc((size_t)131072 * 2);
  bf16* embT = embTB, *embB = embTB + 65536;
  bf16* act1p = (bf16*)alloc((size_t)17305600 * 2);  // [16][130][2][65][64] parity
  bf16* zbp   = (bf16*)alloc((size_t)8921088 * 2);   // [16][66][2][33][128] parity
  bf16* zqtp  = (bf16*)alloc((size_t)2367488 * 2);   // [16][34][34][128]
  bf16* eup   = (bf16*)alloc((size_t)8921088 * 2);   // [16][66][66][128]
  bf16* fqp   = (bf16*)alloc((size_t)8921088 * 2);   // [16][66][66][128]
  bf16* hp    = (bf16*)alloc((size_t)17305600 * 2);  // [16][130][130][64]
  bf16* ztp   = (bf16*)alloc((size_t)2097152 * 2);   // [16][32][32][128]

  // 2 setup launches (halo zeroing folded into setup_all)
  detect_dtype_kernel<<<1, 256, 0, stream>>>(d_in[0], flag, lacc);
  setup_all<<<5583, 256, 0, stream>>>(
      d_in[2], d_in[4], d_in[6], d_in[10], d_in[12], d_in[14],
      d_in[7], d_in[8], d_in[1], d_in[13], d_in[11], d_in[3],
      d_in[5], d_in[9],
      biasAll, embTB, sqAll, Wc1, Wfin, Wd1f, Wt2f, Wttf, Wdtf, flag,
      act1p, hp, zbp, eup, fqp, zqtp);

  // encoder: conv1 = LDS-staged im2col + MFMA GEMM (parity-split store)
  gemm1_lds<<<2048, 256, 0, stream>>>(d_in[0], flag, Wc1, beB1f, act1p);
  // conv2: LDS-staged + T14, 4 waves/block (co-quartered), 1024 x 256 thr
  conv2_lds<<<dim3(64, 1, 16), 256, 0, stream>>>(act1p, Wt2f, beB2f, zbp);
  // conv_t: PXW=33 (zbp parity), output ztp row-major
  mfma_conv<128, 128, 32, 2, 16, 128, 2, 33><<<dim3(16, 2, 16), 256, 0, stream>>>(
      zbp, zbp, 557568, 8448, Wttf, beTf, ztp, 131072, 4096, 128, 30, 0, 0, 0);

  // VQ top (16384 positions, row-major): 16 pos/wave -> 256 blocks, all CUs
  vq_mfma16<<<256, 256, 0, stream>>>(ztp, 131072, 4096, embT, sqT,
                                     zqtp + 4480, 147968, 4352, lacc + 0, 5, 10);

  // decoder_top upsample: 4 classes in one launch (row-major in/out)
  mfma_conv<128, 128, 32, 1, 4, 128, 2, 0><<<dim3(64, 2, 16), 256, 0, stream>>>(
      zqtp, zqtp, 147968, 4352, Wdtf, bdTf, eup, 557568, 16896, 256, 4, 8448, 128, 0);

  // VQ bottom (65536 positions; zbp parity-split input, fqp row-major out)
  vq_mfma<<<256, 256, 0, stream>>>(zbp + 8448, 557568, 8448, embB, sqB,
                                   fqp + 8576, 557568, 8448, lacc + 1, 6, 12, 33);

  // decoder conv d1: 8-wave blocks, wave=(class,row), 512 blocks x 512 thr
  mfma_d1_lds<<<dim3(32, 1, 16), 512, 0, stream>>>(fqp, eup, Wd1f, bd1f, hp);

  // final convT + sigmoid via MFMA -> fp32 NCHW output
  final_convt_mfma<<<1024, 256, 0, stream>>>(hp, Wfin, bd2f, out);
  finalize_loss_kernel<<<1, 64, 0, stream>>>(lacc, out + 3145728);
}

// Round 9
// 427.574 us; speedup vs baseline: 1.2044x; 1.0413x over previous
//
#include <hip/hip_runtime.h>
#include <hip/hip_bf16.h>
#include <cstddef>

typedef __hip_bfloat16 bf16;
typedef __attribute__((ext_vector_type(8))) short short8;
typedef __attribute__((ext_vector_type(4))) float float4v;
typedef __attribute__((ext_vector_type(4))) unsigned short ushort4v;

static __device__ __forceinline__ float b2f(bf16 v) { return __bfloat162float(v); }
static __device__ __forceinline__ float bits2f(unsigned int u) { return __uint_as_float(u); }
static __device__ __forceinline__ unsigned short f2bfbits(float f) {
  bf16 h = __float2bfloat16(f);
  return *reinterpret_cast<unsigned short*>(&h);
}
static __device__ __forceinline__ float ld_any(const void* p, long i, int flag) {
  return flag ? b2f(((const bf16*)p)[i]) : ((const float*)p)[i];
}
static __device__ __forceinline__ void unpack_u4(uint4 u, float* f) {
  f[0] = bits2f(u.x << 16); f[1] = bits2f(u.x & 0xffff0000u);
  f[2] = bits2f(u.y << 16); f[3] = bits2f(u.y & 0xffff0000u);
  f[4] = bits2f(u.z << 16); f[5] = bits2f(u.z & 0xffff0000u);
  f[6] = bits2f(u.w << 16); f[7] = bits2f(u.w & 0xffff0000u);
}

// --------------------------------- dtype detection (+ loss accumulator zero)
__global__ void detect_dtype_kernel(const void* __restrict__ x, int* __restrict__ flag,
                                    float* __restrict__ lacc) {
  if (threadIdx.x < 2) lacc[threadIdx.x] = 0.f;
  __shared__ int ok;
  if (threadIdx.x == 0) ok = 1;
  __syncthreads();
  float v = b2f(((const bf16*)x)[threadIdx.x]);
  if (!(v >= 0.f && v <= 1.0009765625f)) ok = 0;
  __syncthreads();
  if (threadIdx.x == 0) *flag = ok;
}

// ------------------------------------------------- halo-ring zeroing helper
static __device__ __forceinline__ void halo_seg(bf16* p0, bf16* p1, bf16* p2,
                                                int np, int H, int W, int C8,
                                                long imgS, int gpi, int r) {
  int total = 16 * gpi;
  int which = r / total;
  if (which >= np) return;
  int rr = r - which * total;
  int img = rr / gpi, g = rr % gpi;
  int pos = g / C8, c8 = g % C8;
  int row, col;
  if (pos < W) { row = 0; col = pos; }
  else if (pos < 2 * W) { row = H - 1; col = pos - W; }
  else { int s = pos - 2 * W; row = 1 + (s >> 1); col = (s & 1) ? (W - 1) : 0; }
  bf16* base = (which == 0) ? p0 : ((which == 1) ? p1 : p2);
  uint4* dst = (uint4*)(base + (long)img * imgS + ((long)row * W + col) * (C8 * 8) + (long)c8 * 8);
  *dst = uint4{0u, 0u, 0u, 0u};
}

// ---------------- all converts / repacks + halo zeroing in one kernel.
// seg0 (sqAll) is now WAVE-PARALLEL: one 64-lane wave per codebook row
// (2 loads/lane + shfl tree reduce) instead of a serial 128-load chain per
// thread -- removes a ~16 us dependent-load tail from the critical path.
// seg0 placed first so waves align to rows (base offset 0).
__global__ __launch_bounds__(256) void setup_all(
    const void* s2, const void* s4, const void* s6,
    const void* s10, const void* s12, const void* s14,
    const void* sT, const void* sB, const void* c1s,
    const void* fins, const void* d1s, const void* t2s,
    const void* tts, const void* dts,
    float* __restrict__ biasAll, bf16* __restrict__ embTB,
    float* __restrict__ sqAll, bf16* __restrict__ Wc1,
    bf16* __restrict__ Wfin, bf16* __restrict__ Wd1f,
    bf16* __restrict__ Wt2f, bf16* __restrict__ Wttf,
    bf16* __restrict__ Wdtf, const int* __restrict__ flag,
    bf16* act1p, bf16* hp, bf16* zbp, bf16* eup, bf16* fqp, bf16* zqtp) {
  long i = (long)blockIdx.x * 256 + threadIdx.x;
  const int fl = *flag;
  // seg0: emb row sum-of-squares, wave-parallel [65536 = 1024 rows x 64 lanes]
  if (i < 65536) {
    int k = (int)(i >> 6), lane = (int)(i & 63);
    const void* s = (k < 512) ? sT : sB;
    long base = (long)(k & 511) * 128 + lane * 2;
    float v0 = b2f(__float2bfloat16(ld_any(s, base, fl)));
    float v1 = b2f(__float2bfloat16(ld_any(s, base + 1, fl)));
    float acc = fmaf(v1, v1, v0 * v0);
    #pragma unroll
    for (int o = 32; o > 0; o >>= 1) acc += __shfl_down(acc, o, 64);
    if (lane == 0) sqAll[k] = acc;
    return;
  }
  i -= 65536;
  // seg1: 6 conv biases -> one fp32 buffer [515]
  if (i < 515) {
    const void* s; long off;
    if (i < 64)       { s = s2;  off = i; }
    else if (i < 192) { s = s4;  off = i - 64; }
    else if (i < 320) { s = s6;  off = i - 192; }
    else if (i < 448) { s = s10; off = i - 320; }
    else if (i < 512) { s = s12; off = i - 448; }
    else              { s = s14; off = i - 512; }
    biasAll[i] = ld_any(s, off, fl);
    return;
  }
  i -= 515;
  // seg2: both codebooks -> contiguous bf16 [1024][128]
  if (i < 131072) {
    const void* s = (i < 65536) ? sT : sB;
    long off = i & 65535;
    embTB[i] = fl ? ((const bf16*)s)[off] : __float2bfloat16(((const float*)s)[off]);
    return;
  }
  i -= 131072;
  // seg3: conv1 weights [64][3][4][4] -> [co][k], K padded 48->64 [4096]
  if (i < 4096) {
    int co = (int)i >> 6, k = (int)i & 63;
    float v = (k < 48) ? ld_any(c1s, co * 48 + k, fl) : 0.f;
    Wc1[i] = __float2bfloat16(v);
    return;
  }
  i -= 4096;
  // seg4: final convT weights -> A[m=cls*4+co][d=dy*3+dx][64ci] [9216]
  if (i < 9216) {
    int m = (int)i / 576, rem = (int)i % 576;
    int d = rem >> 6, ci = rem & 63;
    int cls = m >> 2, co = m & 3;
    int p = cls >> 1, q = cls & 1;
    int dy = d / 3, dx = d % 3;
    int s_ = p - dy + 1, t_ = q - dx + 1;
    float v = 0.f;
    if (co < 3 && s_ >= 0 && s_ <= 1 && t_ >= 0 && t_ <= 1) {
      int kh = 2 * s_ + 1 - p, kw = 2 * t_ + 1 - q;
      v = ld_any(fins, ci * 48 + co * 16 + kh * 4 + kw, fl);
    }
    Wfin[i] = __float2bfloat16(v);
    return;
  }
  i -= 9216;
  // seg5: d1 weights [256ci][64co][4][4] -> frag [262144]
  if (i < 262144) {
    int low = (int)i & 511;
    int ln = low >> 5, cl = low & 31;
    int c2 = (int)(i >> 9);
    int j = c2 & 3;
    int kc = (c2 >> 2) & 7;
    int t = (c2 >> 5) & 3;
    int cls = c2 >> 7;
    int p = cls >> 1, q = cls & 1;
    int s_ = t >> 1, t2 = t & 1;
    int kh = 2 * s_ + 1 - p, kw = 2 * t2 + 1 - q;
    int co = j * 16 + ln, ci = kc * 32 + cl;
    Wd1f[i] = __float2bfloat16(ld_any(d1s, (long)ci * 1024 + co * 16 + kh * 4 + kw, fl));
    return;
  }
  i -= 262144;
  // seg6: conv2 weights OIHW[128][64][4][4] -> frag direct (MC=4,KC=2) [131072]
  if (i < 131072) {
    int low = (int)i & 511;
    int ln = low >> 5, cl = low & 31;
    int c2 = (int)(i >> 9);
    int j = c2 & 1, c3 = c2 >> 1;
    int kc = c3 & 1, c4 = c3 >> 1;
    int mc = c4 & 3, tg = c4 >> 2;
    int co = mc * 32 + j * 16 + ln, ci = kc * 32 + cl;
    Wt2f[i] = __float2bfloat16(ld_any(t2s, (long)co * 1024 + ci * 16 + tg, fl));
    return;
  }
  i -= 131072;
  // seg7: conv_t weights OIHW[128][128][4][4] -> frag direct (MC=4,KC=4) [262144]
  if (i < 262144) {
    int low = (int)i & 511;
    int ln = low >> 5, cl = low & 31;
    int c2 = (int)(i >> 9);
    int j = c2 & 1, c3 = c2 >> 1;
    int kc = c3 & 3, c4 = c3 >> 2;
    int mc = c4 & 3, tg = c4 >> 2;
    int co = mc * 32 + j * 16 + ln, ci = kc * 32 + cl;
    Wttf[i] = __float2bfloat16(ld_any(tts, (long)co * 2048 + ci * 16 + tg, fl));
    return;
  }
  i -= 262144;
  // seg8: convT dt weights [128ci][128co][4][4] -> class frag direct [262144]
  if (i < 262144) {
    int low = (int)i & 511;
    int ln = low >> 5, cl = low & 31;
    int c2 = (int)(i >> 9);
    int j = c2 & 1, c3 = c2 >> 1;
    int kc = c3 & 3, c4 = c3 >> 2;
    int mc = c4 & 3, tg = c4 >> 2;
    int co = mc * 32 + j * 16 + ln, ci = kc * 32 + cl;
    int cls = tg >> 2, st = tg & 3;
    int p = cls >> 1, q = cls & 1;
    int s_ = st >> 1, tt_ = st & 1;
    int kh = 2 * s_ + 1 - p, kw = 2 * tt_ + 1 - q;
    Wdtf[i] = __float2bfloat16(ld_any(dts, (long)ci * 2048 + co * 16 + kh * 4 + kw, fl));
    return;
  }
  i -= 262144;
  // seg9-11: halo-ring zeroing (independent of flag)
  if (i < 132096) { halo_seg(act1p, hp, nullptr, 2, 130, 130, 8, 1081600, 4128, (int)i); return; }
  i -= 132096;
  if (i < 199680) { halo_seg(zbp, eup, fqp, 3, 66, 66, 16, 557568, 4160, (int)i); return; }
  i -= 199680;
  if (i < 33792)  { halo_seg(zqtp, nullptr, nullptr, 1, 34, 34, 16, 147968, 2112, (int)i); }
}

// -------------------- conv1: LDS-staged im2col + MFMA GEMM.
__global__ __launch_bounds__(256) void gemm1_lds(
    const void* __restrict__ x, const int* __restrict__ flag,
    const bf16* __restrict__ w, const float* __restrict__ bias,
    bf16* __restrict__ act1p) {
  __shared__ unsigned short xs[3 * 4 * 260];   // [ci][r][px], px = iw+1
  const int lane = threadIdx.x & 63, wv = threadIdx.x >> 6;
  const int wm = wv & 1, wn = wv >> 1;
  const int ln = lane & 15, quad = lane >> 4;
  const int n0 = blockIdx.x * 128;
  const int oh = (n0 >> 7) & 127, b = n0 >> 14;
  const int fl = *flag;
  const int ih0 = 2 * oh - 1;

  for (int i = threadIdx.x; i < 3120; i += 256) {
    int px = i % 260;
    int t = i / 260;
    int r = t & 3, ci = t >> 2;
    int ih = ih0 + r;
    int iw = px - 1;
    float v = ((unsigned)ih < 256u && (unsigned)iw < 256u)
                ? ld_any(x, (((long)(b * 3 + ci)) << 16) + ((long)ih << 8) + iw, fl) : 0.f;
    xs[i] = f2bfbits(v);
  }
  __syncthreads();

  float4v acc[2][4];
  #pragma unroll
  for (int i = 0; i < 2; ++i)
    #pragma unroll
    for (int j = 0; j < 4; ++j) acc[i][j] = {0.f, 0.f, 0.f, 0.f};

  const int ow_base = wn * 64;
  #pragma unroll
  for (int kc = 0; kc < 2; ++kc) {
    const bf16* wk = w + (wm * 32 + ln) * 64 + kc * 32 + quad * 8;
    short8 a0 = *(const short8*)(wk);
    short8 a1 = *(const short8*)(wk + 16 * 64);
    const int k0 = kc * 32 + quad * 8;      // 0,8,...,56; >=48 is zero-pad
    const int ci = k0 >> 4;
    const int kh0 = (k0 & 15) >> 2;         // 0 or 2
    #pragma unroll
    for (int bf = 0; bf < 4; ++bf) {
      short8 bv;
      if (k0 >= 48) {
        bv = (short8){0, 0, 0, 0, 0, 0, 0, 0};
      } else {
        int ow = ow_base + bf * 16 + ln;
        union { uint2 u2[2]; short8 s8; } u;
        u.u2[0] = *(const uint2*)(xs + (ci * 4 + kh0) * 260 + ow * 2);
        u.u2[1] = *(const uint2*)(xs + (ci * 4 + kh0 + 1) * 260 + ow * 2);
        bv = u.s8;
      }
      acc[0][bf] = __builtin_amdgcn_mfma_f32_16x16x32_bf16(a0, bv, acc[0][bf], 0, 0, 0);
      acc[1][bf] = __builtin_amdgcn_mfma_f32_16x16x32_bf16(a1, bv, acc[1][bf], 0, 0, 0);
    }
  }
  #pragma unroll
  for (int mf = 0; mf < 2; ++mf) {
    int coB = wm * 32 + mf * 16 + quad * 4;
    float4v bv4 = *(const float4v*)(bias + coB);
    #pragma unroll
    for (int bf = 0; bf < 4; ++bf) {
      int ow = ow_base + bf * 16 + ln;
      int xx = ow + 1;   // parity-split column
      long oaddr = ((long)(b * 130 + oh + 1)) * 8320 +
                   (long)(((xx & 1) * 65) + (xx >> 1)) * 64 + coB;
      float4v v = acc[mf][bf];
      ushort4v o;
      #pragma unroll
      for (int e = 0; e < 4; ++e) o[e] = f2bfbits(fmaxf(v[e] + bv4[e], 0.f));
      *(ushort4v*)(act1p + oaddr) = o;
    }
  }
}

// ------------------------------------------- MFMA implicit-GEMM tap conv
template <int COUT, int CINT, int TC, int S, int NT, int INC, int NBF, int PXW>
__global__ __launch_bounds__(256) void mfma_conv(
    const bf16* __restrict__ in1, const bf16* __restrict__ in2,
    long inImgS, int inRowS,
    const bf16* __restrict__ wf, const float* __restrict__ bias,
    bf16* __restrict__ outp, long outImgS, int oRS, int oCS,
    int nxb, long po, long qo, int oPXW) {
  constexpr int TR = (2 * NBF * 16) / TC;
  constexpr int KC = CINT / 32;
  constexpr int MC = COUT / 32;
  constexpr int KSPLIT = (CINT > INC) ? (INC / 32) : KC;
  const int lane = threadIdx.x & 63;
  const int wv = threadIdx.x >> 6;
  const int wm = wv & 1, wn = wv >> 1;
  const int ln = lane & 15, quad = lane >> 4;
  const int cls = blockIdx.x >> nxb;
  const int xb = blockIdx.x & ((1u << nxb) - 1u);
  const int mTile = blockIdx.y * 64;
  const int mc = blockIdx.y * 2 + wm;
  const int oh0 = xb * TR;
  const int b = blockIdx.z;
  const int p = cls >> 1, q = cls & 1;
  const long ooff = (long)(p + 1) * po + (long)(q + 1) * qo;

  long posOff[NBF];
  int rr[NBF], cc[NBF];
  #pragma unroll
  for (int bf = 0; bf < NBF; ++bf) {
    int n = wn * (NBF * 16) + bf * 16 + ln;
    int r = n / TC, c = n % TC;
    rr[bf] = r; cc[bf] = c;
    posOff[bf] = (long)(S * (oh0 + r)) * inRowS +
                 (PXW ? (long)c * INC : (long)(S * c) * INC);
  }
  const bf16* inb1 = in1 + (long)b * inImgS;
  const bf16* inb2 = in2 + (long)b * inImgS;

  float4v acc[2][NBF];
  #pragma unroll
  for (int i = 0; i < 2; ++i)
    #pragma unroll
    for (int j = 0; j < NBF; ++j) acc[i][j] = {0.f, 0.f, 0.f, 0.f};

  for (int t = 0; t < NT; ++t) {
    int dy, dx;
    if (S == 2) { dy = t >> 2; dx = t & 3; }
    else        { dy = p - (t >> 1) + 1; dx = q - (t & 1) + 1; }
    const int dxo = PXW ? ((dx & 1) * PXW + (dx >> 1)) : dx;
    const long tapOff = (long)dy * inRowS + (long)dxo * INC;
    const bf16* wt = wf + ((long)(cls * NT + t) * MC + mc) * (KC * 1024) + ln * 32 + quad * 8;
    #pragma unroll
    for (int kc = 0; kc < KC; ++kc) {
      short8 a0 = *(const short8*)(wt + kc * 1024);
      short8 a1 = *(const short8*)(wt + kc * 1024 + 512);
      const bf16* bp = (kc < KSPLIT) ? inb1 : inb2;
      int kOff = (kc < KSPLIT ? kc : kc - KSPLIT) * 32 + quad * 8;
      #pragma unroll
      for (int bf = 0; bf < NBF; ++bf) {
        short8 bv = *(const short8*)(bp + posOff[bf] + tapOff + kOff);
        acc[0][bf] = __builtin_amdgcn_mfma_f32_16x16x32_bf16(a0, bv, acc[0][bf], 0, 0, 0);
        acc[1][bf] = __builtin_amdgcn_mfma_f32_16x16x32_bf16(a1, bv, acc[1][bf], 0, 0, 0);
      }
    }
  }

  bf16* outb = outp + (long)b * outImgS + ooff;
  #pragma unroll
  for (int mf = 0; mf < 2; ++mf) {
    int coB = mTile + wm * 32 + mf * 16 + quad * 4;
    float4v bv4 = *(const float4v*)(bias + coB);
    #pragma unroll
    for (int bf = 0; bf < NBF; ++bf) {
      float4v v = acc[mf][bf];
      ushort4v o;
      #pragma unroll
      for (int e = 0; e < 4; ++e)
        o[e] = f2bfbits(fmaxf(v[e] + bv4[e], 0.f));
      long coff = oPXW ? (long)((((cc[bf] + 1) & 1) * oPXW) + ((cc[bf] + 1) >> 1)) * oCS
                       : (long)cc[bf] * oCS;
      long oaddr = (long)(oh0 + rr[bf]) * oRS + coff + oCS * 0 + coB;
      *(ushort4v*)(outb + oaddr) = o;
    }
  }
}

// ---------- conv2 (64 -> 128, s2): LDS-staged + T14, 4 waves (co-quartered)
__global__ __launch_bounds__(256) void conv2_lds(
    const bf16* __restrict__ in, const bf16* __restrict__ wf,
    const float* __restrict__ bias, bf16* __restrict__ outp) {
  __shared__ short8 lds8[2 * 130 * 9];   // 37440 B
  const int lane = threadIdx.x & 63;
  const int w = threadIdx.x >> 6;        // co-quarter (wave id, mc=w)
  const int ln = lane & 15, quad = lane >> 4;
  const int oh = blockIdx.x;             // output row 0..63
  const int b = blockIdx.z;

  const bf16* img = in + (long)b * 1081600;
  const short8* s0 = (const short8*)(img + (long)(2 * oh) * 8320);      // rows 2oh,2oh+1
  const short8* s1 = (const short8*)(img + (long)(2 * oh + 2) * 8320);  // rows 2oh+2,2oh+3

  float4v acc[2][4];   // [j (16-co frag)][bf (pos chunk)]
  #pragma unroll
  for (int j = 0; j < 2; ++j)
    #pragma unroll
    for (int bf = 0; bf < 4; ++bf) acc[j][bf] = {0.f, 0.f, 0.f, 0.f};

  auto compute = [&](int f) {
    #pragma unroll
    for (int tl = 0; tl < 8; ++tl) {
      const int t = 8 * f + tl;
      const int r = (t >> 2) & 1;        // row within phase
      const int dx = t & 3;
      const int pp = dx & 1, cb = dx >> 1;
      const int lbase = (r * 130 + pp * 65 + cb) * 9 + quad;
      #pragma unroll
      for (int kc = 0; kc < 2; ++kc) {
        const bf16* wk = wf + (long)((t * 4 + w) * 2 + kc) * 1024 + ln * 32 + quad * 8;
        short8 a0 = *(const short8*)(wk);          // j=0
        short8 a1 = *(const short8*)(wk + 512);    // j=1
        #pragma unroll
        for (int bf = 0; bf < 4; ++bf) {
          short8 bv = lds8[lbase + (bf * 16 + ln) * 9 + kc * 4];
          acc[0][bf] = __builtin_amdgcn_mfma_f32_16x16x32_bf16(a0, bv, acc[0][bf], 0, 0, 0);
          acc[1][bf] = __builtin_amdgcn_mfma_f32_16x16x32_bf16(a1, bv, acc[1][bf], 0, 0, 0);
        }
      }
    }
  };

  // stage phase 0 directly
  for (int i = threadIdx.x; i < 2080; i += 256) {   // 2 rows x 130 pos x 8
    lds8[(i >> 3) * 9 + (i & 7)] = s0[i];
  }
  // T14: issue phase-1 loads now (9 x 16B regs); latency hides under compute(0)
  short8 pre[9];
  #pragma unroll
  for (int it = 0; it < 9; ++it) {
    int i = threadIdx.x + it * 256;
    if (i < 2080) pre[it] = s1[i];
  }
  __syncthreads();
  compute(0);
  __syncthreads();
  #pragma unroll
  for (int it = 0; it < 9; ++it) {
    int i = threadIdx.x + it * 256;
    if (i < 2080) lds8[(i >> 3) * 9 + (i & 7)] = pre[it];
  }
  __syncthreads();
  compute(1);

  // store: zbp parity layout, row oh+1, col map x -> ((x+1)&1)*33 + ((x+1)>>1)
  bf16* outb = outp + (long)b * 557568 + (long)(oh + 1) * 8448;
  #pragma unroll
  for (int j = 0; j < 2; ++j) {
    int co = w * 32 + j * 16 + quad * 4;
    float4v bv4 = *(const float4v*)(bias + co);
    #pragma unroll
    for (int bf = 0; bf < 4; ++bf) {
      int x = bf * 16 + ln;
      int col = (((x + 1) & 1) * 33) + ((x + 1) >> 1);
      float4v v = acc[j][bf];
      ushort4v o;
      #pragma unroll
      for (int e = 0; e < 4; ++e)
        o[e] = f2bfbits(fmaxf(v[e] + bv4[e], 0.f));
      *(ushort4v*)(outb + (long)col * 128 + co) = o;
    }
  }
}

// ------ d1 (concat 256 -> 64): 8-wave blocks, wave = (class, row). Frozen.
__global__ __launch_bounds__(512) void mfma_d1_lds(
    const bf16* __restrict__ in1, const bf16* __restrict__ in2,
    const bf16* __restrict__ wf, const float* __restrict__ bias,
    bf16* __restrict__ outp) {
  __shared__ short8 lds8[264 * 17];   // 4 rows x 66 pos x 16 chunks, pad 17
  const int lane = threadIdx.x & 63, wv = threadIdx.x >> 6;   // 0..7
  const int ln = lane & 15, quad = lane >> 4;
  const int r0 = blockIdx.x * 2;     // output class-rows r0, r0+1
  const int b = blockIdx.z;
  const int cls = wv & 3, rr = wv >> 2;   // wave = (class, row)
  const int p = cls >> 1, q = cls & 1;

  const bf16* src1 = in1 + (long)b * 557568 + (long)r0 * 8448;  // rows r0..r0+3
  const bf16* src2 = in2 + (long)b * 557568 + (long)r0 * 8448;

  float4v acc[4][4];
  #pragma unroll
  for (int j = 0; j < 4; ++j)
    #pragma unroll
    for (int bf = 0; bf < 4; ++bf) acc[j][bf] = {0.f, 0.f, 0.f, 0.f};

  auto compute = [&](int phase) {
    #pragma unroll
    for (int t = 0; t < 4; ++t) {
      int dy = p - (t >> 1) + 1, dx = q - (t & 1) + 1;
      const bf16* wt = wf + (long)(cls * 4 + t) * 16384 + (long)(phase * 4) * 2048 +
                       ln * 32 + quad * 8;
      const int lbase = ((rr + dy) * 66 + dx) * 17 + quad;
      #pragma unroll
      for (int kc = 0; kc < 4; ++kc) {
        const bf16* wk = wt + kc * 2048;
        short8 a0 = *(const short8*)(wk);
        short8 a1 = *(const short8*)(wk + 512);
        short8 a2 = *(const short8*)(wk + 1024);
        short8 a3 = *(const short8*)(wk + 1536);
        #pragma unroll
        for (int bf = 0; bf < 4; ++bf) {
          short8 bv = lds8[lbase + kc * 4 + (bf * 16 + ln) * 17];
          acc[0][bf] = __builtin_amdgcn_mfma_f32_16x16x32_bf16(a0, bv, acc[0][bf], 0, 0, 0);
          acc[1][bf] = __builtin_amdgcn_mfma_f32_16x16x32_bf16(a1, bv, acc[1][bf], 0, 0, 0);
          acc[2][bf] = __builtin_amdgcn_mfma_f32_16x16x32_bf16(a2, bv, acc[2][bf], 0, 0, 0);
          acc[3][bf] = __builtin_amdgcn_mfma_f32_16x16x32_bf16(a3, bv, acc[3][bf], 0, 0, 0);
        }
      }
    }
  };

  // stage phase 0 (fqp): 264 pos x 16 chunks with 512 threads
  for (int i = threadIdx.x; i < 4224; i += 512) {
    lds8[(i >> 4) * 17 + (i & 15)] = *(const short8*)(src1 + (long)(i >> 4) * 128 + (i & 15) * 8);
  }
  // T14: issue phase-1 (eup) loads now; latency hides under compute(0)
  short8 pre[9];
  #pragma unroll
  for (int it = 0; it < 9; ++it) {
    int i = threadIdx.x + it * 512;
    if (i < 4224) pre[it] = *(const short8*)(src2 + (long)(i >> 4) * 128 + (i & 15) * 8);
  }
  __syncthreads();
  compute(0);
  __syncthreads();
  #pragma unroll
  for (int it = 0; it < 9; ++it) {
    int i = threadIdx.x + it * 512;
    if (i < 4224) lds8[(i >> 4) * 17 + (i & 15)] = pre[it];
  }
  __syncthreads();
  compute(1);

  bf16* outb = outp + (long)b * 1081600 + (long)(p + 1) * 8320 + (long)(q + 1) * 64 +
               (long)(r0 + rr) * 16640;
  #pragma unroll
  for (int j = 0; j < 4; ++j) {
    int co = j * 16 + quad * 4;
    float4v bv4 = *(const float4v*)(bias + co);
    #pragma unroll
    for (int bf = 0; bf < 4; ++bf) {
      float4v v = acc[j][bf];
      ushort4v o;
      #pragma unroll
      for (int e = 0; e < 4; ++e)
        o[e] = f2bfbits(fmaxf(v[e] + bv4[e], 0.f));
      *(ushort4v*)(outb + (long)(bf * 16 + ln) * 128 + co) = o;
    }
  }
}

// ---------------------------------------------------- VQ via MFMA GEMM
__global__ __launch_bounds__(256) void vq_mfma(
    const bf16* __restrict__ z, long zImgS, int zRowS,
    const bf16* __restrict__ emb, const float* __restrict__ embsq,
    bf16* __restrict__ zq, long qImgS, int qRowS,
    float* __restrict__ loss_acc, int wb, int hwb, int ipxw) {
  const int lane = threadIdx.x & 63, wv = threadIdx.x >> 6;
  const int ln = lane & 15, quad = lane >> 4;
  const int base = blockIdx.x * 256 + wv * 64;

  short8 bfrag[4][4];
  #pragma unroll
  for (int bf = 0; bf < 4; ++bf) {
    int n = base + bf * 16 + ln;
    int b = n >> hwb;
    int rem = n & ((1 << hwb) - 1);
    int y = rem >> wb, x = rem & ((1 << wb) - 1);
    int xcol = ipxw ? ((((x + 1) & 1) * ipxw) + ((x + 1) >> 1)) : x;
    const bf16* zrow = z + (long)b * zImgS + (long)y * zRowS + (long)xcol * 128;
    #pragma unroll
    for (int kc = 0; kc < 4; ++kc)
      bfrag[bf][kc] = *(const short8*)(zrow + kc * 32 + quad * 8);
  }

  float best0 = 3.4e38f, best1 = 3.4e38f, best2 = 3.4e38f, best3 = 3.4e38f;
  int bk0 = 0, bk1 = 0, bk2 = 0, bk3 = 0;
  for (int ct = 0; ct < 32; ++ct) {
    const bf16* erow = emb + (long)(ct * 16 + ln) * 128 + quad * 8;
    short8 a0 = *(const short8*)(erow);
    short8 a1 = *(const short8*)(erow + 32);
    short8 a2 = *(const short8*)(erow + 64);
    short8 a3 = *(const short8*)(erow + 96);
    float4v sq4 = *(const float4v*)(embsq + ct * 16 + quad * 4);
    #pragma unroll
    for (int bf = 0; bf < 4; ++bf) {
      float4v acc = {0.f, 0.f, 0.f, 0.f};
      acc = __builtin_amdgcn_mfma_f32_16x16x32_bf16(a0, bfrag[bf][0], acc, 0, 0, 0);
      acc = __builtin_amdgcn_mfma_f32_16x16x32_bf16(a1, bfrag[bf][1], acc, 0, 0, 0);
      acc = __builtin_amdgcn_mfma_f32_16x16x32_bf16(a2, bfrag[bf][2], acc, 0, 0, 0);
      acc = __builtin_amdgcn_mfma_f32_16x16x32_bf16(a3, bfrag[bf][3], acc, 0, 0, 0);
      int kb = ct * 16 + quad * 4;
      #pragma unroll
      for (int r = 0; r < 4; ++r) {
        float s = fmaf(-2.f, acc[r], sq4[r]);
        if (bf == 0) { if (s < best0) { best0 = s; bk0 = kb + r; } }
        if (bf == 1) { if (s < best1) { best1 = s; bk1 = kb + r; } }
        if (bf == 2) { if (s < best2) { best2 = s; bk2 = kb + r; } }
        if (bf == 3) { if (s < best3) { best3 = s; bk3 = kb + r; } }
      }
    }
  }
  float bs[4] = {best0, best1, best2, best3};
  int bk[4] = {bk0, bk1, bk2, bk3};
  #pragma unroll
  for (int bf = 0; bf < 4; ++bf) {
    #pragma unroll
    for (int m = 16; m <= 32; m <<= 1) {
      float os = __shfl_xor(bs[bf], m, 64);
      int ok = __shfl_xor(bk[bf], m, 64);
      if (os < bs[bf] || (os == bs[bf] && ok < bk[bf])) { bs[bf] = os; bk[bf] = ok; }
    }
  }
  int myk = (quad == 0) ? bk[0] : (quad == 1) ? bk[1] : (quad == 2) ? bk[2] : bk[3];
  int n = base + quad * 16 + ln;
  int b = n >> hwb;
  int rem = n & ((1 << hwb) - 1);
  int y = rem >> wb, x = rem & ((1 << wb) - 1);
  int xcol = ipxw ? ((((x + 1) & 1) * ipxw) + ((x + 1) >> 1)) : x;
  const uint4* zr = (const uint4*)(z + (long)b * zImgS + (long)y * zRowS + (long)xcol * 128);
  uint4* qr = (uint4*)(zq + (long)b * qImgS + (long)y * qRowS + (long)x * 128);
  const uint4* er = (const uint4*)(emb + (long)myk * 128);
  float lsum = 0.f;
  #pragma unroll
  for (int j = 0; j < 16; ++j) {
    uint4 ue = er[j];
    uint4 uz = zr[j];
    qr[j] = ue;
    float ev[8], zv[8];
    unpack_u4(ue, ev);
    unpack_u4(uz, zv);
    #pragma unroll
    for (int e = 0; e < 8; ++e) {
      float dv = ev[e] - zv[e];
      lsum = fmaf(dv, dv, lsum);
    }
  }
  for (int o = 32; o > 0; o >>= 1) lsum += __shfl_down(lsum, o, 64);
  if (lane == 0) atomicAdd(loss_acc, lsum);
}

// ---------- VQ, 16 positions/wave variant (full-chip grid for small N).
__global__ __launch_bounds__(256) void vq_mfma16(
    const bf16* __restrict__ z, long zImgS, int zRowS,
    const bf16* __restrict__ emb, const float* __restrict__ embsq,
    bf16* __restrict__ zq, long qImgS, int qRowS,
    float* __restrict__ loss_acc, int wb, int hwb) {
  const int lane = threadIdx.x & 63, wv = threadIdx.x >> 6;
  const int ln = lane & 15, quad = lane >> 4;
  const int base = blockIdx.x * 64 + wv * 16;   // 16 positions per wave

  const int n = base + ln;
  const int b = n >> hwb;
  const int rem = n & ((1 << hwb) - 1);
  const int y = rem >> wb, x = rem & ((1 << wb) - 1);
  const bf16* zrow = z + (long)b * zImgS + (long)y * zRowS + (long)x * 128;
  short8 bfrag[4];
  #pragma unroll
  for (int kc = 0; kc < 4; ++kc)
    bfrag[kc] = *(const short8*)(zrow + kc * 32 + quad * 8);

  float best = 3.4e38f;
  int bk = 0;
  for (int ct = 0; ct < 32; ++ct) {
    const bf16* erow = emb + (long)(ct * 16 + ln) * 128 + quad * 8;
    short8 a0 = *(const short8*)(erow);
    short8 a1 = *(const short8*)(erow + 32);
    short8 a2 = *(const short8*)(erow + 64);
    short8 a3 = *(const short8*)(erow + 96);
    float4v sq4 = *(const float4v*)(embsq + ct * 16 + quad * 4);
    float4v acc = {0.f, 0.f, 0.f, 0.f};
    acc = __builtin_amdgcn_mfma_f32_16x16x32_bf16(a0, bfrag[0], acc, 0, 0, 0);
    acc = __builtin_amdgcn_mfma_f32_16x16x32_bf16(a1, bfrag[1], acc, 0, 0, 0);
    acc = __builtin_amdgcn_mfma_f32_16x16x32_bf16(a2, bfrag[2], acc, 0, 0, 0);
    acc = __builtin_amdgcn_mfma_f32_16x16x32_bf16(a3, bfrag[3], acc, 0, 0, 0);
    int kb = ct * 16 + quad * 4;
    #pragma unroll
    for (int r = 0; r < 4; ++r) {
      float s = fmaf(-2.f, acc[r], sq4[r]);
      if (s < best) { best = s; bk = kb + r; }
    }
  }
  #pragma unroll
  for (int m = 16; m <= 32; m <<= 1) {
    float os = __shfl_xor(best, m, 64);
    int ok = __shfl_xor(bk, m, 64);
    if (os < best || (os == best && ok < bk)) { best = os; bk = ok; }
  }
  const uint4* zr = (const uint4*)zrow;
  uint4* qr = (uint4*)(zq + (long)b * qImgS + (long)y * qRowS + (long)x * 128);
  const uint4* er = (const uint4*)(emb + (long)bk * 128);
  float lsum = 0.f;
  #pragma unroll
  for (int t = 0; t < 4; ++t) {
    int j = quad * 4 + t;
    uint4 ue = er[j];
    uint4 uz = zr[j];
    qr[j] = ue;
    float ev[8], zv[8];
    unpack_u4(ue, ev);
    unpack_u4(uz, zv);
    #pragma unroll
    for (int e = 0; e < 8; ++e) {
      float dv = ev[e] - zv[e];
      lsum = fmaf(dv, dv, lsum);
    }
  }
  for (int o = 32; o > 0; o >>= 1) lsum += __shfl_down(lsum, o, 64);
  if (lane == 0) atomicAdd(loss_acc, lsum);
}

// --------------------- final convT(64->3)+sigmoid via class-packed MFMA
__global__ __launch_bounds__(256) void final_convt_mfma(
    const bf16* __restrict__ hp, const bf16* __restrict__ wfin,
    const float* __restrict__ bf_, float* __restrict__ out) {
  const int lane = threadIdx.x & 63, wv = threadIdx.x >> 6;
  const int ln = lane & 15, quad = lane >> 4;
  const int base = blockIdx.x * 256 + wv * 64;   // 262144 positions total

  short8 afr[18];
  #pragma unroll
  for (int kc = 0; kc < 18; ++kc)
    afr[kc] = *(const short8*)(wfin + ln * 576 + kc * 32 + quad * 8);

  float4v acc[4];
  #pragma unroll
  for (int bf = 0; bf < 4; ++bf) acc[bf] = {0.f, 0.f, 0.f, 0.f};

  #pragma unroll
  for (int bf = 0; bf < 4; ++bf) {
    int n = base + bf * 16 + ln;
    int xx = n & 127, y = (n >> 7) & 127, b = n >> 14;
    const bf16* hb = hp + (long)b * 1081600 + (long)y * 8320 + (long)xx * 64;
    #pragma unroll
    for (int kc = 0; kc < 18; ++kc) {
      int d = kc >> 1;
      const bf16* bp = hb + (long)(d / 3) * 8320 + (d % 3) * 64 + (kc & 1) * 32 + quad * 8;
      short8 bv = *(const short8*)bp;
      acc[bf] = __builtin_amdgcn_mfma_f32_16x16x32_bf16(afr[kc], bv, acc[bf], 0, 0, 0);
    }
  }

  const int p = quad >> 1, q = quad & 1;
  float b0 = bf_[0], b1 = bf_[1], b2 = bf_[2];
  #pragma unroll
  for (int bf = 0; bf < 4; ++bf) {
    int n = base + bf * 16 + ln;
    int xx = n & 127, y = (n >> 7) & 127, b = n >> 14;
    long ob = (long)b * 196608 + (long)(2 * y + p) * 256 + (2 * xx + q);
    float v0 = acc[bf][0] + b0, v1 = acc[bf][1] + b1, v2 = acc[bf][2] + b2;
    out[ob]          = 1.f / (1.f + expf(-v0));
    out[ob + 65536]  = 1.f / (1.f + expf(-v1));
    out[ob + 131072] = 1.f / (1.f + expf(-v2));
  }
}

__global__ void finalize_loss_kernel(const float* __restrict__ lacc, float* __restrict__ out) {
  if (threadIdx.x == 0) {
    float lt = lacc[0] * (1.5f / 2097152.f);
    float lb = lacc[1] * (1.5f / 8388608.f);
    *out = lt + lb;
  }
}

// ------------------------------------------------------------------ launch
extern "C" void kernel_launch(void* const* d_in, const int* in_sizes, int n_in,
                              void* d_out, int out_size, void* d_ws, size_t ws_size,
                              hipStream_t stream) {
  float* out = (float*)d_out;
  char* base = (char*)d_ws;
  size_t off = 0;
  auto alloc = [&](size_t bytes) {
    void* pp = base + off;
    off = (off + bytes + 255) & ~(size_t)255;
    return pp;
  };

  int* flag = (int*)alloc(256);
  float* biasAll = (float*)alloc(515 * 4);
  float* beB1f = biasAll + 0;
  float* beB2f = biasAll + 64;
  float* beTf  = biasAll + 192;
  float* bdTf  = biasAll + 320;
  float* bd1f  = biasAll + 448;
  float* bd2f  = biasAll + 512;
  float* sqAll = (float*)alloc(1024 * 4);
  float* sqT = sqAll, *sqB = sqAll + 512;
  float* lacc = (float*)alloc(2 * 4);
  bf16* Wc1  = (bf16*)alloc((size_t)4096 * 2);
  bf16* Wt2f = (bf16*)alloc((size_t)131072 * 2);
  bf16* Wttf = (bf16*)alloc((size_t)262144 * 2);
  bf16* Wdtf = (bf16*)alloc((size_t)262144 * 2);
  bf16* Wd1f = (bf16*)alloc((size_t)262144 * 2);
  bf16* Wfin = (bf16*)alloc((size_t)9216 * 2);
  bf16* embTB = (bf16*)alloc((size_t)131072 * 2);
  bf16* embT = embTB, *embB = embTB + 65536;
  bf16* act1p = (bf16*)alloc((size_t)17305600 * 2);  // [16][130][2][65][64] parity
  bf16* zbp   = (bf16*)alloc((size_t)8921088 * 2);   // [16][66][2][33][128] parity
  bf16* zqtp  = (bf16*)alloc((size_t)2367488 * 2);   // [16][34][34][128]
  bf16* eup   = (bf16*)alloc((size_t)8921088 * 2);   // [16][66][66][128]
  bf16* fqp   = (bf16*)alloc((size_t)8921088 * 2);   // [16][66][66][128]
  bf16* hp    = (bf16*)alloc((size_t)17305600 * 2);  // [16][130][130][64]
  bf16* ztp   = (bf16*)alloc((size_t)2097152 * 2);   // [16][32][32][128]

  // 2 setup launches (sqAll now wave-parallel -> +252 blocks, -serial tail)
  detect_dtype_kernel<<<1, 256, 0, stream>>>(d_in[0], flag, lacc);
  setup_all<<<5835, 256, 0, stream>>>(
      d_in[2], d_in[4], d_in[6], d_in[10], d_in[12], d_in[14],
      d_in[7], d_in[8], d_in[1], d_in[13], d_in[11], d_in[3],
      d_in[5], d_in[9],
      biasAll, embTB, sqAll, Wc1, Wfin, Wd1f, Wt2f, Wttf, Wdtf, flag,
      act1p, hp, zbp, eup, fqp, zqtp);

  // encoder: conv1 = LDS-staged im2col + MFMA GEMM (parity-split store)
  gemm1_lds<<<2048, 256, 0, stream>>>(d_in[0], flag, Wc1, beB1f, act1p);
  // conv2: LDS-staged + T14, 4 waves/block (co-quartered), 1024 x 256 thr
  conv2_lds<<<dim3(64, 1, 16), 256, 0, stream>>>(act1p, Wt2f, beB2f, zbp);
  // conv_t: PXW=33 (zbp parity), output ztp row-major
  mfma_conv<128, 128, 32, 2, 16, 128, 2, 33><<<dim3(16, 2, 16), 256, 0, stream>>>(
      zbp, zbp, 557568, 8448, Wttf, beTf, ztp, 131072, 4096, 128, 30, 0, 0, 0);

  // VQ top (16384 positions, row-major): 16 pos/wave -> 256 blocks, all CUs
  vq_mfma16<<<256, 256, 0, stream>>>(ztp, 131072, 4096, embT, sqT,
                                     zqtp + 4480, 147968, 4352, lacc + 0, 5, 10);

  // decoder_top upsample: 4 classes in one launch (row-major in/out)
  mfma_conv<128, 128, 32, 1, 4, 128, 2, 0><<<dim3(64, 2, 16), 256, 0, stream>>>(
      zqtp, zqtp, 147968, 4352, Wdtf, bdTf, eup, 557568, 16896, 256, 4, 8448, 128, 0);

  // VQ bottom (65536 positions; zbp parity-split input, fqp row-major out)
  vq_mfma<<<256, 256, 0, stream>>>(zbp + 8448, 557568, 8448, embB, sqB,
                                   fqp + 8576, 557568, 8448, lacc + 1, 6, 12, 33);

  // decoder conv d1: 8-wave blocks, wave=(class,row), 512 blocks x 512 thr
  mfma_d1_lds<<<dim3(32, 1, 16), 512, 0, stream>>>(fqp, eup, Wd1f, bd1f, hp);

  // final convT + sigmoid via MFMA -> fp32 NCHW output
  final_convt_mfma<<<1024, 256, 0, stream>>>(hp, Wfin, bd2f, out);
  finalize_loss_kernel<<<1, 64, 0, stream>>>(lacc, out + 3145728);
}